// Round 1
// 671.296 us; speedup vs baseline: 1.0027x; 1.0027x over previous
//
#include <hip/hip_runtime.h>
#include <cmath>

#define N_NODES 50000
#define N_EDGES 800000
#define D_IN    128
#define D_HID   256
#define D_OUT   47
#define BN_EPS  1e-5f
#define SCAN_NBLK ((N_NODES + 255) / 256)   // 196

typedef __attribute__((ext_vector_type(8))) short bf16x8;
typedef __attribute__((ext_vector_type(4))) float floatx4;
typedef unsigned short u16;

__device__ __forceinline__ short f2bf(float f) {          // legacy (short)
    unsigned u = __float_as_uint(f);
    u += 0x7fff + ((u >> 16) & 1);
    return (short)(u >> 16);
}
__device__ __forceinline__ u16 f2bf_u(float f) {
    unsigned u = __float_as_uint(f);
    u += 0x7fff + ((u >> 16) & 1);
    return (u16)(u >> 16);
}
__device__ __forceinline__ float bf2f(u16 h) {
    return __uint_as_float(((unsigned)h) << 16);
}

// ---------------------------------------------------------------------------
// edge_index layout detection (int64 vs int32)
// ---------------------------------------------------------------------------
__global__ void detect_idx_kernel(const int* __restrict__ ei, int* __restrict__ flag) {
    __shared__ int any_nonzero;
    if (threadIdx.x == 0) any_nonzero = 0;
    __syncthreads();
    int v = ei[2 * threadIdx.x + 1];
    if (v != 0) atomicAdd(&any_nonzero, 1);
    __syncthreads();
    if (threadIdx.x == 0) *flag = (any_nonzero == 0) ? 1 : 0;
}

__device__ __forceinline__ int load_edge(const int* __restrict__ ei, int e, int which, int is64) {
    if (is64) return ei[2 * ((long long)which * N_EDGES + e)];
    return ei[(long long)which * N_EDGES + e];
}

// ---------------------------------------------------------------------------
// CSR build
// ---------------------------------------------------------------------------
__global__ void count_deg_kernel(const int* __restrict__ ei, const int* __restrict__ flag,
                                 int* __restrict__ degi) {
    int e = blockIdx.x * blockDim.x + threadIdx.x;
    if (e >= N_EDGES) return;
    int is64 = *flag;
    atomicAdd(&degi[load_edge(ei, e, 1, is64)], 1);
}

__global__ __launch_bounds__(256) void block_sum_kernel(const int* __restrict__ degi,
                                                        int* __restrict__ bsum) {
    const int i = blockIdx.x * 256 + threadIdx.x;
    int v = (i < N_NODES) ? degi[i] : 0;
#pragma unroll
    for (int off = 32; off > 0; off >>= 1) v += __shfl_down(v, off);
    __shared__ int sh[4];
    if ((threadIdx.x & 63) == 0) sh[threadIdx.x >> 6] = v;
    __syncthreads();
    if (threadIdx.x == 0) bsum[blockIdx.x] = sh[0] + sh[1] + sh[2] + sh[3];
}

__global__ __launch_bounds__(256) void scan_bsums_kernel(int* __restrict__ bsum,
                                                         int* __restrict__ row_ptr) {
    const int t = threadIdx.x;
    __shared__ int sh[256];
    int v = (t < SCAN_NBLK) ? bsum[t] : 0;
    sh[t] = v;
    __syncthreads();
#pragma unroll
    for (int off = 1; off < 256; off <<= 1) {
        int u = (t >= off) ? sh[t - off] : 0;
        __syncthreads();
        sh[t] += u;
        __syncthreads();
    }
    if (t < SCAN_NBLK) bsum[t] = sh[t] - v;
    if (t == 255) row_ptr[N_NODES] = sh[255];
}

__global__ __launch_bounds__(256) void fill_rowptr_kernel(const int* __restrict__ degi,
                                                          const int* __restrict__ bsum,
                                                          int* __restrict__ row_ptr,
                                                          int* __restrict__ cursor,
                                                          float* __restrict__ invd) {
    const int t = threadIdx.x;
    const int i = blockIdx.x * 256 + t;
    __shared__ int sh[256];
    int d = (i < N_NODES) ? degi[i] : 0;
    sh[t] = d;
    __syncthreads();
#pragma unroll
    for (int off = 1; off < 256; off <<= 1) {
        int u = (t >= off) ? sh[t - off] : 0;
        __syncthreads();
        sh[t] += u;
        __syncthreads();
    }
    if (i < N_NODES) {
        const int pos = bsum[blockIdx.x] + sh[t] - d;
        row_ptr[i] = pos;
        cursor[i]  = pos;
        invd[i]    = 1.0f / fmaxf((float)d, 1.0f);
    }
}

__global__ void fill_csr_kernel(const int* __restrict__ ei, const int* __restrict__ flag,
                                int* __restrict__ cursor, int* __restrict__ ssrc) {
    int e = blockIdx.x * blockDim.x + threadIdx.x;
    if (e >= N_EDGES) return;
    int is64 = *flag;
    int s = load_edge(ei, e, 0, is64);
    int d = load_edge(ei, e, 1, is64);
    int pos = atomicAdd(&cursor[d], 1);
    ssrc[pos] = s;
}

// ===========================================================================
// FULL (bf16-direct) path kernels
// ===========================================================================

// x (fp32) -> xb (bf16), N*128 elems
__global__ void convert_xb_kernel(const float* __restrict__ x, u16* __restrict__ xb) {
    const int n4 = N_NODES * D_IN / 4;
    int i = blockIdx.x * 256 + threadIdx.x;
    if (i >= n4) return;
    float4 v = ((const float4*)x)[i];
    ushort4 o;
    o.x = f2bf_u(v.x); o.y = f2bf_u(v.y); o.z = f2bf_u(v.z); o.w = f2bf_u(v.w);
    ((ushort4*)xb)[i] = o;
}

// all weights -> bf16, k-blocked layout: WT[kb][col][32] (kb = k/32)
// so the 8 col-frag loads per k-step are base + c*1024B immediates.
// WT3 = [W3_l | W3_r | 0pad] (128 cols x 256 k)
__global__ void build_wt_kernel(const float* __restrict__ W1l, const float* __restrict__ W1r,
                                const float* __restrict__ W2l, const float* __restrict__ W2r,
                                const float* __restrict__ W3l, const float* __restrict__ W3r,
                                u16* __restrict__ wt1l, u16* __restrict__ wt1r,
                                u16* __restrict__ wt2l, u16* __restrict__ wt2r,
                                u16* __restrict__ wt3) {
    int idx = blockIdx.x * 256 + threadIdx.x;
    if (idx < 65536) {                       // WT1l / WT1r : NC=256, K=128
        int seg = idx >> 15, d = idx & 32767;
        int kb = d >> 13, col = (d >> 5) & 255, kq = d & 31;
        int k = kb * 32 + kq;
        const float* W = seg ? W1r : W1l;
        u16* WT = seg ? wt1r : wt1l;
        WT[d] = f2bf_u(W[k * 256 + col]);
    } else if (idx < 196608) {               // WT2l / WT2r : NC=256, K=256
        int d = idx - 65536;
        int seg = d >> 16; d &= 65535;
        int kb = d >> 13, col = (d >> 5) & 255, kq = d & 31;
        int k = kb * 32 + kq;
        const float* W = seg ? W2r : W2l;
        u16* WT = seg ? wt2r : wt2l;
        WT[d] = f2bf_u(W[k * 256 + col]);
    } else if (idx < 229376) {               // WT3 : NC=128, K=256, zero-padded
        int d = idx - 196608;
        int kb = d >> 12, col = (d >> 5) & 127, kq = d & 31;
        int k = kb * 32 + kq;
        float v = 0.f;
        if (col < 47)      v = W3l[k * 47 + col];
        else if (col < 94) v = W3r[k * 47 + (col - 47)];
        wt3[d] = f2bf_u(v);
    }
}

// CSR gather-mean over bf16 rows: one wave per node
template <int CC>
__global__ __launch_bounds__(256) void gather_mean_bf(
    const u16* __restrict__ Xb, const int* __restrict__ rp,
    const int* __restrict__ ssrc, const float* __restrict__ invd,
    u16* __restrict__ agg)
{
    const int w = (blockIdx.x * 256 + threadIdx.x) >> 6;
    const int lane = threadIdx.x & 63;
    if (w >= N_NODES) return;
    const int start = rp[w], end = rp[w + 1];
    const float sc = invd[w];

    if constexpr (CC == 256) {
        const u16* base = Xb + lane * 4;
        float4 a = make_float4(0.f, 0.f, 0.f, 0.f);
        int e = start;
        for (; e + 1 < end; e += 2) {
            const ushort4 v0 = *(const ushort4*)(base + (size_t)ssrc[e] * 256);
            const ushort4 v1 = *(const ushort4*)(base + (size_t)ssrc[e + 1] * 256);
            a.x += bf2f(v0.x) + bf2f(v1.x); a.y += bf2f(v0.y) + bf2f(v1.y);
            a.z += bf2f(v0.z) + bf2f(v1.z); a.w += bf2f(v0.w) + bf2f(v1.w);
        }
        if (e < end) {
            const ushort4 v = *(const ushort4*)(base + (size_t)ssrc[e] * 256);
            a.x += bf2f(v.x); a.y += bf2f(v.y); a.z += bf2f(v.z); a.w += bf2f(v.w);
        }
        ushort4 o;
        o.x = f2bf_u(a.x * sc); o.y = f2bf_u(a.y * sc);
        o.z = f2bf_u(a.z * sc); o.w = f2bf_u(a.w * sc);
        *(ushort4*)(agg + (size_t)w * 256 + lane * 4) = o;
    } else {  // CC == 128
        const u16* base = Xb + lane * 2;
        float2 a = make_float2(0.f, 0.f);
        int e = start;
        for (; e + 1 < end; e += 2) {
            const ushort2 v0 = *(const ushort2*)(base + (size_t)ssrc[e] * 128);
            const ushort2 v1 = *(const ushort2*)(base + (size_t)ssrc[e + 1] * 128);
            a.x += bf2f(v0.x) + bf2f(v1.x); a.y += bf2f(v0.y) + bf2f(v1.y);
        }
        if (e < end) {
            const ushort2 v = *(const ushort2*)(base + (size_t)ssrc[e] * 128);
            a.x += bf2f(v.x); a.y += bf2f(v.y);
        }
        ushort2 o;
        o.x = f2bf_u(a.x * sc); o.y = f2bf_u(a.y * sc);
        *(ushort2*)(agg + (size_t)w * 128 + lane * 2) = o;
    }
}

// ---------------------------------------------------------------------------
// Direct-from-global bf16 MFMA GEMM (no LDS, no barriers).
// Latency-hiding redesign:
//   * 64-row x 128-col block (4 waves x 16 rows) -> 2x blocks -> occ cap 16 w/CU
//   * explicit 2-stage register pipeline on the k-loop (load k+1 before MFMA k)
//   * k-blocked weight layout WT[kb][col][32]: one B base pointer, c*1024B imm
// K compile-time (NK = K/32, even). A row-major bf16 [N][K].
// split>0: cols<split -> C (no bias); split<=col<2*split -> C2 + bias.
// ---------------------------------------------------------------------------
template <int NK, int NC>
__device__ __forceinline__ void gemm_pass(const u16* __restrict__ A,
                                          const u16* __restrict__ WTb,
                                          int rowi, int col0, int lr, int quad,
                                          floatx4 (&acc)[8])
{
    constexpr int K = NK * 32;
    const u16* pa = A + (size_t)rowi * K + quad * 8;
    const u16* pb = WTb + (size_t)(col0 + lr) * 32 + quad * 8;

    bf16x8 aA = *(const bf16x8*)pa;
    bf16x8 bA[8];
#pragma unroll
    for (int c = 0; c < 8; ++c) bA[c] = *(const bf16x8*)(pb + c * 512);

#pragma unroll
    for (int kb = 0; kb < NK; kb += 2) {
        // stage B loads (k-block kb+1) issued before stage-A MFMAs
        const u16* pbn = pb + (size_t)(kb + 1) * NC * 32;
        bf16x8 aB = *(const bf16x8*)(pa + (kb + 1) * 32);
        bf16x8 bB[8];
#pragma unroll
        for (int c = 0; c < 8; ++c) bB[c] = *(const bf16x8*)(pbn + c * 512);
#pragma unroll
        for (int c = 0; c < 8; ++c)
            acc[c] = __builtin_amdgcn_mfma_f32_16x16x32_bf16(aA, bA[c], acc[c], 0, 0, 0);
        if (kb + 2 < NK) {
            const u16* pb2 = pb + (size_t)(kb + 2) * NC * 32;
            aA = *(const bf16x8*)(pa + (kb + 2) * 32);
#pragma unroll
            for (int c = 0; c < 8; ++c) bA[c] = *(const bf16x8*)(pb2 + c * 512);
        }
#pragma unroll
        for (int c = 0; c < 8; ++c)
            acc[c] = __builtin_amdgcn_mfma_f32_16x16x32_bf16(aB, bB[c], acc[c], 0, 0, 0);
    }
}

template <int NK0, int NK1, int NC>
__global__ __launch_bounds__(256, 4) void mfma_direct(
    const u16* __restrict__ A0, const u16* __restrict__ WT0,
    const u16* __restrict__ A1, const u16* __restrict__ WT1,
    const float* __restrict__ bias,
    const float* __restrict__ gamma, const float* __restrict__ beta,
    const float* __restrict__ mean, const float* __restrict__ var,
    float* __restrict__ C, int M, int do_bias, int bn_relu,
    u16* __restrict__ Cb, float* __restrict__ C2, int split)
{
    const int t = threadIdx.x;
    const int wv = t >> 6, lane = t & 63;
    const int lr = lane & 15, quad = lane >> 4;
    const int row_base = blockIdx.y * 64 + wv * 16;
    const int col0 = blockIdx.x * 128;

    floatx4 acc[8];
#pragma unroll
    for (int c = 0; c < 8; ++c) acc[c] = (floatx4){0.f, 0.f, 0.f, 0.f};

    int rowi = row_base + lr;
    if (rowi >= N_NODES) rowi = N_NODES - 1;

    gemm_pass<NK0, NC>(A0, WT0, rowi, col0, lr, quad, acc);
    if constexpr (NK1 > 0)
        gemm_pass<NK1, NC>(A1, WT1, rowi, col0, lr, quad, acc);

    // epilogue (C/D: col=lr, row=quad*4+g)
#pragma unroll
    for (int g = 0; g < 4; ++g) {
        const int row = row_base + quad * 4 + g;
        if (row >= N_NODES) continue;
#pragma unroll
        for (int c = 0; c < 8; ++c) {
            const int col = col0 + c * 16 + lr;
            float v = acc[c][g];
            if (split > 0) {
                if (col < split) {
                    C[(size_t)row * split + col] = v;
                } else if (col < 2 * split) {
                    C2[(size_t)row * split + (col - split)] = v + bias[col - split];
                }
            } else {
                if (col >= M) continue;
                if (do_bias) v += bias[col];
                if (bn_relu) {
                    v = (v - mean[col]) * (gamma[col] * rsqrtf(var[col] + BN_EPS)) + beta[col];
                    v = fmaxf(v, 0.0f);
                }
                const size_t off = (size_t)row * M + col;
                C[off] = v;
                if (Cb) Cb[off] = f2bf_u(v);
            }
        }
    }
}

// ===========================================================================
// SAFE path kernels (R5, proven)
// ===========================================================================
template <int CC>
__global__ __launch_bounds__(256) void gather_mean(
    const float* __restrict__ X, int ldx,
    const int* __restrict__ rp, const int* __restrict__ ssrc,
    const float* __restrict__ invd, float* __restrict__ agg)
{
    const long long gid = (long long)blockIdx.x * blockDim.x + threadIdx.x;
    const int w = (int)(gid >> 6);
    const int lane = threadIdx.x & 63;
    if (w >= N_NODES) return;
    const int start = rp[w], end = rp[w + 1];
    const float sc = invd[w];

    if constexpr (CC == 256) {
        const float* base = X + lane * 4;
        float4 a = make_float4(0.f, 0.f, 0.f, 0.f);
        int e = start;
        for (; e + 1 < end; e += 2) {
            int s0 = ssrc[e], s1 = ssrc[e + 1];
            float4 v0 = *(const float4*)(base + (long long)s0 * ldx);
            float4 v1 = *(const float4*)(base + (long long)s1 * ldx);
            a.x += v0.x + v1.x; a.y += v0.y + v1.y;
            a.z += v0.z + v1.z; a.w += v0.w + v1.w;
        }
        if (e < end) {
            float4 v = *(const float4*)(base + (long long)ssrc[e] * ldx);
            a.x += v.x; a.y += v.y; a.z += v.z; a.w += v.w;
        }
        float4 o = make_float4(a.x * sc, a.y * sc, a.z * sc, a.w * sc);
        *(float4*)(agg + (long long)w * 256 + lane * 4) = o;
    } else {
        const float* base = X + lane * 2;
        float2 a = make_float2(0.f, 0.f);
        int e = start;
        for (; e + 1 < end; e += 2) {
            int s0 = ssrc[e], s1 = ssrc[e + 1];
            float2 v0 = *(const float2*)(base + (long long)s0 * ldx);
            float2 v1 = *(const float2*)(base + (long long)s1 * ldx);
            a.x += v0.x + v1.x; a.y += v0.y + v1.y;
        }
        if (e < end) {
            float2 v = *(const float2*)(base + (long long)ssrc[e] * ldx);
            a.x += v.x; a.y += v.y;
        }
        float2 o = make_float2(a.x * sc, a.y * sc);
        *(float2*)(agg + (long long)w * 128 + lane * 2) = o;
    }
}

#define GBM 128
#define GBN 64
#define GBK 32
#define LDA 40
#define LDB 40

__global__ __launch_bounds__(256) void mfma_gemm(
    const float* __restrict__ A0, const float* __restrict__ B0, int K0,
    const float* __restrict__ A1, const float* __restrict__ B1, int K1,
    const float* __restrict__ bias,
    const float* __restrict__ gamma, const float* __restrict__ beta,
    const float* __restrict__ mean, const float* __restrict__ var,
    float* __restrict__ C, int M, int do_bias, int bn_relu)
{
    __shared__ short As[GBM * LDA];
    __shared__ short Bs[GBN * LDB];

    const int t = threadIdx.x;
    const int wv = t >> 6;
    const int lane = t & 63;
    const int row0 = blockIdx.y * GBM;
    const int col0 = blockIdx.x * GBN;

    const int lr = lane & 15;
    const int lk = (lane >> 4) * 8;

    floatx4 acc[2][4];
#pragma unroll
    for (int r = 0; r < 2; ++r)
#pragma unroll
        for (int c = 0; c < 4; ++c) acc[r][c] = (floatx4){0.f, 0.f, 0.f, 0.f};

    const int arow = t >> 3;
    const int akc  = (t & 7) * 4;
    const int bkr  = t >> 4;
    const int bcc  = (t & 15) * 4;

    for (int pass = 0; pass < 2; ++pass) {
        if (pass == 1 && A1 == nullptr) break;
        const float* __restrict__ A = pass ? A1 : A0;
        const float* __restrict__ B = pass ? B1 : B0;
        const int K = pass ? K1 : K0;

        for (int k0 = 0; k0 < K; k0 += GBK) {
            __syncthreads();
#pragma unroll
            for (int i = 0; i < 4; ++i) {
                const int lrow = arow + i * 32;
                const int grow = row0 + lrow;
                float4 v = make_float4(0.f, 0.f, 0.f, 0.f);
                if (grow < N_NODES)
                    v = *(const float4*)(A + (long long)grow * K + k0 + akc);
                short4 sv;
                sv.x = f2bf(v.x); sv.y = f2bf(v.y);
                sv.z = f2bf(v.z); sv.w = f2bf(v.w);
                *(short4*)(&As[lrow * LDA + akc]) = sv;
            }
#pragma unroll
            for (int i = 0; i < 2; ++i) {
                const int k = bkr + i * 16;
                const int gc = col0 + bcc;
                float4 v;
                if (gc + 3 < M) {
                    v = *(const float4*)(B + (long long)(k0 + k) * M + gc);
                } else {
                    v.x = (gc + 0 < M) ? B[(long long)(k0 + k) * M + gc + 0] : 0.f;
                    v.y = (gc + 1 < M) ? B[(long long)(k0 + k) * M + gc + 1] : 0.f;
                    v.z = (gc + 2 < M) ? B[(long long)(k0 + k) * M + gc + 2] : 0.f;
                    v.w = (gc + 3 < M) ? B[(long long)(k0 + k) * M + gc + 3] : 0.f;
                }
                Bs[(bcc + 0) * LDB + k] = f2bf(v.x);
                Bs[(bcc + 1) * LDB + k] = f2bf(v.y);
                Bs[(bcc + 2) * LDB + k] = f2bf(v.z);
                Bs[(bcc + 3) * LDB + k] = f2bf(v.w);
            }
            __syncthreads();

            bf16x8 af[2], bfr[4];
#pragma unroll
            for (int r = 0; r < 2; ++r)
                af[r] = *(const bf16x8*)(&As[(wv * 32 + r * 16 + lr) * LDA + lk]);
#pragma unroll
            for (int c = 0; c < 4; ++c)
                bfr[c] = *(const bf16x8*)(&Bs[(c * 16 + lr) * LDB + lk]);
#pragma unroll
            for (int r = 0; r < 2; ++r)
#pragma unroll
                for (int c = 0; c < 4; ++c)
                    acc[r][c] = __builtin_amdgcn_mfma_f32_16x16x32_bf16(
                        af[r], bfr[c], acc[r][c], 0, 0, 0);
        }
    }

#pragma unroll
    for (int r = 0; r < 2; ++r) {
#pragma unroll
        for (int g = 0; g < 4; ++g) {
            const int row = row0 + wv * 32 + r * 16 + (lane >> 4) * 4 + g;
            if (row >= N_NODES) continue;
#pragma unroll
            for (int c = 0; c < 4; ++c) {
                const int col = col0 + c * 16 + lr;
                if (col >= M) continue;
                float v = acc[r][c][g];
                if (do_bias) v += bias[col];
                if (bn_relu) {
                    v = (v - mean[col]) * (gamma[col] * rsqrtf(var[col] + BN_EPS)) + beta[col];
                    v = fmaxf(v, 0.0f);
                }
                C[(long long)row * M + col] = v;
            }
        }
    }
}

// ---------------------------------------------------------------------------
// shared epilogue kernels
// ---------------------------------------------------------------------------
__global__ __launch_bounds__(256) void gather_add_out(
    const float* __restrict__ U, const int* __restrict__ rp,
    const int* __restrict__ ssrc, const float* __restrict__ invd,
    float* __restrict__ z)
{
    const int w = (blockIdx.x * 256 + threadIdx.x) >> 6;
    const int lane = threadIdx.x & 63;
    if (w >= N_NODES) return;
    const int start = rp[w], end = rp[w + 1];
    float a = 0.f;
    for (int e = start; e < end; ++e) {
        int s = ssrc[e];
        if (lane < D_OUT) a += U[(long long)s * D_OUT + lane];
    }
    if (lane < D_OUT) z[(long long)w * D_OUT + lane] += a * invd[w];
}

__global__ void log_softmax_kernel(const float* __restrict__ z, float* __restrict__ y) {
    const int gtid = blockIdx.x * blockDim.x + threadIdx.x;
    const int row = gtid >> 6;
    const int lane = threadIdx.x & 63;
    if (row >= N_NODES) return;

    const float* zr = z + (long long)row * D_OUT;
    float v = (lane < D_OUT) ? zr[lane] : -INFINITY;

    float m = v;
#pragma unroll
    for (int off = 32; off > 0; off >>= 1) m = fmaxf(m, __shfl_down(m, off));
    m = __shfl(m, 0);

    float ev = (lane < D_OUT) ? expf(v - m) : 0.0f;
    float s = ev;
#pragma unroll
    for (int off = 32; off > 0; off >>= 1) s += __shfl_down(s, off);
    s = __shfl(s, 0);

    if (lane < D_OUT) y[(long long)row * D_OUT + lane] = v - m - logf(s);
}

// ---------------------------------------------------------------------------
// launch
// ---------------------------------------------------------------------------
extern "C" void kernel_launch(void* const* d_in, const int* in_sizes, int n_in,
                              void* d_out, int out_size, void* d_ws, size_t ws_size,
                              hipStream_t stream) {
    const float* x     = (const float*)d_in[0];
    const int*   ei    = (const int*)d_in[1];
    const float* W1_l  = (const float*)d_in[2];
    const float* b1    = (const float*)d_in[3];
    const float* W1_r  = (const float*)d_in[4];
    const float* bn1_g = (const float*)d_in[5];
    const float* bn1_b = (const float*)d_in[6];
    const float* bn1_m = (const float*)d_in[7];
    const float* bn1_v = (const float*)d_in[8];
    const float* W2_l  = (const float*)d_in[9];
    const float* b2    = (const float*)d_in[10];
    const float* W2_r  = (const float*)d_in[11];
    const float* bn2_g = (const float*)d_in[12];
    const float* bn2_b = (const float*)d_in[13];
    const float* bn2_m = (const float*)d_in[14];
    const float* bn2_v = (const float*)d_in[15];
    const float* W3_l  = (const float*)d_in[16];
    const float* b3    = (const float*)d_in[17];
    const float* W3_r  = (const float*)d_in[18];

    // --- common workspace (CSR) ---
    char* ws = (char*)d_ws;
    int*   degi    = (int*)(ws + 0);
    int*   row_ptr = (int*)(ws + 200064);
    int*   cursor  = (int*)(ws + 400128);
    float* invd    = (float*)(ws + 600192);
    int*   flag    = (int*)(ws + 800256);
    int*   bsum    = (int*)(ws + 800320);
    int*   ssrc    = (int*)(ws + 801152);          // 3.2 MB -> ends 4,001,152

    // d_out layout: z [N*47] | y_pred [N*47] | S1 [N*256] | S2 [N*256]
    float* z     = (float*)d_out;
    float* ypred = z + (long long)N_NODES * D_OUT;
    float* S1    = ypred + (long long)N_NODES * D_OUT;
    float* S2    = S1 + (long long)N_NODES * D_HID;

    // --- CSR build (shared) ---
    detect_idx_kernel<<<1, 256, 0, stream>>>(ei, flag);
    hipMemsetAsync(degi, 0, N_NODES * sizeof(int), stream);
    count_deg_kernel<<<(N_EDGES + 255) / 256, 256, 0, stream>>>(ei, flag, degi);
    block_sum_kernel<<<SCAN_NBLK, 256, 0, stream>>>(degi, bsum);
    scan_bsums_kernel<<<1, 256, 0, stream>>>(bsum, row_ptr);
    fill_rowptr_kernel<<<SCAN_NBLK, 256, 0, stream>>>(degi, bsum, row_ptr, cursor, invd);
    fill_csr_kernel<<<(N_EDGES + 255) / 256, 256, 0, stream>>>(ei, flag, cursor, ssrc);

    const int gblocks = (N_NODES * 64 + 255) / 256;

    // FULL bf16-direct plan needs 94,059,904 B of ws
    if (ws_size >= 94059904ULL) {
        u16*   wt1l = (u16*)(ws + 4001152);
        u16*   wt1r = (u16*)(ws + 4066688);
        u16*   wt2l = (u16*)(ws + 4132224);
        u16*   wt2r = (u16*)(ws + 4263296);
        u16*   wt3  = (u16*)(ws + 4394368);
        u16*   xb   = (u16*)(ws + 4459904);        // N*128 bf16
        u16*   S1b  = (u16*)(ws + 17259904);       // N*256 bf16
        u16*   S2b  = (u16*)(ws + 42859904);       // N*256 bf16
        u16*   agg  = (u16*)(ws + 68459904);       // N*256 bf16 (reused as U fp32)
        float* U    = (float*)agg;

        convert_xb_kernel<<<(N_NODES * D_IN / 4 + 255) / 256, 256, 0, stream>>>(x, xb);
        build_wt_kernel<<<(229376 + 255) / 256, 256, 0, stream>>>(
            W1_l, W1_r, W2_l, W2_r, W3_l, W3_r, wt1l, wt1r, wt2l, wt2r, wt3);

        const dim3 gHid(2, (N_NODES + 63) / 64);   // M=256, 64-row blocks
        const dim3 gOut(1, (N_NODES + 63) / 64);   // M=94 (padded 128)

        // layer 1 (K=128 x2 passes)
        gather_mean_bf<128><<<gblocks, 256, 0, stream>>>(xb, row_ptr, ssrc, invd, agg);
        mfma_direct<4, 4, 256><<<gHid, 256, 0, stream>>>(
            agg, wt1l, xb, wt1r,
            b1, bn1_g, bn1_b, bn1_m, bn1_v,
            S1, D_HID, 1, 1, S1b, nullptr, 0);
        // layer 2 (K=256 x2 passes)
        gather_mean_bf<256><<<gblocks, 256, 0, stream>>>(S1b, row_ptr, ssrc, invd, agg);
        mfma_direct<8, 8, 256><<<gHid, 256, 0, stream>>>(
            agg, wt2l, S1b, wt2r,
            b2, bn2_g, bn2_b, bn2_m, bn2_v,
            S2, D_HID, 1, 1, S2b, nullptr, 0);
        // layer 3 (fused transform-first: U = S2@W3_l, z = S2@W3_r + b3)
        mfma_direct<8, 0, 128><<<gOut, 256, 0, stream>>>(
            S2b, wt3, nullptr, nullptr,
            b3, nullptr, nullptr, nullptr, nullptr,
            U, 94, 0, 0, nullptr, z, D_OUT);
        gather_add_out<<<gblocks, 256, 0, stream>>>(U, row_ptr, ssrc, invd, z);
    } else {
        // SAFE: R5 fp32-LDS pipeline (proven <= 55.2 MB)
        float* aggF = (float*)(ws + 4001152);      // N*256 fp32, ends 55,201,152
        float* U    = aggF;

        const dim3 gHid(D_HID / GBN, (N_NODES + GBM - 1) / GBM);
        const dim3 gOut(1, (N_NODES + GBM - 1) / GBM);

        gather_mean<128><<<gblocks, 256, 0, stream>>>(x, D_IN, row_ptr, ssrc, invd, aggF);
        mfma_gemm<<<gHid, 256, 0, stream>>>(aggF, W1_l, D_IN, x, W1_r, D_IN,
                                            b1, bn1_g, bn1_b, bn1_m, bn1_v,
                                            S1, D_HID, 1, 1);
        gather_mean<256><<<gblocks, 256, 0, stream>>>(S1, D_HID, row_ptr, ssrc, invd, aggF);
        mfma_gemm<<<gHid, 256, 0, stream>>>(aggF, W2_l, D_HID, S1, W2_r, D_HID,
                                            b2, bn2_g, bn2_b, bn2_m, bn2_v,
                                            S2, D_HID, 1, 1);
        mfma_gemm<<<gOut, 256, 0, stream>>>(S2, W3_l, D_HID, nullptr, nullptr, 0,
                                            nullptr, nullptr, nullptr, nullptr, nullptr,
                                            U, D_OUT, 0, 0);
        mfma_gemm<<<gOut, 256, 0, stream>>>(S2, W3_r, D_HID, nullptr, nullptr, 0,
                                            b3, nullptr, nullptr, nullptr, nullptr,
                                            z, D_OUT, 1, 0);
        gather_add_out<<<gblocks, 256, 0, stream>>>(U, row_ptr, ssrc, invd, z);
    }

    log_softmax_kernel<<<gblocks, 256, 0, stream>>>(z, ypred);
}

// Round 4
// 640.820 us; speedup vs baseline: 1.0504x; 1.0476x over previous
//
#include <hip/hip_runtime.h>
#include <cmath>

#define N_NODES 50000
#define N_EDGES 800000
#define D_IN    128
#define D_HID   256
#define D_OUT   47
#define BN_EPS  1e-5f
#define SCAN_NBLK ((N_NODES + 255) / 256)   // 196

typedef __attribute__((ext_vector_type(8))) short bf16x8;
typedef __attribute__((ext_vector_type(4))) float floatx4;
typedef unsigned short u16;

__device__ __forceinline__ short f2bf(float f) {          // legacy (short)
    unsigned u = __float_as_uint(f);
    u += 0x7fff + ((u >> 16) & 1);
    return (short)(u >> 16);
}
__device__ __forceinline__ u16 f2bf_u(float f) {
    unsigned u = __float_as_uint(f);
    u += 0x7fff + ((u >> 16) & 1);
    return (u16)(u >> 16);
}
__device__ __forceinline__ float bf2f(u16 h) {
    return __uint_as_float(((unsigned)h) << 16);
}

// ---------------------------------------------------------------------------
// edge_index layout detection (int64 vs int32)
// ---------------------------------------------------------------------------
__global__ void detect_idx_kernel(const int* __restrict__ ei, int* __restrict__ flag) {
    __shared__ int any_nonzero;
    if (threadIdx.x == 0) any_nonzero = 0;
    __syncthreads();
    int v = ei[2 * threadIdx.x + 1];
    if (v != 0) atomicAdd(&any_nonzero, 1);
    __syncthreads();
    if (threadIdx.x == 0) *flag = (any_nonzero == 0) ? 1 : 0;
}

__device__ __forceinline__ int load_edge(const int* __restrict__ ei, int e, int which, int is64) {
    if (is64) return ei[2 * ((long long)which * N_EDGES + e)];
    return ei[(long long)which * N_EDGES + e];
}

// ---------------------------------------------------------------------------
// CSR build
// ---------------------------------------------------------------------------
__global__ void count_deg_kernel(const int* __restrict__ ei, const int* __restrict__ flag,
                                 int* __restrict__ degi) {
    int e = blockIdx.x * blockDim.x + threadIdx.x;
    if (e >= N_EDGES) return;
    int is64 = *flag;
    atomicAdd(&degi[load_edge(ei, e, 1, is64)], 1);
}

__global__ __launch_bounds__(256) void block_sum_kernel(const int* __restrict__ degi,
                                                        int* __restrict__ bsum) {
    const int i = blockIdx.x * 256 + threadIdx.x;
    int v = (i < N_NODES) ? degi[i] : 0;
#pragma unroll
    for (int off = 32; off > 0; off >>= 1) v += __shfl_down(v, off);
    __shared__ int sh[4];
    if ((threadIdx.x & 63) == 0) sh[threadIdx.x >> 6] = v;
    __syncthreads();
    if (threadIdx.x == 0) bsum[blockIdx.x] = sh[0] + sh[1] + sh[2] + sh[3];
}

__global__ __launch_bounds__(256) void scan_bsums_kernel(int* __restrict__ bsum,
                                                         int* __restrict__ row_ptr) {
    const int t = threadIdx.x;
    __shared__ int sh[256];
    int v = (t < SCAN_NBLK) ? bsum[t] : 0;
    sh[t] = v;
    __syncthreads();
#pragma unroll
    for (int off = 1; off < 256; off <<= 1) {
        int u = (t >= off) ? sh[t - off] : 0;
        __syncthreads();
        sh[t] += u;
        __syncthreads();
    }
    if (t < SCAN_NBLK) bsum[t] = sh[t] - v;
    if (t == 255) row_ptr[N_NODES] = sh[255];
}

__global__ __launch_bounds__(256) void fill_rowptr_kernel(const int* __restrict__ degi,
                                                          const int* __restrict__ bsum,
                                                          int* __restrict__ row_ptr,
                                                          int* __restrict__ cursor,
                                                          float* __restrict__ invd) {
    const int t = threadIdx.x;
    const int i = blockIdx.x * 256 + t;
    __shared__ int sh[256];
    int d = (i < N_NODES) ? degi[i] : 0;
    sh[t] = d;
    __syncthreads();
#pragma unroll
    for (int off = 1; off < 256; off <<= 1) {
        int u = (t >= off) ? sh[t - off] : 0;
        __syncthreads();
        sh[t] += u;
        __syncthreads();
    }
    if (i < N_NODES) {
        const int pos = bsum[blockIdx.x] + sh[t] - d;
        row_ptr[i] = pos;
        cursor[i]  = pos;
        invd[i]    = 1.0f / fmaxf((float)d, 1.0f);
    }
}

__global__ void fill_csr_kernel(const int* __restrict__ ei, const int* __restrict__ flag,
                                int* __restrict__ cursor, int* __restrict__ ssrc) {
    int e = blockIdx.x * blockDim.x + threadIdx.x;
    if (e >= N_EDGES) return;
    int is64 = *flag;
    int s = load_edge(ei, e, 0, is64);
    int d = load_edge(ei, e, 1, is64);
    int pos = atomicAdd(&cursor[d], 1);
    ssrc[pos] = s;
}

// ===========================================================================
// FULL (bf16-direct) path kernels
// ===========================================================================

// x (fp32) -> xb (bf16), N*128 elems
__global__ void convert_xb_kernel(const float* __restrict__ x, u16* __restrict__ xb) {
    const int n4 = N_NODES * D_IN / 4;
    int i = blockIdx.x * 256 + threadIdx.x;
    if (i >= n4) return;
    float4 v = ((const float4*)x)[i];
    ushort4 o;
    o.x = f2bf_u(v.x); o.y = f2bf_u(v.y); o.z = f2bf_u(v.z); o.w = f2bf_u(v.w);
    ((ushort4*)xb)[i] = o;
}

// all weights -> bf16, k-blocked layout: WT[kb][col][32] (kb = k/32)
// so per-k-step col-frag loads are base + c*1024B immediates.
// WT3 = [W3_l | W3_r | 0pad] (128 cols x 256 k)
__global__ void build_wt_kernel(const float* __restrict__ W1l, const float* __restrict__ W1r,
                                const float* __restrict__ W2l, const float* __restrict__ W2r,
                                const float* __restrict__ W3l, const float* __restrict__ W3r,
                                u16* __restrict__ wt1l, u16* __restrict__ wt1r,
                                u16* __restrict__ wt2l, u16* __restrict__ wt2r,
                                u16* __restrict__ wt3) {
    int idx = blockIdx.x * 256 + threadIdx.x;
    if (idx < 65536) {                       // WT1l / WT1r : NC=256, K=128
        int seg = idx >> 15, d = idx & 32767;
        int kb = d >> 13, col = (d >> 5) & 255, kq = d & 31;
        int k = kb * 32 + kq;
        const float* W = seg ? W1r : W1l;
        u16* WT = seg ? wt1r : wt1l;
        WT[d] = f2bf_u(W[k * 256 + col]);
    } else if (idx < 196608) {               // WT2l / WT2r : NC=256, K=256
        int d = idx - 65536;
        int seg = d >> 16; d &= 65535;
        int kb = d >> 13, col = (d >> 5) & 255, kq = d & 31;
        int k = kb * 32 + kq;
        const float* W = seg ? W2r : W2l;
        u16* WT = seg ? wt2r : wt2l;
        WT[d] = f2bf_u(W[k * 256 + col]);
    } else if (idx < 229376) {               // WT3 : NC=128, K=256, zero-padded
        int d = idx - 196608;
        int kb = d >> 12, col = (d >> 5) & 127, kq = d & 31;
        int k = kb * 32 + kq;
        float v = 0.f;
        if (col < 47)      v = W3l[k * 47 + col];
        else if (col < 94) v = W3r[k * 47 + (col - 47)];
        wt3[d] = f2bf_u(v);
    }
}

// CSR gather-mean over bf16 rows: one wave per node
template <int CC>
__global__ __launch_bounds__(256) void gather_mean_bf(
    const u16* __restrict__ Xb, const int* __restrict__ rp,
    const int* __restrict__ ssrc, const float* __restrict__ invd,
    u16* __restrict__ agg)
{
    const int w = (blockIdx.x * 256 + threadIdx.x) >> 6;
    const int lane = threadIdx.x & 63;
    if (w >= N_NODES) return;
    const int start = rp[w], end = rp[w + 1];
    const float sc = invd[w];

    if constexpr (CC == 256) {
        const u16* base = Xb + lane * 4;
        float4 a = make_float4(0.f, 0.f, 0.f, 0.f);
        int e = start;
        for (; e + 1 < end; e += 2) {
            const ushort4 v0 = *(const ushort4*)(base + (size_t)ssrc[e] * 256);
            const ushort4 v1 = *(const ushort4*)(base + (size_t)ssrc[e + 1] * 256);
            a.x += bf2f(v0.x) + bf2f(v1.x); a.y += bf2f(v0.y) + bf2f(v1.y);
            a.z += bf2f(v0.z) + bf2f(v1.z); a.w += bf2f(v0.w) + bf2f(v1.w);
        }
        if (e < end) {
            const ushort4 v = *(const ushort4*)(base + (size_t)ssrc[e] * 256);
            a.x += bf2f(v.x); a.y += bf2f(v.y); a.z += bf2f(v.z); a.w += bf2f(v.w);
        }
        ushort4 o;
        o.x = f2bf_u(a.x * sc); o.y = f2bf_u(a.y * sc);
        o.z = f2bf_u(a.z * sc); o.w = f2bf_u(a.w * sc);
        *(ushort4*)(agg + (size_t)w * 256 + lane * 4) = o;
    } else {  // CC == 128
        const u16* base = Xb + lane * 2;
        float2 a = make_float2(0.f, 0.f);
        int e = start;
        for (; e + 1 < end; e += 2) {
            const ushort2 v0 = *(const ushort2*)(base + (size_t)ssrc[e] * 128);
            const ushort2 v1 = *(const ushort2*)(base + (size_t)ssrc[e + 1] * 128);
            a.x += bf2f(v0.x) + bf2f(v1.x); a.y += bf2f(v0.y) + bf2f(v1.y);
        }
        if (e < end) {
            const ushort2 v = *(const ushort2*)(base + (size_t)ssrc[e] * 128);
            a.x += bf2f(v.x); a.y += bf2f(v.y);
        }
        ushort2 o;
        o.x = f2bf_u(a.x * sc); o.y = f2bf_u(a.y * sc);
        *(ushort2*)(agg + (size_t)w * 128 + lane * 2) = o;
    }
}

// ---------------------------------------------------------------------------
// Direct-from-global bf16 MFMA GEMM (no LDS, no barriers).
// Round-2 structure (2nd resubmission after broker timeouts):
//   * 128-row x 64-col block: 4 waves x (2 row-frags x 4 col-frags).
//     Per k-step/wave: 2 A-loads (HBM, the streaming operand) + 4 B-loads (L2)
//     + 8 MFMA -> doubles the HBM-load fraction vs 64-row blocks.
//   * explicit 2-deep register pipeline (cur/next ping-pong). Budget:
//     acc 32 + 2*(2A+4B)*4 = 48 + addr ~= 90-110 VGPR -> fits under the
//     launch_bounds(256,4)=128 cap so regalloc RETAINS the pipeline
//     (round-1 failure mode: needed ~140, got de-pipelined to VGPR=44).
//   * grid (NC/64, 391) = 1564 blocks -> ~6 blocks/CU, 16 waves/CU cap.
// K compile-time (NK = K/32). A row-major bf16 [N][K]; WT [kb][col][32].
// split>0: cols<split -> C (no bias); split<=col<2*split -> C2 + bias.
// ---------------------------------------------------------------------------
template <int NK, int NC>
__device__ __forceinline__ void gemm_pass(const u16* __restrict__ A,
                                          const u16* __restrict__ WTb,
                                          int rowi0, int rowi1, int col0,
                                          int lr, int quad,
                                          floatx4 (&acc)[2][4])
{
    constexpr int K = NK * 32;
    const u16* pa0 = A + (size_t)rowi0 * K + quad * 8;
    const u16* pa1 = A + (size_t)rowi1 * K + quad * 8;
    const u16* pb  = WTb + (size_t)(col0 + lr) * 32 + quad * 8;

    bf16x8 a0c = *(const bf16x8*)pa0;
    bf16x8 a1c = *(const bf16x8*)pa1;
    bf16x8 bc[4];
#pragma unroll
    for (int c = 0; c < 4; ++c) bc[c] = *(const bf16x8*)(pb + c * 512);

#pragma unroll
    for (int kb = 0; kb < NK; ++kb) {
        bf16x8 a0n, a1n, bn[4];
        if (kb + 1 < NK) {
            // issue next k-block loads BEFORE consuming current regs
            a0n = *(const bf16x8*)(pa0 + (kb + 1) * 32);
            a1n = *(const bf16x8*)(pa1 + (kb + 1) * 32);
            const u16* pbn = pb + (size_t)(kb + 1) * NC * 32;
#pragma unroll
            for (int c = 0; c < 4; ++c) bn[c] = *(const bf16x8*)(pbn + c * 512);
        }
#pragma unroll
        for (int c = 0; c < 4; ++c) {
            acc[0][c] = __builtin_amdgcn_mfma_f32_16x16x32_bf16(a0c, bc[c], acc[0][c], 0, 0, 0);
            acc[1][c] = __builtin_amdgcn_mfma_f32_16x16x32_bf16(a1c, bc[c], acc[1][c], 0, 0, 0);
        }
        if (kb + 1 < NK) {
            a0c = a0n; a1c = a1n;
#pragma unroll
            for (int c = 0; c < 4; ++c) bc[c] = bn[c];
        }
    }
}

template <int NK0, int NK1, int NC>
__global__ __launch_bounds__(256, 4) void mfma_direct(
    const u16* __restrict__ A0, const u16* __restrict__ WT0,
    const u16* __restrict__ A1, const u16* __restrict__ WT1,
    const float* __restrict__ bias,
    const float* __restrict__ gamma, const float* __restrict__ beta,
    const float* __restrict__ mean, const float* __restrict__ var,
    float* __restrict__ C, int M, int do_bias, int bn_relu,
    u16* __restrict__ Cb, float* __restrict__ C2, int split)
{
    const int t = threadIdx.x;
    const int wv = t >> 6, lane = t & 63;
    const int lr = lane & 15, quad = lane >> 4;
    const int row_base = blockIdx.y * 128 + wv * 32;
    const int col0 = blockIdx.x * 64;

    floatx4 acc[2][4];
#pragma unroll
    for (int r = 0; r < 2; ++r)
#pragma unroll
        for (int c = 0; c < 4; ++c) acc[r][c] = (floatx4){0.f, 0.f, 0.f, 0.f};

    int rowi0 = row_base + lr;
    int rowi1 = row_base + 16 + lr;
    if (rowi0 >= N_NODES) rowi0 = N_NODES - 1;
    if (rowi1 >= N_NODES) rowi1 = N_NODES - 1;

    gemm_pass<NK0, NC>(A0, WT0, rowi0, rowi1, col0, lr, quad, acc);
    if constexpr (NK1 > 0)
        gemm_pass<NK1, NC>(A1, WT1, rowi0, rowi1, col0, lr, quad, acc);

    // epilogue (C/D: col=lr, row=quad*4+g)
#pragma unroll
    for (int r = 0; r < 2; ++r) {
#pragma unroll
        for (int g = 0; g < 4; ++g) {
            const int row = row_base + r * 16 + quad * 4 + g;
            if (row >= N_NODES) continue;
#pragma unroll
            for (int c = 0; c < 4; ++c) {
                const int col = col0 + c * 16 + lr;
                float v = acc[r][c][g];
                if (split > 0) {
                    if (col < split) {
                        C[(size_t)row * split + col] = v;
                    } else if (col < 2 * split) {
                        C2[(size_t)row * split + (col - split)] = v + bias[col - split];
                    }
                } else {
                    if (col >= M) continue;
                    if (do_bias) v += bias[col];
                    if (bn_relu) {
                        v = (v - mean[col]) * (gamma[col] * rsqrtf(var[col] + BN_EPS)) + beta[col];
                        v = fmaxf(v, 0.0f);
                    }
                    const size_t off = (size_t)row * M + col;
                    C[off] = v;
                    if (Cb) Cb[off] = f2bf_u(v);
                }
            }
        }
    }
}

// ===========================================================================
// SAFE path kernels (R5, proven)
// ===========================================================================
template <int CC>
__global__ __launch_bounds__(256) void gather_mean(
    const float* __restrict__ X, int ldx,
    const int* __restrict__ rp, const int* __restrict__ ssrc,
    const float* __restrict__ invd, float* __restrict__ agg)
{
    const long long gid = (long long)blockIdx.x * blockDim.x + threadIdx.x;
    const int w = (int)(gid >> 6);
    const int lane = threadIdx.x & 63;
    if (w >= N_NODES) return;
    const int start = rp[w], end = rp[w + 1];
    const float sc = invd[w];

    if constexpr (CC == 256) {
        const float* base = X + lane * 4;
        float4 a = make_float4(0.f, 0.f, 0.f, 0.f);
        int e = start;
        for (; e + 1 < end; e += 2) {
            int s0 = ssrc[e], s1 = ssrc[e + 1];
            float4 v0 = *(const float4*)(base + (long long)s0 * ldx);
            float4 v1 = *(const float4*)(base + (long long)s1 * ldx);
            a.x += v0.x + v1.x; a.y += v0.y + v1.y;
            a.z += v0.z + v1.z; a.w += v0.w + v1.w;
        }
        if (e < end) {
            float4 v = *(const float4*)(base + (long long)ssrc[e] * ldx);
            a.x += v.x; a.y += v.y; a.z += v.z; a.w += v.w;
        }
        float4 o = make_float4(a.x * sc, a.y * sc, a.z * sc, a.w * sc);
        *(float4*)(agg + (long long)w * 256 + lane * 4) = o;
    } else {
        const float* base = X + lane * 2;
        float2 a = make_float2(0.f, 0.f);
        int e = start;
        for (; e + 1 < end; e += 2) {
            int s0 = ssrc[e], s1 = ssrc[e + 1];
            float2 v0 = *(const float2*)(base + (long long)s0 * ldx);
            float2 v1 = *(const float2*)(base + (long long)s1 * ldx);
            a.x += v0.x + v1.x; a.y += v0.y + v1.y;
        }
        if (e < end) {
            float2 v = *(const float2*)(base + (long long)ssrc[e] * ldx);
            a.x += v.x; a.y += v.y;
        }
        float2 o = make_float2(a.x * sc, a.y * sc);
        *(float2*)(agg + (long long)w * 128 + lane * 2) = o;
    }
}

#define GBM 128
#define GBN 64
#define GBK 32
#define LDA 40
#define LDB 40

__global__ __launch_bounds__(256) void mfma_gemm(
    const float* __restrict__ A0, const float* __restrict__ B0, int K0,
    const float* __restrict__ A1, const float* __restrict__ B1, int K1,
    const float* __restrict__ bias,
    const float* __restrict__ gamma, const float* __restrict__ beta,
    const float* __restrict__ mean, const float* __restrict__ var,
    float* __restrict__ C, int M, int do_bias, int bn_relu)
{
    __shared__ short As[GBM * LDA];
    __shared__ short Bs[GBN * LDB];

    const int t = threadIdx.x;
    const int wv = t >> 6;
    const int lane = t & 63;
    const int row0 = blockIdx.y * GBM;
    const int col0 = blockIdx.x * GBN;

    const int lr = lane & 15;
    const int lk = (lane >> 4) * 8;

    floatx4 acc[2][4];
#pragma unroll
    for (int r = 0; r < 2; ++r)
#pragma unroll
        for (int c = 0; c < 4; ++c) acc[r][c] = (floatx4){0.f, 0.f, 0.f, 0.f};

    const int arow = t >> 3;
    const int akc  = (t & 7) * 4;
    const int bkr  = t >> 4;
    const int bcc  = (t & 15) * 4;

    for (int pass = 0; pass < 2; ++pass) {
        if (pass == 1 && A1 == nullptr) break;
        const float* __restrict__ A = pass ? A1 : A0;
        const float* __restrict__ B = pass ? B1 : B0;
        const int K = pass ? K1 : K0;

        for (int k0 = 0; k0 < K; k0 += GBK) {
            __syncthreads();
#pragma unroll
            for (int i = 0; i < 4; ++i) {
                const int lrow = arow + i * 32;
                const int grow = row0 + lrow;
                float4 v = make_float4(0.f, 0.f, 0.f, 0.f);
                if (grow < N_NODES)
                    v = *(const float4*)(A + (long long)grow * K + k0 + akc);
                short4 sv;
                sv.x = f2bf(v.x); sv.y = f2bf(v.y);
                sv.z = f2bf(v.z); sv.w = f2bf(v.w);
                *(short4*)(&As[lrow * LDA + akc]) = sv;
            }
#pragma unroll
            for (int i = 0; i < 2; ++i) {
                const int k = bkr + i * 16;
                const int gc = col0 + bcc;
                float4 v;
                if (gc + 3 < M) {
                    v = *(const float4*)(B + (long long)(k0 + k) * M + gc);
                } else {
                    v.x = (gc + 0 < M) ? B[(long long)(k0 + k) * M + gc + 0] : 0.f;
                    v.y = (gc + 1 < M) ? B[(long long)(k0 + k) * M + gc + 1] : 0.f;
                    v.z = (gc + 2 < M) ? B[(long long)(k0 + k) * M + gc + 2] : 0.f;
                    v.w = (gc + 3 < M) ? B[(long long)(k0 + k) * M + gc + 3] : 0.f;
                }
                Bs[(bcc + 0) * LDB + k] = f2bf(v.x);
                Bs[(bcc + 1) * LDB + k] = f2bf(v.y);
                Bs[(bcc + 2) * LDB + k] = f2bf(v.z);
                Bs[(bcc + 3) * LDB + k] = f2bf(v.w);
            }
            __syncthreads();

            bf16x8 af[2], bfr[4];
#pragma unroll
            for (int r = 0; r < 2; ++r)
                af[r] = *(const bf16x8*)(&As[(wv * 32 + r * 16 + lr) * LDA + lk]);
#pragma unroll
            for (int c = 0; c < 4; ++c)
                bfr[c] = *(const bf16x8*)(&Bs[(c * 16 + lr) * LDB + lk]);
#pragma unroll
            for (int r = 0; r < 2; ++r)
#pragma unroll
                for (int c = 0; c < 4; ++c)
                    acc[r][c] = __builtin_amdgcn_mfma_f32_16x16x32_bf16(
                        af[r], bfr[c], acc[r][c], 0, 0, 0);
        }
    }

#pragma unroll
    for (int r = 0; r < 2; ++r) {
#pragma unroll
        for (int g = 0; g < 4; ++g) {
            const int row = row0 + wv * 32 + r * 16 + (lane >> 4) * 4 + g;
            if (row >= N_NODES) continue;
#pragma unroll
            for (int c = 0; c < 4; ++c) {
                const int col = col0 + c * 16 + lr;
                if (col >= M) continue;
                float v = acc[r][c][g];
                if (do_bias) v += bias[col];
                if (bn_relu) {
                    v = (v - mean[col]) * (gamma[col] * rsqrtf(var[col] + BN_EPS)) + beta[col];
                    v = fmaxf(v, 0.0f);
                }
                C[(long long)row * M + col] = v;
            }
        }
    }
}

// ---------------------------------------------------------------------------
// shared epilogue kernels
// ---------------------------------------------------------------------------
__global__ __launch_bounds__(256) void gather_add_out(
    const float* __restrict__ U, const int* __restrict__ rp,
    const int* __restrict__ ssrc, const float* __restrict__ invd,
    float* __restrict__ z)
{
    const int w = (blockIdx.x * 256 + threadIdx.x) >> 6;
    const int lane = threadIdx.x & 63;
    if (w >= N_NODES) return;
    const int start = rp[w], end = rp[w + 1];
    float a = 0.f;
    for (int e = start; e < end; ++e) {
        int s = ssrc[e];
        if (lane < D_OUT) a += U[(long long)s * D_OUT + lane];
    }
    if (lane < D_OUT) z[(long long)w * D_OUT + lane] += a * invd[w];
}

__global__ void log_softmax_kernel(const float* __restrict__ z, float* __restrict__ y) {
    const int gtid = blockIdx.x * blockDim.x + threadIdx.x;
    const int row = gtid >> 6;
    const int lane = threadIdx.x & 63;
    if (row >= N_NODES) return;

    const float* zr = z + (long long)row * D_OUT;
    float v = (lane < D_OUT) ? zr[lane] : -INFINITY;

    float m = v;
#pragma unroll
    for (int off = 32; off > 0; off >>= 1) m = fmaxf(m, __shfl_down(m, off));
    m = __shfl(m, 0);

    float ev = (lane < D_OUT) ? expf(v - m) : 0.0f;
    float s = ev;
#pragma unroll
    for (int off = 32; off > 0; off >>= 1) s += __shfl_down(s, off);
    s = __shfl(s, 0);

    if (lane < D_OUT) y[(long long)row * D_OUT + lane] = v - m - logf(s);
}

// ---------------------------------------------------------------------------
// launch
// ---------------------------------------------------------------------------
extern "C" void kernel_launch(void* const* d_in, const int* in_sizes, int n_in,
                              void* d_out, int out_size, void* d_ws, size_t ws_size,
                              hipStream_t stream) {
    const float* x     = (const float*)d_in[0];
    const int*   ei    = (const int*)d_in[1];
    const float* W1_l  = (const float*)d_in[2];
    const float* b1    = (const float*)d_in[3];
    const float* W1_r  = (const float*)d_in[4];
    const float* bn1_g = (const float*)d_in[5];
    const float* bn1_b = (const float*)d_in[6];
    const float* bn1_m = (const float*)d_in[7];
    const float* bn1_v = (const float*)d_in[8];
    const float* W2_l  = (const float*)d_in[9];
    const float* b2    = (const float*)d_in[10];
    const float* W2_r  = (const float*)d_in[11];
    const float* bn2_g = (const float*)d_in[12];
    const float* bn2_b = (const float*)d_in[13];
    const float* bn2_m = (const float*)d_in[14];
    const float* bn2_v = (const float*)d_in[15];
    const float* W3_l  = (const float*)d_in[16];
    const float* b3    = (const float*)d_in[17];
    const float* W3_r  = (const float*)d_in[18];

    // --- common workspace (CSR) ---
    char* ws = (char*)d_ws;
    int*   degi    = (int*)(ws + 0);
    int*   row_ptr = (int*)(ws + 200064);
    int*   cursor  = (int*)(ws + 400128);
    float* invd    = (float*)(ws + 600192);
    int*   flag    = (int*)(ws + 800256);
    int*   bsum    = (int*)(ws + 800320);
    int*   ssrc    = (int*)(ws + 801152);          // 3.2 MB -> ends 4,001,152

    // d_out layout: z [N*47] | y_pred [N*47] | S1 [N*256] | S2 [N*256]
    float* z     = (float*)d_out;
    float* ypred = z + (long long)N_NODES * D_OUT;
    float* S1    = ypred + (long long)N_NODES * D_OUT;
    float* S2    = S1 + (long long)N_NODES * D_HID;

    // --- CSR build (shared) ---
    detect_idx_kernel<<<1, 256, 0, stream>>>(ei, flag);
    hipMemsetAsync(degi, 0, N_NODES * sizeof(int), stream);
    count_deg_kernel<<<(N_EDGES + 255) / 256, 256, 0, stream>>>(ei, flag, degi);
    block_sum_kernel<<<SCAN_NBLK, 256, 0, stream>>>(degi, bsum);
    scan_bsums_kernel<<<1, 256, 0, stream>>>(bsum, row_ptr);
    fill_rowptr_kernel<<<SCAN_NBLK, 256, 0, stream>>>(degi, bsum, row_ptr, cursor, invd);
    fill_csr_kernel<<<(N_EDGES + 255) / 256, 256, 0, stream>>>(ei, flag, cursor, ssrc);

    const int gblocks = (N_NODES * 64 + 255) / 256;

    // FULL bf16-direct plan needs 94,059,904 B of ws
    if (ws_size >= 94059904ULL) {
        u16*   wt1l = (u16*)(ws + 4001152);
        u16*   wt1r = (u16*)(ws + 4066688);
        u16*   wt2l = (u16*)(ws + 4132224);
        u16*   wt2r = (u16*)(ws + 4263296);
        u16*   wt3  = (u16*)(ws + 4394368);
        u16*   xb   = (u16*)(ws + 4459904);        // N*128 bf16
        u16*   S1b  = (u16*)(ws + 17259904);       // N*256 bf16
        u16*   S2b  = (u16*)(ws + 42859904);       // N*256 bf16
        u16*   agg  = (u16*)(ws + 68459904);       // N*256 bf16 (reused as U fp32)
        float* U    = (float*)agg;

        convert_xb_kernel<<<(N_NODES * D_IN / 4 + 255) / 256, 256, 0, stream>>>(x, xb);
        build_wt_kernel<<<(229376 + 255) / 256, 256, 0, stream>>>(
            W1_l, W1_r, W2_l, W2_r, W3_l, W3_r, wt1l, wt1r, wt2l, wt2r, wt3);

        const dim3 gHid(4, (N_NODES + 127) / 128);   // M=256, 128x64 blocks
        const dim3 gOut(2, (N_NODES + 127) / 128);   // M=94 (padded 128)

        // layer 1 (K=128 x2 passes)
        gather_mean_bf<128><<<gblocks, 256, 0, stream>>>(xb, row_ptr, ssrc, invd, agg);
        mfma_direct<4, 4, 256><<<gHid, 256, 0, stream>>>(
            agg, wt1l, xb, wt1r,
            b1, bn1_g, bn1_b, bn1_m, bn1_v,
            S1, D_HID, 1, 1, S1b, nullptr, 0);
        // layer 2 (K=256 x2 passes)
        gather_mean_bf<256><<<gblocks, 256, 0, stream>>>(S1b, row_ptr, ssrc, invd, agg);
        mfma_direct<8, 8, 256><<<gHid, 256, 0, stream>>>(
            agg, wt2l, S1b, wt2r,
            b2, bn2_g, bn2_b, bn2_m, bn2_v,
            S2, D_HID, 1, 1, S2b, nullptr, 0);
        // layer 3 (fused transform-first: U = S2@W3_l, z = S2@W3_r + b3)
        mfma_direct<8, 0, 128><<<gOut, 256, 0, stream>>>(
            S2b, wt3, nullptr, nullptr,
            b3, nullptr, nullptr, nullptr, nullptr,
            U, 94, 0, 0, nullptr, z, D_OUT);
        gather_add_out<<<gblocks, 256, 0, stream>>>(U, row_ptr, ssrc, invd, z);
    } else {
        // SAFE: R5 fp32-LDS pipeline (proven <= 55.2 MB)
        float* aggF = (float*)(ws + 4001152);      // N*256 fp32, ends 55,201,152
        float* U    = aggF;

        const dim3 gHid(D_HID / GBN, (N_NODES + GBM - 1) / GBM);
        const dim3 gOut(1, (N_NODES + GBM - 1) / GBM);

        gather_mean<128><<<gblocks, 256, 0, stream>>>(x, D_IN, row_ptr, ssrc, invd, aggF);
        mfma_gemm<<<gHid, 256, 0, stream>>>(aggF, W1_l, D_IN, x, W1_r, D_IN,
                                            b1, bn1_g, bn1_b, bn1_m, bn1_v,
                                            S1, D_HID, 1, 1);
        gather_mean<256><<<gblocks, 256, 0, stream>>>(S1, D_HID, row_ptr, ssrc, invd, aggF);
        mfma_gemm<<<gHid, 256, 0, stream>>>(aggF, W2_l, D_HID, S1, W2_r, D_HID,
                                            b2, bn2_g, bn2_b, bn2_m, bn2_v,
                                            S2, D_HID, 1, 1);
        mfma_gemm<<<gOut, 256, 0, stream>>>(S2, W3_l, D_HID, nullptr, nullptr, 0,
                                            nullptr, nullptr, nullptr, nullptr, nullptr,
                                            U, D_OUT, 0, 0);
        mfma_gemm<<<gOut, 256, 0, stream>>>(S2, W3_r, D_HID, nullptr, nullptr, 0,
                                            b3, nullptr, nullptr, nullptr, nullptr,
                                            z, D_OUT, 1, 0);
        gather_add_out<<<gblocks, 256, 0, stream>>>(U, row_ptr, ssrc, invd, z);
    }

    log_softmax_kernel<<<gblocks, 256, 0, stream>>>(z, ypred);
}

// Round 5
// 615.977 us; speedup vs baseline: 1.0928x; 1.0403x over previous
//
#include <hip/hip_runtime.h>
#include <cmath>

#define N_NODES 50000
#define N_EDGES 800000
#define D_IN    128
#define D_HID   256
#define D_OUT   47
#define BN_EPS  1e-5f
#define SCAN_NBLK ((N_NODES + 255) / 256)   // 196

typedef __attribute__((ext_vector_type(8))) short bf16x8;
typedef __attribute__((ext_vector_type(4))) float floatx4;
typedef unsigned short u16;
typedef unsigned int u32;

__device__ __forceinline__ short f2bf(float f) {          // legacy (short)
    unsigned u = __float_as_uint(f);
    u += 0x7fff + ((u >> 16) & 1);
    return (short)(u >> 16);
}
__device__ __forceinline__ u16 f2bf_u(float f) {
    unsigned u = __float_as_uint(f);
    u += 0x7fff + ((u >> 16) & 1);
    return (u16)(u >> 16);
}
__device__ __forceinline__ float bf2f(u16 h) {
    return __uint_as_float(((unsigned)h) << 16);
}

// async 16B global->LDS DMA (the op hipcc cannot sink; waited at barrier)
__device__ __forceinline__ void load_lds16(const void* g, void* l) {
    __builtin_amdgcn_global_load_lds(
        (const __attribute__((address_space(1))) u32*)g,
        (__attribute__((address_space(3))) u32*)l,
        16, 0, 0);
}

// ---------------------------------------------------------------------------
// edge_index layout detection (int64 vs int32)
// ---------------------------------------------------------------------------
__global__ void detect_idx_kernel(const int* __restrict__ ei, int* __restrict__ flag) {
    __shared__ int any_nonzero;
    if (threadIdx.x == 0) any_nonzero = 0;
    __syncthreads();
    int v = ei[2 * threadIdx.x + 1];
    if (v != 0) atomicAdd(&any_nonzero, 1);
    __syncthreads();
    if (threadIdx.x == 0) *flag = (any_nonzero == 0) ? 1 : 0;
}

__device__ __forceinline__ int load_edge(const int* __restrict__ ei, int e, int which, int is64) {
    if (is64) return ei[2 * ((long long)which * N_EDGES + e)];
    return ei[(long long)which * N_EDGES + e];
}

// ---------------------------------------------------------------------------
// CSR build
// ---------------------------------------------------------------------------
__global__ void count_deg_kernel(const int* __restrict__ ei, const int* __restrict__ flag,
                                 int* __restrict__ degi) {
    int e = blockIdx.x * blockDim.x + threadIdx.x;
    if (e >= N_EDGES) return;
    int is64 = *flag;
    atomicAdd(&degi[load_edge(ei, e, 1, is64)], 1);
}

__global__ __launch_bounds__(256) void block_sum_kernel(const int* __restrict__ degi,
                                                        int* __restrict__ bsum) {
    const int i = blockIdx.x * 256 + threadIdx.x;
    int v = (i < N_NODES) ? degi[i] : 0;
#pragma unroll
    for (int off = 32; off > 0; off >>= 1) v += __shfl_down(v, off);
    __shared__ int sh[4];
    if ((threadIdx.x & 63) == 0) sh[threadIdx.x >> 6] = v;
    __syncthreads();
    if (threadIdx.x == 0) bsum[blockIdx.x] = sh[0] + sh[1] + sh[2] + sh[3];
}

__global__ __launch_bounds__(256) void scan_bsums_kernel(int* __restrict__ bsum,
                                                         int* __restrict__ row_ptr) {
    const int t = threadIdx.x;
    __shared__ int sh[256];
    int v = (t < SCAN_NBLK) ? bsum[t] : 0;
    sh[t] = v;
    __syncthreads();
#pragma unroll
    for (int off = 1; off < 256; off <<= 1) {
        int u = (t >= off) ? sh[t - off] : 0;
        __syncthreads();
        sh[t] += u;
        __syncthreads();
    }
    if (t < SCAN_NBLK) bsum[t] = sh[t] - v;
    if (t == 255) row_ptr[N_NODES] = sh[255];
}

__global__ __launch_bounds__(256) void fill_rowptr_kernel(const int* __restrict__ degi,
                                                          const int* __restrict__ bsum,
                                                          int* __restrict__ row_ptr,
                                                          int* __restrict__ cursor,
                                                          float* __restrict__ invd) {
    const int t = threadIdx.x;
    const int i = blockIdx.x * 256 + t;
    __shared__ int sh[256];
    int d = (i < N_NODES) ? degi[i] : 0;
    sh[t] = d;
    __syncthreads();
#pragma unroll
    for (int off = 1; off < 256; off <<= 1) {
        int u = (t >= off) ? sh[t - off] : 0;
        __syncthreads();
        sh[t] += u;
        __syncthreads();
    }
    if (i < N_NODES) {
        const int pos = bsum[blockIdx.x] + sh[t] - d;
        row_ptr[i] = pos;
        cursor[i]  = pos;
        invd[i]    = 1.0f / fmaxf((float)d, 1.0f);
    }
}

__global__ void fill_csr_kernel(const int* __restrict__ ei, const int* __restrict__ flag,
                                int* __restrict__ cursor, int* __restrict__ ssrc) {
    int e = blockIdx.x * blockDim.x + threadIdx.x;
    if (e >= N_EDGES) return;
    int is64 = *flag;
    int s = load_edge(ei, e, 0, is64);
    int d = load_edge(ei, e, 1, is64);
    int pos = atomicAdd(&cursor[d], 1);
    ssrc[pos] = s;
}

// ===========================================================================
// FULL (bf16-direct) path kernels
// ===========================================================================

// x (fp32) -> xb (bf16), N*128 elems
__global__ void convert_xb_kernel(const float* __restrict__ x, u16* __restrict__ xb) {
    const int n4 = N_NODES * D_IN / 4;
    int i = blockIdx.x * 256 + threadIdx.x;
    if (i >= n4) return;
    float4 v = ((const float4*)x)[i];
    ushort4 o;
    o.x = f2bf_u(v.x); o.y = f2bf_u(v.y); o.z = f2bf_u(v.z); o.w = f2bf_u(v.w);
    ((ushort4*)xb)[i] = o;
}

// all weights -> bf16, k-blocked layout: WT[kb][col][32] (kb = k/32).
// WT3 = [W3_l | W3_r | 0pad] (128 cols x 256 k)
__global__ void build_wt_kernel(const float* __restrict__ W1l, const float* __restrict__ W1r,
                                const float* __restrict__ W2l, const float* __restrict__ W2r,
                                const float* __restrict__ W3l, const float* __restrict__ W3r,
                                u16* __restrict__ wt1l, u16* __restrict__ wt1r,
                                u16* __restrict__ wt2l, u16* __restrict__ wt2r,
                                u16* __restrict__ wt3) {
    int idx = blockIdx.x * 256 + threadIdx.x;
    if (idx < 65536) {                       // WT1l / WT1r : NC=256, K=128
        int seg = idx >> 15, d = idx & 32767;
        int kb = d >> 13, col = (d >> 5) & 255, kq = d & 31;
        int k = kb * 32 + kq;
        const float* W = seg ? W1r : W1l;
        u16* WT = seg ? wt1r : wt1l;
        WT[d] = f2bf_u(W[k * 256 + col]);
    } else if (idx < 196608) {               // WT2l / WT2r : NC=256, K=256
        int d = idx - 65536;
        int seg = d >> 16; d &= 65535;
        int kb = d >> 13, col = (d >> 5) & 255, kq = d & 31;
        int k = kb * 32 + kq;
        const float* W = seg ? W2r : W2l;
        u16* WT = seg ? wt2r : wt2l;
        WT[d] = f2bf_u(W[k * 256 + col]);
    } else if (idx < 229376) {               // WT3 : NC=128, K=256, zero-padded
        int d = idx - 196608;
        int kb = d >> 12, col = (d >> 5) & 127, kq = d & 31;
        int k = kb * 32 + kq;
        float v = 0.f;
        if (col < 47)      v = W3l[k * 47 + col];
        else if (col < 94) v = W3r[k * 47 + (col - 47)];
        wt3[d] = f2bf_u(v);
    }
}

// CSR gather-mean over bf16 rows: one wave per node
template <int CC>
__global__ __launch_bounds__(256) void gather_mean_bf(
    const u16* __restrict__ Xb, const int* __restrict__ rp,
    const int* __restrict__ ssrc, const float* __restrict__ invd,
    u16* __restrict__ agg)
{
    const int w = (blockIdx.x * 256 + threadIdx.x) >> 6;
    const int lane = threadIdx.x & 63;
    if (w >= N_NODES) return;
    const int start = rp[w], end = rp[w + 1];
    const float sc = invd[w];

    if constexpr (CC == 256) {
        const u16* base = Xb + lane * 4;
        float4 a = make_float4(0.f, 0.f, 0.f, 0.f);
        int e = start;
        for (; e + 1 < end; e += 2) {
            const ushort4 v0 = *(const ushort4*)(base + (size_t)ssrc[e] * 256);
            const ushort4 v1 = *(const ushort4*)(base + (size_t)ssrc[e + 1] * 256);
            a.x += bf2f(v0.x) + bf2f(v1.x); a.y += bf2f(v0.y) + bf2f(v1.y);
            a.z += bf2f(v0.z) + bf2f(v1.z); a.w += bf2f(v0.w) + bf2f(v1.w);
        }
        if (e < end) {
            const ushort4 v = *(const ushort4*)(base + (size_t)ssrc[e] * 256);
            a.x += bf2f(v.x); a.y += bf2f(v.y); a.z += bf2f(v.z); a.w += bf2f(v.w);
        }
        ushort4 o;
        o.x = f2bf_u(a.x * sc); o.y = f2bf_u(a.y * sc);
        o.z = f2bf_u(a.z * sc); o.w = f2bf_u(a.w * sc);
        *(ushort4*)(agg + (size_t)w * 256 + lane * 4) = o;
    } else {  // CC == 128
        const u16* base = Xb + lane * 2;
        float2 a = make_float2(0.f, 0.f);
        int e = start;
        for (; e + 1 < end; e += 2) {
            const ushort2 v0 = *(const ushort2*)(base + (size_t)ssrc[e] * 128);
            const ushort2 v1 = *(const ushort2*)(base + (size_t)ssrc[e + 1] * 128);
            a.x += bf2f(v0.x) + bf2f(v1.x); a.y += bf2f(v0.y) + bf2f(v1.y);
        }
        if (e < end) {
            const ushort2 v = *(const ushort2*)(base + (size_t)ssrc[e] * 128);
            a.x += bf2f(v.x); a.y += bf2f(v.y);
        }
        ushort2 o;
        o.x = f2bf_u(a.x * sc); o.y = f2bf_u(a.y * sc);
        *(ushort2*)(agg + (size_t)w * 128 + lane * 2) = o;
    }
}

// ---------------------------------------------------------------------------
// LDS-staged bf16 MFMA GEMM, 2-phase double-buffered via global_load_lds (T3).
//   * Tile 128 rows x 128 cols, 4 waves (wave = 32 rows x 128 cols, 16 MFMA/K-step)
//   * Per K-step (BK=32): stage NEXT A-tile (8KB) + B-tile (8KB) with
//     global_load_lds width=16 (async DMA hipcc cannot sink), compute CURRENT
//     buffer (ds_read_b128 + MFMA), one __syncthreads (implicit vmcnt(0) drain).
//     Stage latency hides under the whole compute phase.
//   * Bank-conflict fix via PRE-SWIZZLED GLOBAL SOURCE (rule #21: gload_lds
//     writes linearly): LDS[idx][c] = global[idx][c ^ ((idx>>1)&3)], read back
//     with the same XOR -> 2 lanes/bank (free) instead of 8-way.
// K compile-time: NK0+NK1 k-blocks of 32. A row-major bf16 [N][K].
// WT k-blocked [kb][col][32]. split>0: col<split -> C; split<=col<2s -> C2+bias.
// ---------------------------------------------------------------------------
template <int NK0, int NK1, int NC>
__global__ __launch_bounds__(256, 2) void mfma_lds(
    const u16* __restrict__ A0, const u16* __restrict__ WT0,
    const u16* __restrict__ A1, const u16* __restrict__ WT1,
    const float* __restrict__ bias,
    const float* __restrict__ gamma, const float* __restrict__ beta,
    const float* __restrict__ mean, const float* __restrict__ var,
    float* __restrict__ C, int M, int do_bias, int bn_relu,
    u16* __restrict__ Cb, float* __restrict__ C2, int split)
{
    __shared__ __align__(16) char lds[32768];   // A dbuf @0/8192, B dbuf @16384/24576

    const int t = threadIdx.x;
    const int wv = t >> 6, lane = t & 63;
    const int lr = lane & 15, quad = lane >> 4;
    const int row0 = blockIdx.y * 128;
    const int col0 = blockIdx.x * 128;
    constexpr int NKT = NK0 + NK1;

    // ---- per-thread stage constants (2 slots of 16B per operand per K-step)
    int sIdx[2], sCs[2];
#pragma unroll
    for (int i = 0; i < 2; ++i) {
        int slot = i * 256 + t;            // 0..511
        sIdx[i] = slot >> 2;               // 0..127 (row for A / col for B)
        int c = slot & 3;
        sCs[i] = c ^ ((sIdx[i] >> 1) & 3); // source-side pre-swizzle
    }
    int srowA[2];
#pragma unroll
    for (int i = 0; i < 2; ++i) {
        int r = row0 + sIdx[i];
        srowA[i] = (r < N_NODES) ? r : (N_NODES - 1);   // clamp (garbage rows unused)
    }

    // ---- ds_read byte offsets within an 8KB tile (swizzled chunk)
    int offA[2], offB[8];
#pragma unroll
    for (int r = 0; r < 2; ++r) {
        int idx = wv * 32 + r * 16 + lr;
        offA[r] = idx * 64 + ((quad ^ ((idx >> 1) & 3)) * 16);
    }
#pragma unroll
    for (int c = 0; c < 8; ++c) {
        int idx = c * 16 + lr;
        offB[c] = idx * 64 + ((quad ^ ((idx >> 1) & 3)) * 16);
    }

    floatx4 acc[2][8];
#pragma unroll
    for (int r = 0; r < 2; ++r)
#pragma unroll
        for (int c = 0; c < 8; ++c) acc[r][c] = (floatx4){0.f, 0.f, 0.f, 0.f};

    // ---- stage k-step ks into buffer 'cur'
    auto stage = [&](int ks, int cur) {
        const char* Ab; const char* Wb; int kb; size_t Kb;  // Kb = row stride bytes
        if (ks < NK0) { Ab = (const char*)A0; Wb = (const char*)WT0; kb = ks;       Kb = (size_t)NK0 * 64; }
        else          { Ab = (const char*)A1; Wb = (const char*)WT1; kb = ks - NK0; Kb = (size_t)NK1 * 64; }
#pragma unroll
        for (int i = 0; i < 2; ++i) {
            const char* srcA = Ab + (size_t)srowA[i] * Kb + (size_t)kb * 64 + sCs[i] * 16;
            load_lds16(srcA, lds + cur * 8192 + (i * 256 + t) * 16);
            const char* srcB = Wb + ((size_t)kb * NC + col0 + sIdx[i]) * 64 + sCs[i] * 16;
            load_lds16(srcB, lds + 16384 + cur * 8192 + (i * 256 + t) * 16);
        }
    };

    // ---- compute current buffer: 2 A-frags + 8 B-frags + 16 MFMA
    auto compute = [&](int cur) {
        const char* la = lds + cur * 8192;
        const char* lb = lds + 16384 + cur * 8192;
        bf16x8 a[2], b[8];
#pragma unroll
        for (int r = 0; r < 2; ++r) a[r] = *(const bf16x8*)(la + offA[r]);
#pragma unroll
        for (int c = 0; c < 8; ++c) b[c] = *(const bf16x8*)(lb + offB[c]);
#pragma unroll
        for (int c = 0; c < 8; ++c) {
            acc[0][c] = __builtin_amdgcn_mfma_f32_16x16x32_bf16(a[0], b[c], acc[0][c], 0, 0, 0);
            acc[1][c] = __builtin_amdgcn_mfma_f32_16x16x32_bf16(a[1], b[c], acc[1][c], 0, 0, 0);
        }
    };

    // ---- 2-phase main loop
    stage(0, 0);
    __syncthreads();                 // drain prologue stage
    int cur = 0;
#pragma unroll
    for (int ks = 0; ks < NKT - 1; ++ks) {
        stage(ks + 1, cur ^ 1);      // async loads fly under compute
        compute(cur);
        __syncthreads();             // implicit vmcnt(0)+lgkmcnt(0): next buf ready
        cur ^= 1;
    }
    compute(cur);

    // ---- epilogue (C/D: col=lr, row=quad*4+g) — proven round-0 mapping
#pragma unroll
    for (int r = 0; r < 2; ++r) {
#pragma unroll
        for (int g = 0; g < 4; ++g) {
            const int row = row0 + wv * 32 + r * 16 + quad * 4 + g;
            if (row >= N_NODES) continue;
#pragma unroll
            for (int c = 0; c < 8; ++c) {
                const int col = col0 + c * 16 + lr;
                float v = acc[r][c][g];
                if (split > 0) {
                    if (col < split) {
                        C[(size_t)row * split + col] = v;
                    } else if (col < 2 * split) {
                        C2[(size_t)row * split + (col - split)] = v + bias[col - split];
                    }
                } else {
                    if (col >= M) continue;
                    if (do_bias) v += bias[col];
                    if (bn_relu) {
                        v = (v - mean[col]) * (gamma[col] * rsqrtf(var[col] + BN_EPS)) + beta[col];
                        v = fmaxf(v, 0.0f);
                    }
                    const size_t off = (size_t)row * M + col;
                    C[off] = v;
                    if (Cb) Cb[off] = f2bf_u(v);
                }
            }
        }
    }
}

// ===========================================================================
// SAFE path kernels (R5, proven)
// ===========================================================================
template <int CC>
__global__ __launch_bounds__(256) void gather_mean(
    const float* __restrict__ X, int ldx,
    const int* __restrict__ rp, const int* __restrict__ ssrc,
    const float* __restrict__ invd, float* __restrict__ agg)
{
    const long long gid = (long long)blockIdx.x * blockDim.x + threadIdx.x;
    const int w = (int)(gid >> 6);
    const int lane = threadIdx.x & 63;
    if (w >= N_NODES) return;
    const int start = rp[w], end = rp[w + 1];
    const float sc = invd[w];

    if constexpr (CC == 256) {
        const float* base = X + lane * 4;
        float4 a = make_float4(0.f, 0.f, 0.f, 0.f);
        int e = start;
        for (; e + 1 < end; e += 2) {
            int s0 = ssrc[e], s1 = ssrc[e + 1];
            float4 v0 = *(const float4*)(base + (long long)s0 * ldx);
            float4 v1 = *(const float4*)(base + (long long)s1 * ldx);
            a.x += v0.x + v1.x; a.y += v0.y + v1.y;
            a.z += v0.z + v1.z; a.w += v0.w + v1.w;
        }
        if (e < end) {
            float4 v = *(const float4*)(base + (long long)ssrc[e] * ldx);
            a.x += v.x; a.y += v.y; a.z += v.z; a.w += v.w;
        }
        float4 o = make_float4(a.x * sc, a.y * sc, a.z * sc, a.w * sc);
        *(float4*)(agg + (long long)w * 256 + lane * 4) = o;
    } else {
        const float* base = X + lane * 2;
        float2 a = make_float2(0.f, 0.f);
        int e = start;
        for (; e + 1 < end; e += 2) {
            int s0 = ssrc[e], s1 = ssrc[e + 1];
            float2 v0 = *(const float2*)(base + (long long)s0 * ldx);
            float2 v1 = *(const float2*)(base + (long long)s1 * ldx);
            a.x += v0.x + v1.x; a.y += v0.y + v1.y;
        }
        if (e < end) {
            float2 v = *(const float2*)(base + (long long)ssrc[e] * ldx);
            a.x += v.x; a.y += v.y;
        }
        float2 o = make_float2(a.x * sc, a.y * sc);
        *(float2*)(agg + (long long)w * 128 + lane * 2) = o;
    }
}

#define GBM 128
#define GBN 64
#define GBK 32
#define LDA 40
#define LDB 40

__global__ __launch_bounds__(256) void mfma_gemm(
    const float* __restrict__ A0, const float* __restrict__ B0, int K0,
    const float* __restrict__ A1, const float* __restrict__ B1, int K1,
    const float* __restrict__ bias,
    const float* __restrict__ gamma, const float* __restrict__ beta,
    const float* __restrict__ mean, const float* __restrict__ var,
    float* __restrict__ C, int M, int do_bias, int bn_relu)
{
    __shared__ short As[GBM * LDA];
    __shared__ short Bs[GBN * LDB];

    const int t = threadIdx.x;
    const int wv = t >> 6;
    const int lane = t & 63;
    const int row0 = blockIdx.y * GBM;
    const int col0 = blockIdx.x * GBN;

    const int lr = lane & 15;
    const int lk = (lane >> 4) * 8;

    floatx4 acc[2][4];
#pragma unroll
    for (int r = 0; r < 2; ++r)
#pragma unroll
        for (int c = 0; c < 4; ++c) acc[r][c] = (floatx4){0.f, 0.f, 0.f, 0.f};

    const int arow = t >> 3;
    const int akc  = (t & 7) * 4;
    const int bkr  = t >> 4;
    const int bcc  = (t & 15) * 4;

    for (int pass = 0; pass < 2; ++pass) {
        if (pass == 1 && A1 == nullptr) break;
        const float* __restrict__ A = pass ? A1 : A0;
        const float* __restrict__ B = pass ? B1 : B0;
        const int K = pass ? K1 : K0;

        for (int k0 = 0; k0 < K; k0 += GBK) {
            __syncthreads();
#pragma unroll
            for (int i = 0; i < 4; ++i) {
                const int lrow = arow + i * 32;
                const int grow = row0 + lrow;
                float4 v = make_float4(0.f, 0.f, 0.f, 0.f);
                if (grow < N_NODES)
                    v = *(const float4*)(A + (long long)grow * K + k0 + akc);
                short4 sv;
                sv.x = f2bf(v.x); sv.y = f2bf(v.y);
                sv.z = f2bf(v.z); sv.w = f2bf(v.w);
                *(short4*)(&As[lrow * LDA + akc]) = sv;
            }
#pragma unroll
            for (int i = 0; i < 2; ++i) {
                const int k = bkr + i * 16;
                const int gc = col0 + bcc;
                float4 v;
                if (gc + 3 < M) {
                    v = *(const float4*)(B + (long long)(k0 + k) * M + gc);
                } else {
                    v.x = (gc + 0 < M) ? B[(long long)(k0 + k) * M + gc + 0] : 0.f;
                    v.y = (gc + 1 < M) ? B[(long long)(k0 + k) * M + gc + 1] : 0.f;
                    v.z = (gc + 2 < M) ? B[(long long)(k0 + k) * M + gc + 2] : 0.f;
                    v.w = (gc + 3 < M) ? B[(long long)(k0 + k) * M + gc + 3] : 0.f;
                }
                Bs[(bcc + 0) * LDB + k] = f2bf(v.x);
                Bs[(bcc + 1) * LDB + k] = f2bf(v.y);
                Bs[(bcc + 2) * LDB + k] = f2bf(v.z);
                Bs[(bcc + 3) * LDB + k] = f2bf(v.w);
            }
            __syncthreads();

            bf16x8 af[2], bfr[4];
#pragma unroll
            for (int r = 0; r < 2; ++r)
                af[r] = *(const bf16x8*)(&As[(wv * 32 + r * 16 + lr) * LDA + lk]);
#pragma unroll
            for (int c = 0; c < 4; ++c)
                bfr[c] = *(const bf16x8*)(&Bs[(c * 16 + lr) * LDB + lk]);
#pragma unroll
            for (int r = 0; r < 2; ++r)
#pragma unroll
                for (int c = 0; c < 4; ++c)
                    acc[r][c] = __builtin_amdgcn_mfma_f32_16x16x32_bf16(
                        af[r], bfr[c], acc[r][c], 0, 0, 0);
        }
    }

#pragma unroll
    for (int r = 0; r < 2; ++r) {
#pragma unroll
        for (int g = 0; g < 4; ++g) {
            const int row = row0 + wv * 32 + r * 16 + (lane >> 4) * 4 + g;
            if (row >= N_NODES) continue;
#pragma unroll
            for (int c = 0; c < 4; ++c) {
                const int col = col0 + c * 16 + lr;
                if (col >= M) continue;
                float v = acc[r][c][g];
                if (do_bias) v += bias[col];
                if (bn_relu) {
                    v = (v - mean[col]) * (gamma[col] * rsqrtf(var[col] + BN_EPS)) + beta[col];
                    v = fmaxf(v, 0.0f);
                }
                C[(long long)row * M + col] = v;
            }
        }
    }
}

// ---------------------------------------------------------------------------
// shared epilogue kernels
// ---------------------------------------------------------------------------
__global__ __launch_bounds__(256) void gather_add_out(
    const float* __restrict__ U, const int* __restrict__ rp,
    const int* __restrict__ ssrc, const float* __restrict__ invd,
    float* __restrict__ z)
{
    const int w = (blockIdx.x * 256 + threadIdx.x) >> 6;
    const int lane = threadIdx.x & 63;
    if (w >= N_NODES) return;
    const int start = rp[w], end = rp[w + 1];
    float a = 0.f;
    for (int e = start; e < end; ++e) {
        int s = ssrc[e];
        if (lane < D_OUT) a += U[(long long)s * D_OUT + lane];
    }
    if (lane < D_OUT) z[(long long)w * D_OUT + lane] += a * invd[w];
}

__global__ void log_softmax_kernel(const float* __restrict__ z, float* __restrict__ y) {
    const int gtid = blockIdx.x * blockDim.x + threadIdx.x;
    const int row = gtid >> 6;
    const int lane = threadIdx.x & 63;
    if (row >= N_NODES) return;

    const float* zr = z + (long long)row * D_OUT;
    float v = (lane < D_OUT) ? zr[lane] : -INFINITY;

    float m = v;
#pragma unroll
    for (int off = 32; off > 0; off >>= 1) m = fmaxf(m, __shfl_down(m, off));
    m = __shfl(m, 0);

    float ev = (lane < D_OUT) ? expf(v - m) : 0.0f;
    float s = ev;
#pragma unroll
    for (int off = 32; off > 0; off >>= 1) s += __shfl_down(s, off);
    s = __shfl(s, 0);

    if (lane < D_OUT) y[(long long)row * D_OUT + lane] = v - m - logf(s);
}

// ---------------------------------------------------------------------------
// launch
// ---------------------------------------------------------------------------
extern "C" void kernel_launch(void* const* d_in, const int* in_sizes, int n_in,
                              void* d_out, int out_size, void* d_ws, size_t ws_size,
                              hipStream_t stream) {
    const float* x     = (const float*)d_in[0];
    const int*   ei    = (const int*)d_in[1];
    const float* W1_l  = (const float*)d_in[2];
    const float* b1    = (const float*)d_in[3];
    const float* W1_r  = (const float*)d_in[4];
    const float* bn1_g = (const float*)d_in[5];
    const float* bn1_b = (const float*)d_in[6];
    const float* bn1_m = (const float*)d_in[7];
    const float* bn1_v = (const float*)d_in[8];
    const float* W2_l  = (const float*)d_in[9];
    const float* b2    = (const float*)d_in[10];
    const float* W2_r  = (const float*)d_in[11];
    const float* bn2_g = (const float*)d_in[12];
    const float* bn2_b = (const float*)d_in[13];
    const float* bn2_m = (const float*)d_in[14];
    const float* bn2_v = (const float*)d_in[15];
    const float* W3_l  = (const float*)d_in[16];
    const float* b3    = (const float*)d_in[17];
    const float* W3_r  = (const float*)d_in[18];

    // --- common workspace (CSR) ---
    char* ws = (char*)d_ws;
    int*   degi    = (int*)(ws + 0);
    int*   row_ptr = (int*)(ws + 200064);
    int*   cursor  = (int*)(ws + 400128);
    float* invd    = (float*)(ws + 600192);
    int*   flag    = (int*)(ws + 800256);
    int*   bsum    = (int*)(ws + 800320);
    int*   ssrc    = (int*)(ws + 801152);          // 3.2 MB -> ends 4,001,152

    // d_out layout: z [N*47] | y_pred [N*47] | S1 [N*256] | S2 [N*256]
    float* z     = (float*)d_out;
    float* ypred = z + (long long)N_NODES * D_OUT;
    float* S1    = ypred + (long long)N_NODES * D_OUT;
    float* S2    = S1 + (long long)N_NODES * D_HID;

    // --- CSR build (shared) ---
    detect_idx_kernel<<<1, 256, 0, stream>>>(ei, flag);
    hipMemsetAsync(degi, 0, N_NODES * sizeof(int), stream);
    count_deg_kernel<<<(N_EDGES + 255) / 256, 256, 0, stream>>>(ei, flag, degi);
    block_sum_kernel<<<SCAN_NBLK, 256, 0, stream>>>(degi, bsum);
    scan_bsums_kernel<<<1, 256, 0, stream>>>(bsum, row_ptr);
    fill_rowptr_kernel<<<SCAN_NBLK, 256, 0, stream>>>(degi, bsum, row_ptr, cursor, invd);
    fill_csr_kernel<<<(N_EDGES + 255) / 256, 256, 0, stream>>>(ei, flag, cursor, ssrc);

    const int gblocks = (N_NODES * 64 + 255) / 256;

    // FULL bf16-direct plan needs 94,059,904 B of ws
    if (ws_size >= 94059904ULL) {
        u16*   wt1l = (u16*)(ws + 4001152);
        u16*   wt1r = (u16*)(ws + 4066688);
        u16*   wt2l = (u16*)(ws + 4132224);
        u16*   wt2r = (u16*)(ws + 4263296);
        u16*   wt3  = (u16*)(ws + 4394368);
        u16*   xb   = (u16*)(ws + 4459904);        // N*128 bf16
        u16*   S1b  = (u16*)(ws + 17259904);       // N*256 bf16
        u16*   S2b  = (u16*)(ws + 42859904);       // N*256 bf16
        u16*   agg  = (u16*)(ws + 68459904);       // N*256 bf16 (reused as U fp32)
        float* U    = (float*)agg;

        convert_xb_kernel<<<(N_NODES * D_IN / 4 + 255) / 256, 256, 0, stream>>>(x, xb);
        build_wt_kernel<<<(229376 + 255) / 256, 256, 0, stream>>>(
            W1_l, W1_r, W2_l, W2_r, W3_l, W3_r, wt1l, wt1r, wt2l, wt2r, wt3);

        const dim3 gHid(2, (N_NODES + 127) / 128);   // M=256, 128x128 blocks
        const dim3 gOut(1, (N_NODES + 127) / 128);   // M=94 (padded 128)

        // layer 1 (K=128 x2 passes, NKT=8)
        gather_mean_bf<128><<<gblocks, 256, 0, stream>>>(xb, row_ptr, ssrc, invd, agg);
        mfma_lds<4, 4, 256><<<gHid, 256, 0, stream>>>(
            agg, wt1l, xb, wt1r,
            b1, bn1_g, bn1_b, bn1_m, bn1_v,
            S1, D_HID, 1, 1, S1b, nullptr, 0);
        // layer 2 (K=256 x2 passes, NKT=16)
        gather_mean_bf<256><<<gblocks, 256, 0, stream>>>(S1b, row_ptr, ssrc, invd, agg);
        mfma_lds<8, 8, 256><<<gHid, 256, 0, stream>>>(
            agg, wt2l, S1b, wt2r,
            b2, bn2_g, bn2_b, bn2_m, bn2_v,
            S2, D_HID, 1, 1, S2b, nullptr, 0);
        // layer 3 (fused transform-first: U = S2@W3_l, z = S2@W3_r + b3)
        mfma_lds<8, 0, 128><<<gOut, 256, 0, stream>>>(
            S2b, wt3, nullptr, nullptr,
            b3, nullptr, nullptr, nullptr, nullptr,
            U, 94, 0, 0, nullptr, z, D_OUT);
        gather_add_out<<<gblocks, 256, 0, stream>>>(U, row_ptr, ssrc, invd, z);
    } else {
        // SAFE: R5 fp32-LDS pipeline (proven <= 55.2 MB)
        float* aggF = (float*)(ws + 4001152);      // N*256 fp32, ends 55,201,152
        float* U    = aggF;

        const dim3 gHid(D_HID / GBN, (N_NODES + GBM - 1) / GBM);
        const dim3 gOut(1, (N_NODES + GBM - 1) / GBM);

        gather_mean<128><<<gblocks, 256, 0, stream>>>(x, D_IN, row_ptr, ssrc, invd, aggF);
        mfma_gemm<<<gHid, 256, 0, stream>>>(aggF, W1_l, D_IN, x, W1_r, D_IN,
                                            b1, bn1_g, bn1_b, bn1_m, bn1_v,
                                            S1, D_HID, 1, 1);
        gather_mean<256><<<gblocks, 256, 0, stream>>>(S1, D_HID, row_ptr, ssrc, invd, aggF);
        mfma_gemm<<<gHid, 256, 0, stream>>>(aggF, W2_l, D_HID, S1, W2_r, D_HID,
                                            b2, bn2_g, bn2_b, bn2_m, bn2_v,
                                            S2, D_HID, 1, 1);
        mfma_gemm<<<gOut, 256, 0, stream>>>(S2, W3_l, D_HID, nullptr, nullptr, 0,
                                            nullptr, nullptr, nullptr, nullptr, nullptr,
                                            U, D_OUT, 0, 0);
        mfma_gemm<<<gOut, 256, 0, stream>>>(S2, W3_r, D_HID, nullptr, nullptr, 0,
                                            b3, nullptr, nullptr, nullptr, nullptr,
                                            z, D_OUT, 1, 0);
        gather_add_out<<<gblocks, 256, 0, stream>>>(U, row_ptr, ssrc, invd, z);
    }

    log_softmax_kernel<<<gblocks, 256, 0, stream>>>(z, ypred);
}

// Round 6
// 544.175 us; speedup vs baseline: 1.2369x; 1.1319x over previous
//
#include <hip/hip_runtime.h>
#include <cmath>

#define N_NODES 50000
#define N_EDGES 800000
#define D_IN    128
#define D_HID   256
#define D_OUT   47
#define BN_EPS  1e-5f
#define SCAN_NBLK ((N_NODES + 255) / 256)   // 196

typedef __attribute__((ext_vector_type(8))) short bf16x8;
typedef __attribute__((ext_vector_type(4))) float floatx4;
typedef unsigned short u16;
typedef unsigned int u32;

__device__ __forceinline__ short f2bf(float f) {          // legacy (short)
    unsigned u = __float_as_uint(f);
    u += 0x7fff + ((u >> 16) & 1);
    return (short)(u >> 16);
}
__device__ __forceinline__ u16 f2bf_u(float f) {
    unsigned u = __float_as_uint(f);
    u += 0x7fff + ((u >> 16) & 1);
    return (u16)(u >> 16);
}
__device__ __forceinline__ float bf2f(u16 h) {
    return __uint_as_float(((unsigned)h) << 16);
}

// async 16B global->LDS DMA (the op hipcc cannot sink; waited at barrier)
__device__ __forceinline__ void load_lds16(const void* g, void* l) {
    __builtin_amdgcn_global_load_lds(
        (const __attribute__((address_space(1))) u32*)g,
        (__attribute__((address_space(3))) u32*)l,
        16, 0, 0);
}

// ---------------------------------------------------------------------------
// edge_index layout detection (int64 vs int32)
// ---------------------------------------------------------------------------
__global__ void detect_idx_kernel(const int* __restrict__ ei, int* __restrict__ flag) {
    __shared__ int any_nonzero;
    if (threadIdx.x == 0) any_nonzero = 0;
    __syncthreads();
    int v = ei[2 * threadIdx.x + 1];
    if (v != 0) atomicAdd(&any_nonzero, 1);
    __syncthreads();
    if (threadIdx.x == 0) *flag = (any_nonzero == 0) ? 1 : 0;
}

__device__ __forceinline__ int load_edge(const int* __restrict__ ei, int e, int which, int is64) {
    if (is64) return ei[2 * ((long long)which * N_EDGES + e)];
    return ei[(long long)which * N_EDGES + e];
}

// ---------------------------------------------------------------------------
// CSR build
// ---------------------------------------------------------------------------
__global__ void count_deg_kernel(const int* __restrict__ ei, const int* __restrict__ flag,
                                 int* __restrict__ degi) {
    int e = blockIdx.x * blockDim.x + threadIdx.x;
    if (e >= N_EDGES) return;
    int is64 = *flag;
    atomicAdd(&degi[load_edge(ei, e, 1, is64)], 1);
}

__global__ __launch_bounds__(256) void block_sum_kernel(const int* __restrict__ degi,
                                                        int* __restrict__ bsum) {
    const int i = blockIdx.x * 256 + threadIdx.x;
    int v = (i < N_NODES) ? degi[i] : 0;
#pragma unroll
    for (int off = 32; off > 0; off >>= 1) v += __shfl_down(v, off);
    __shared__ int sh[4];
    if ((threadIdx.x & 63) == 0) sh[threadIdx.x >> 6] = v;
    __syncthreads();
    if (threadIdx.x == 0) bsum[blockIdx.x] = sh[0] + sh[1] + sh[2] + sh[3];
}

__global__ __launch_bounds__(256) void scan_bsums_kernel(int* __restrict__ bsum,
                                                         int* __restrict__ row_ptr) {
    const int t = threadIdx.x;
    __shared__ int sh[256];
    int v = (t < SCAN_NBLK) ? bsum[t] : 0;
    sh[t] = v;
    __syncthreads();
#pragma unroll
    for (int off = 1; off < 256; off <<= 1) {
        int u = (t >= off) ? sh[t - off] : 0;
        __syncthreads();
        sh[t] += u;
        __syncthreads();
    }
    if (t < SCAN_NBLK) bsum[t] = sh[t] - v;
    if (t == 255) row_ptr[N_NODES] = sh[255];
}

__global__ __launch_bounds__(256) void fill_rowptr_kernel(const int* __restrict__ degi,
                                                          const int* __restrict__ bsum,
                                                          int* __restrict__ row_ptr,
                                                          int* __restrict__ cursor,
                                                          float* __restrict__ invd) {
    const int t = threadIdx.x;
    const int i = blockIdx.x * 256 + t;
    __shared__ int sh[256];
    int d = (i < N_NODES) ? degi[i] : 0;
    sh[t] = d;
    __syncthreads();
#pragma unroll
    for (int off = 1; off < 256; off <<= 1) {
        int u = (t >= off) ? sh[t - off] : 0;
        __syncthreads();
        sh[t] += u;
        __syncthreads();
    }
    if (i < N_NODES) {
        const int pos = bsum[blockIdx.x] + sh[t] - d;
        row_ptr[i] = pos;
        cursor[i]  = pos;
        invd[i]    = 1.0f / fmaxf((float)d, 1.0f);
    }
}

__global__ void fill_csr_kernel(const int* __restrict__ ei, const int* __restrict__ flag,
                                int* __restrict__ cursor, int* __restrict__ ssrc) {
    int e = blockIdx.x * blockDim.x + threadIdx.x;
    if (e >= N_EDGES) return;
    int is64 = *flag;
    int s = load_edge(ei, e, 0, is64);
    int d = load_edge(ei, e, 1, is64);
    int pos = atomicAdd(&cursor[d], 1);
    ssrc[pos] = s;
}

// ===========================================================================
// FULL (bf16-direct) path kernels
// ===========================================================================

// x (fp32) -> xb (bf16), N*128 elems
__global__ void convert_xb_kernel(const float* __restrict__ x, u16* __restrict__ xb) {
    const int n4 = N_NODES * D_IN / 4;
    int i = blockIdx.x * 256 + threadIdx.x;
    if (i >= n4) return;
    float4 v = ((const float4*)x)[i];
    ushort4 o;
    o.x = f2bf_u(v.x); o.y = f2bf_u(v.y); o.z = f2bf_u(v.z); o.w = f2bf_u(v.w);
    ((ushort4*)xb)[i] = o;
}

// all weights -> bf16, k-blocked layout: WT[kb][col][32] (kb = k/32).
// WT3 = [W3_l | W3_r | 0pad] (128 cols x 256 k)
__global__ void build_wt_kernel(const float* __restrict__ W1l, const float* __restrict__ W1r,
                                const float* __restrict__ W2l, const float* __restrict__ W2r,
                                const float* __restrict__ W3l, const float* __restrict__ W3r,
                                u16* __restrict__ wt1l, u16* __restrict__ wt1r,
                                u16* __restrict__ wt2l, u16* __restrict__ wt2r,
                                u16* __restrict__ wt3) {
    int idx = blockIdx.x * 256 + threadIdx.x;
    if (idx < 65536) {                       // WT1l / WT1r : NC=256, K=128
        int seg = idx >> 15, d = idx & 32767;
        int kb = d >> 13, col = (d >> 5) & 255, kq = d & 31;
        int k = kb * 32 + kq;
        const float* W = seg ? W1r : W1l;
        u16* WT = seg ? wt1r : wt1l;
        WT[d] = f2bf_u(W[k * 256 + col]);
    } else if (idx < 196608) {               // WT2l / WT2r : NC=256, K=256
        int d = idx - 65536;
        int seg = d >> 16; d &= 65535;
        int kb = d >> 13, col = (d >> 5) & 255, kq = d & 31;
        int k = kb * 32 + kq;
        const float* W = seg ? W2r : W2l;
        u16* WT = seg ? wt2r : wt2l;
        WT[d] = f2bf_u(W[k * 256 + col]);
    } else if (idx < 229376) {               // WT3 : NC=128, K=256, zero-padded
        int d = idx - 196608;
        int kb = d >> 12, col = (d >> 5) & 127, kq = d & 31;
        int k = kb * 32 + kq;
        float v = 0.f;
        if (col < 47)      v = W3l[k * 47 + col];
        else if (col < 94) v = W3r[k * 47 + (col - 47)];
        wt3[d] = f2bf_u(v);
    }
}

// CSR gather-mean over bf16 rows: one wave per node.
// 4-way edge unroll: 4 independent row-loads in flight per wave (latency hiding).
template <int CC>
__global__ __launch_bounds__(256) void gather_mean_bf(
    const u16* __restrict__ Xb, const int* __restrict__ rp,
    const int* __restrict__ ssrc, const float* __restrict__ invd,
    u16* __restrict__ agg)
{
    const int w = (blockIdx.x * 256 + threadIdx.x) >> 6;
    const int lane = threadIdx.x & 63;
    if (w >= N_NODES) return;
    const int start = rp[w], end = rp[w + 1];
    const float sc = invd[w];

    if constexpr (CC == 256) {
        const u16* base = Xb + lane * 4;
        float4 a = make_float4(0.f, 0.f, 0.f, 0.f);
        int e = start;
        for (; e + 3 < end; e += 4) {
            const ushort4 v0 = *(const ushort4*)(base + (size_t)ssrc[e] * 256);
            const ushort4 v1 = *(const ushort4*)(base + (size_t)ssrc[e + 1] * 256);
            const ushort4 v2 = *(const ushort4*)(base + (size_t)ssrc[e + 2] * 256);
            const ushort4 v3 = *(const ushort4*)(base + (size_t)ssrc[e + 3] * 256);
            a.x += (bf2f(v0.x) + bf2f(v1.x)) + (bf2f(v2.x) + bf2f(v3.x));
            a.y += (bf2f(v0.y) + bf2f(v1.y)) + (bf2f(v2.y) + bf2f(v3.y));
            a.z += (bf2f(v0.z) + bf2f(v1.z)) + (bf2f(v2.z) + bf2f(v3.z));
            a.w += (bf2f(v0.w) + bf2f(v1.w)) + (bf2f(v2.w) + bf2f(v3.w));
        }
        for (; e < end; ++e) {
            const ushort4 v = *(const ushort4*)(base + (size_t)ssrc[e] * 256);
            a.x += bf2f(v.x); a.y += bf2f(v.y); a.z += bf2f(v.z); a.w += bf2f(v.w);
        }
        ushort4 o;
        o.x = f2bf_u(a.x * sc); o.y = f2bf_u(a.y * sc);
        o.z = f2bf_u(a.z * sc); o.w = f2bf_u(a.w * sc);
        *(ushort4*)(agg + (size_t)w * 256 + lane * 4) = o;
    } else {  // CC == 128
        const u16* base = Xb + lane * 2;
        float2 a = make_float2(0.f, 0.f);
        int e = start;
        for (; e + 3 < end; e += 4) {
            const ushort2 v0 = *(const ushort2*)(base + (size_t)ssrc[e] * 128);
            const ushort2 v1 = *(const ushort2*)(base + (size_t)ssrc[e + 1] * 128);
            const ushort2 v2 = *(const ushort2*)(base + (size_t)ssrc[e + 2] * 128);
            const ushort2 v3 = *(const ushort2*)(base + (size_t)ssrc[e + 3] * 128);
            a.x += (bf2f(v0.x) + bf2f(v1.x)) + (bf2f(v2.x) + bf2f(v3.x));
            a.y += (bf2f(v0.y) + bf2f(v1.y)) + (bf2f(v2.y) + bf2f(v3.y));
        }
        for (; e < end; ++e) {
            const ushort2 v = *(const ushort2*)(base + (size_t)ssrc[e] * 128);
            a.x += bf2f(v.x); a.y += bf2f(v.y);
        }
        ushort2 o;
        o.x = f2bf_u(a.x * sc); o.y = f2bf_u(a.y * sc);
        *(ushort2*)(agg + (size_t)w * 128 + lane * 2) = o;
    }
}

// ---------------------------------------------------------------------------
// LDS-staged bf16 MFMA GEMM, 2-phase double-buffered via global_load_lds (T3).
// (unchanged from round 5 — proven, no longer top-5)
// ---------------------------------------------------------------------------
template <int NK0, int NK1, int NC>
__global__ __launch_bounds__(256, 2) void mfma_lds(
    const u16* __restrict__ A0, const u16* __restrict__ WT0,
    const u16* __restrict__ A1, const u16* __restrict__ WT1,
    const float* __restrict__ bias,
    const float* __restrict__ gamma, const float* __restrict__ beta,
    const float* __restrict__ mean, const float* __restrict__ var,
    float* __restrict__ C, int M, int do_bias, int bn_relu,
    u16* __restrict__ Cb, float* __restrict__ C2, int split)
{
    __shared__ __align__(16) char lds[32768];   // A dbuf @0/8192, B dbuf @16384/24576

    const int t = threadIdx.x;
    const int wv = t >> 6, lane = t & 63;
    const int lr = lane & 15, quad = lane >> 4;
    const int row0 = blockIdx.y * 128;
    const int col0 = blockIdx.x * 128;
    constexpr int NKT = NK0 + NK1;

    // ---- per-thread stage constants (2 slots of 16B per operand per K-step)
    int sIdx[2], sCs[2];
#pragma unroll
    for (int i = 0; i < 2; ++i) {
        int slot = i * 256 + t;            // 0..511
        sIdx[i] = slot >> 2;               // 0..127 (row for A / col for B)
        int c = slot & 3;
        sCs[i] = c ^ ((sIdx[i] >> 1) & 3); // source-side pre-swizzle
    }
    int srowA[2];
#pragma unroll
    for (int i = 0; i < 2; ++i) {
        int r = row0 + sIdx[i];
        srowA[i] = (r < N_NODES) ? r : (N_NODES - 1);   // clamp (garbage rows unused)
    }

    // ---- ds_read byte offsets within an 8KB tile (swizzled chunk)
    int offA[2], offB[8];
#pragma unroll
    for (int r = 0; r < 2; ++r) {
        int idx = wv * 32 + r * 16 + lr;
        offA[r] = idx * 64 + ((quad ^ ((idx >> 1) & 3)) * 16);
    }
#pragma unroll
    for (int c = 0; c < 8; ++c) {
        int idx = c * 16 + lr;
        offB[c] = idx * 64 + ((quad ^ ((idx >> 1) & 3)) * 16);
    }

    floatx4 acc[2][8];
#pragma unroll
    for (int r = 0; r < 2; ++r)
#pragma unroll
        for (int c = 0; c < 8; ++c) acc[r][c] = (floatx4){0.f, 0.f, 0.f, 0.f};

    // ---- stage k-step ks into buffer 'cur'
    auto stage = [&](int ks, int cur) {
        const char* Ab; const char* Wb; int kb; size_t Kb;  // Kb = row stride bytes
        if (ks < NK0) { Ab = (const char*)A0; Wb = (const char*)WT0; kb = ks;       Kb = (size_t)NK0 * 64; }
        else          { Ab = (const char*)A1; Wb = (const char*)WT1; kb = ks - NK0; Kb = (size_t)NK1 * 64; }
#pragma unroll
        for (int i = 0; i < 2; ++i) {
            const char* srcA = Ab + (size_t)srowA[i] * Kb + (size_t)kb * 64 + sCs[i] * 16;
            load_lds16(srcA, lds + cur * 8192 + (i * 256 + t) * 16);
            const char* srcB = Wb + ((size_t)kb * NC + col0 + sIdx[i]) * 64 + sCs[i] * 16;
            load_lds16(srcB, lds + 16384 + cur * 8192 + (i * 256 + t) * 16);
        }
    };

    // ---- compute current buffer: 2 A-frags + 8 B-frags + 16 MFMA
    auto compute = [&](int cur) {
        const char* la = lds + cur * 8192;
        const char* lb = lds + 16384 + cur * 8192;
        bf16x8 a[2], b[8];
#pragma unroll
        for (int r = 0; r < 2; ++r) a[r] = *(const bf16x8*)(la + offA[r]);
#pragma unroll
        for (int c = 0; c < 8; ++c) b[c] = *(const bf16x8*)(lb + offB[c]);
#pragma unroll
        for (int c = 0; c < 8; ++c) {
            acc[0][c] = __builtin_amdgcn_mfma_f32_16x16x32_bf16(a[0], b[c], acc[0][c], 0, 0, 0);
            acc[1][c] = __builtin_amdgcn_mfma_f32_16x16x32_bf16(a[1], b[c], acc[1][c], 0, 0, 0);
        }
    };

    // ---- 2-phase main loop
    stage(0, 0);
    __syncthreads();                 // drain prologue stage
    int cur = 0;
#pragma unroll
    for (int ks = 0; ks < NKT - 1; ++ks) {
        stage(ks + 1, cur ^ 1);      // async loads fly under compute
        compute(cur);
        __syncthreads();             // implicit vmcnt(0)+lgkmcnt(0): next buf ready
        cur ^= 1;
    }
    compute(cur);

    // ---- epilogue (C/D: col=lr, row=quad*4+g) — proven round-0 mapping
#pragma unroll
    for (int r = 0; r < 2; ++r) {
#pragma unroll
        for (int g = 0; g < 4; ++g) {
            const int row = row0 + wv * 32 + r * 16 + quad * 4 + g;
            if (row >= N_NODES) continue;
#pragma unroll
            for (int c = 0; c < 8; ++c) {
                const int col = col0 + c * 16 + lr;
                float v = acc[r][c][g];
                if (split > 0) {
                    if (col < split) {
                        C[(size_t)row * split + col] = v;
                    } else if (col < 2 * split) {
                        C2[(size_t)row * split + (col - split)] = v + bias[col - split];
                    }
                } else {
                    if (col >= M) continue;
                    if (do_bias) v += bias[col];
                    if (bn_relu) {
                        v = (v - mean[col]) * (gamma[col] * rsqrtf(var[col] + BN_EPS)) + beta[col];
                        v = fmaxf(v, 0.0f);
                    }
                    const size_t off = (size_t)row * M + col;
                    C[off] = v;
                    if (Cb) Cb[off] = f2bf_u(v);
                }
            }
        }
    }
}

// ===========================================================================
// SAFE path kernels (R5, proven)
// ===========================================================================
template <int CC>
__global__ __launch_bounds__(256) void gather_mean(
    const float* __restrict__ X, int ldx,
    const int* __restrict__ rp, const int* __restrict__ ssrc,
    const float* __restrict__ invd, float* __restrict__ agg)
{
    const long long gid = (long long)blockIdx.x * blockDim.x + threadIdx.x;
    const int w = (int)(gid >> 6);
    const int lane = threadIdx.x & 63;
    if (w >= N_NODES) return;
    const int start = rp[w], end = rp[w + 1];
    const float sc = invd[w];

    if constexpr (CC == 256) {
        const float* base = X + lane * 4;
        float4 a = make_float4(0.f, 0.f, 0.f, 0.f);
        int e = start;
        for (; e + 1 < end; e += 2) {
            int s0 = ssrc[e], s1 = ssrc[e + 1];
            float4 v0 = *(const float4*)(base + (long long)s0 * ldx);
            float4 v1 = *(const float4*)(base + (long long)s1 * ldx);
            a.x += v0.x + v1.x; a.y += v0.y + v1.y;
            a.z += v0.z + v1.z; a.w += v0.w + v1.w;
        }
        if (e < end) {
            float4 v = *(const float4*)(base + (long long)ssrc[e] * ldx);
            a.x += v.x; a.y += v.y; a.z += v.z; a.w += v.w;
        }
        float4 o = make_float4(a.x * sc, a.y * sc, a.z * sc, a.w * sc);
        *(float4*)(agg + (long long)w * 256 + lane * 4) = o;
    } else {
        const float* base = X + lane * 2;
        float2 a = make_float2(0.f, 0.f);
        int e = start;
        for (; e + 1 < end; e += 2) {
            int s0 = ssrc[e], s1 = ssrc[e + 1];
            float2 v0 = *(const float2*)(base + (long long)s0 * ldx);
            float2 v1 = *(const float2*)(base + (long long)s1 * ldx);
            a.x += v0.x + v1.x; a.y += v0.y + v1.y;
        }
        if (e < end) {
            float2 v = *(const float2*)(base + (long long)ssrc[e] * ldx);
            a.x += v.x; a.y += v.y;
        }
        float2 o = make_float2(a.x * sc, a.y * sc);
        *(float2*)(agg + (long long)w * 128 + lane * 2) = o;
    }
}

#define GBM 128
#define GBN 64
#define GBK 32
#define LDA 40
#define LDB 40

__global__ __launch_bounds__(256) void mfma_gemm(
    const float* __restrict__ A0, const float* __restrict__ B0, int K0,
    const float* __restrict__ A1, const float* __restrict__ B1, int K1,
    const float* __restrict__ bias,
    const float* __restrict__ gamma, const float* __restrict__ beta,
    const float* __restrict__ mean, const float* __restrict__ var,
    float* __restrict__ C, int M, int do_bias, int bn_relu)
{
    __shared__ short As[GBM * LDA];
    __shared__ short Bs[GBN * LDB];

    const int t = threadIdx.x;
    const int wv = t >> 6;
    const int lane = t & 63;
    const int row0 = blockIdx.y * GBM;
    const int col0 = blockIdx.x * GBN;

    const int lr = lane & 15;
    const int lk = (lane >> 4) * 8;

    floatx4 acc[2][4];
#pragma unroll
    for (int r = 0; r < 2; ++r)
#pragma unroll
        for (int c = 0; c < 4; ++c) acc[r][c] = (floatx4){0.f, 0.f, 0.f, 0.f};

    const int arow = t >> 3;
    const int akc  = (t & 7) * 4;
    const int bkr  = t >> 4;
    const int bcc  = (t & 15) * 4;

    for (int pass = 0; pass < 2; ++pass) {
        if (pass == 1 && A1 == nullptr) break;
        const float* __restrict__ A = pass ? A1 : A0;
        const float* __restrict__ B = pass ? B1 : B0;
        const int K = pass ? K1 : K0;

        for (int k0 = 0; k0 < K; k0 += GBK) {
            __syncthreads();
#pragma unroll
            for (int i = 0; i < 4; ++i) {
                const int lrow = arow + i * 32;
                const int grow = row0 + lrow;
                float4 v = make_float4(0.f, 0.f, 0.f, 0.f);
                if (grow < N_NODES)
                    v = *(const float4*)(A + (long long)grow * K + k0 + akc);
                short4 sv;
                sv.x = f2bf(v.x); sv.y = f2bf(v.y);
                sv.z = f2bf(v.z); sv.w = f2bf(v.w);
                *(short4*)(&As[lrow * LDA + akc]) = sv;
            }
#pragma unroll
            for (int i = 0; i < 2; ++i) {
                const int k = bkr + i * 16;
                const int gc = col0 + bcc;
                float4 v;
                if (gc + 3 < M) {
                    v = *(const float4*)(B + (long long)(k0 + k) * M + gc);
                } else {
                    v.x = (gc + 0 < M) ? B[(long long)(k0 + k) * M + gc + 0] : 0.f;
                    v.y = (gc + 1 < M) ? B[(long long)(k0 + k) * M + gc + 1] : 0.f;
                    v.z = (gc + 2 < M) ? B[(long long)(k0 + k) * M + gc + 2] : 0.f;
                    v.w = (gc + 3 < M) ? B[(long long)(k0 + k) * M + gc + 3] : 0.f;
                }
                Bs[(bcc + 0) * LDB + k] = f2bf(v.x);
                Bs[(bcc + 1) * LDB + k] = f2bf(v.y);
                Bs[(bcc + 2) * LDB + k] = f2bf(v.z);
                Bs[(bcc + 3) * LDB + k] = f2bf(v.w);
            }
            __syncthreads();

            bf16x8 af[2], bfr[4];
#pragma unroll
            for (int r = 0; r < 2; ++r)
                af[r] = *(const bf16x8*)(&As[(wv * 32 + r * 16 + lr) * LDA + lk]);
#pragma unroll
            for (int c = 0; c < 4; ++c)
                bfr[c] = *(const bf16x8*)(&Bs[(c * 16 + lr) * LDB + lk]);
#pragma unroll
            for (int r = 0; r < 2; ++r)
#pragma unroll
                for (int c = 0; c < 4; ++c)
                    acc[r][c] = __builtin_amdgcn_mfma_f32_16x16x32_bf16(
                        af[r], bfr[c], acc[r][c], 0, 0, 0);
        }
    }

#pragma unroll
    for (int r = 0; r < 2; ++r) {
#pragma unroll
        for (int g = 0; g < 4; ++g) {
            const int row = row0 + wv * 32 + r * 16 + (lane >> 4) * 4 + g;
            if (row >= N_NODES) continue;
#pragma unroll
            for (int c = 0; c < 4; ++c) {
                const int col = col0 + c * 16 + lr;
                if (col >= M) continue;
                float v = acc[r][c][g];
                if (do_bias) v += bias[col];
                if (bn_relu) {
                    v = (v - mean[col]) * (gamma[col] * rsqrtf(var[col] + BN_EPS)) + beta[col];
                    v = fmaxf(v, 0.0f);
                }
                C[(long long)row * M + col] = v;
            }
        }
    }
}

// ---------------------------------------------------------------------------
// shared epilogue kernels
// ---------------------------------------------------------------------------
// 4-way edge unroll: 4 independent 188B U-row loads in flight per wave
// (was 1 -> latency-bound at 82us, 1.15 TB/s, VALUBusy 9%).
__global__ __launch_bounds__(256) void gather_add_out(
    const float* __restrict__ U, const int* __restrict__ rp,
    const int* __restrict__ ssrc, const float* __restrict__ invd,
    float* __restrict__ z)
{
    const int w = (blockIdx.x * 256 + threadIdx.x) >> 6;
    const int lane = threadIdx.x & 63;
    if (w >= N_NODES) return;
    if (lane >= D_OUT) return;
    const int start = rp[w], end = rp[w + 1];
    const float* Ub = U + lane;
    float a0 = 0.f, a1 = 0.f, a2 = 0.f, a3 = 0.f;
    int e = start;
    for (; e + 3 < end; e += 4) {
        int s0 = ssrc[e], s1 = ssrc[e + 1], s2 = ssrc[e + 2], s3 = ssrc[e + 3];
        a0 += Ub[(long long)s0 * D_OUT];
        a1 += Ub[(long long)s1 * D_OUT];
        a2 += Ub[(long long)s2 * D_OUT];
        a3 += Ub[(long long)s3 * D_OUT];
    }
    for (; e < end; ++e) a0 += Ub[(long long)ssrc[e] * D_OUT];
    z[(long long)w * D_OUT + lane] += ((a0 + a1) + (a2 + a3)) * invd[w];
}

__global__ void log_softmax_kernel(const float* __restrict__ z, float* __restrict__ y) {
    const int gtid = blockIdx.x * blockDim.x + threadIdx.x;
    const int row = gtid >> 6;
    const int lane = threadIdx.x & 63;
    if (row >= N_NODES) return;

    const float* zr = z + (long long)row * D_OUT;
    float v = (lane < D_OUT) ? zr[lane] : -INFINITY;

    float m = v;
#pragma unroll
    for (int off = 32; off > 0; off >>= 1) m = fmaxf(m, __shfl_down(m, off));
    m = __shfl(m, 0);

    float ev = (lane < D_OUT) ? expf(v - m) : 0.0f;
    float s = ev;
#pragma unroll
    for (int off = 32; off > 0; off >>= 1) s += __shfl_down(s, off);
    s = __shfl(s, 0);

    if (lane < D_OUT) y[(long long)row * D_OUT + lane] = v - m - logf(s);
}

// ---------------------------------------------------------------------------
// launch
// ---------------------------------------------------------------------------
extern "C" void kernel_launch(void* const* d_in, const int* in_sizes, int n_in,
                              void* d_out, int out_size, void* d_ws, size_t ws_size,
                              hipStream_t stream) {
    const float* x     = (const float*)d_in[0];
    const int*   ei    = (const int*)d_in[1];
    const float* W1_l  = (const float*)d_in[2];
    const float* b1    = (const float*)d_in[3];
    const float* W1_r  = (const float*)d_in[4];
    const float* bn1_g = (const float*)d_in[5];
    const float* bn1_b = (const float*)d_in[6];
    const float* bn1_m = (const float*)d_in[7];
    const float* bn1_v = (const float*)d_in[8];
    const float* W2_l  = (const float*)d_in[9];
    const float* b2    = (const float*)d_in[10];
    const float* W2_r  = (const float*)d_in[11];
    const float* bn2_g = (const float*)d_in[12];
    const float* bn2_b = (const float*)d_in[13];
    const float* bn2_m = (const float*)d_in[14];
    const float* bn2_v = (const float*)d_in[15];
    const float* W3_l  = (const float*)d_in[16];
    const float* b3    = (const float*)d_in[17];
    const float* W3_r  = (const float*)d_in[18];

    // --- common workspace (CSR) ---
    char* ws = (char*)d_ws;
    int*   degi    = (int*)(ws + 0);
    int*   row_ptr = (int*)(ws + 200064);
    int*   cursor  = (int*)(ws + 400128);
    float* invd    = (float*)(ws + 600192);
    int*   flag    = (int*)(ws + 800256);
    int*   bsum    = (int*)(ws + 800320);
    int*   ssrc    = (int*)(ws + 801152);          // 3.2 MB -> ends 4,001,152

    // d_out layout: z [N*47] | y_pred [N*47] | S1 [N*256] | S2 [N*256]
    float* z     = (float*)d_out;
    float* ypred = z + (long long)N_NODES * D_OUT;
    float* S1    = ypred + (long long)N_NODES * D_OUT;
    float* S2    = S1 + (long long)N_NODES * D_HID;

    // --- CSR build (shared) ---
    detect_idx_kernel<<<1, 256, 0, stream>>>(ei, flag);
    hipMemsetAsync(degi, 0, N_NODES * sizeof(int), stream);
    count_deg_kernel<<<(N_EDGES + 255) / 256, 256, 0, stream>>>(ei, flag, degi);
    block_sum_kernel<<<SCAN_NBLK, 256, 0, stream>>>(degi, bsum);
    scan_bsums_kernel<<<1, 256, 0, stream>>>(bsum, row_ptr);
    fill_rowptr_kernel<<<SCAN_NBLK, 256, 0, stream>>>(degi, bsum, row_ptr, cursor, invd);
    fill_csr_kernel<<<(N_EDGES + 255) / 256, 256, 0, stream>>>(ei, flag, cursor, ssrc);

    const int gblocks = (N_NODES * 64 + 255) / 256;

    // FULL bf16-direct plan needs 94,059,904 B of ws
    if (ws_size >= 94059904ULL) {
        u16*   wt1l = (u16*)(ws + 4001152);
        u16*   wt1r = (u16*)(ws + 4066688);
        u16*   wt2l = (u16*)(ws + 4132224);
        u16*   wt2r = (u16*)(ws + 4263296);
        u16*   wt3  = (u16*)(ws + 4394368);
        u16*   xb   = (u16*)(ws + 4459904);        // N*128 bf16
        u16*   S1b  = (u16*)(ws + 17259904);       // N*256 bf16
        u16*   S2b  = (u16*)(ws + 42859904);       // N*256 bf16
        u16*   agg  = (u16*)(ws + 68459904);       // N*256 bf16 (reused as U fp32)
        float* U    = (float*)agg;

        convert_xb_kernel<<<(N_NODES * D_IN / 4 + 255) / 256, 256, 0, stream>>>(x, xb);
        build_wt_kernel<<<(229376 + 255) / 256, 256, 0, stream>>>(
            W1_l, W1_r, W2_l, W2_r, W3_l, W3_r, wt1l, wt1r, wt2l, wt2r, wt3);

        const dim3 gHid(2, (N_NODES + 127) / 128);   // M=256, 128x128 blocks
        const dim3 gOut(1, (N_NODES + 127) / 128);   // M=94 (padded 128)

        // layer 1 (K=128 x2 passes, NKT=8)
        gather_mean_bf<128><<<gblocks, 256, 0, stream>>>(xb, row_ptr, ssrc, invd, agg);
        mfma_lds<4, 4, 256><<<gHid, 256, 0, stream>>>(
            agg, wt1l, xb, wt1r,
            b1, bn1_g, bn1_b, bn1_m, bn1_v,
            S1, D_HID, 1, 1, S1b, nullptr, 0);
        // layer 2 (K=256 x2 passes, NKT=16)
        gather_mean_bf<256><<<gblocks, 256, 0, stream>>>(S1b, row_ptr, ssrc, invd, agg);
        mfma_lds<8, 8, 256><<<gHid, 256, 0, stream>>>(
            agg, wt2l, S1b, wt2r,
            b2, bn2_g, bn2_b, bn2_m, bn2_v,
            S2, D_HID, 1, 1, S2b, nullptr, 0);
        // layer 3 (fused transform-first: U = S2@W3_l, z = S2@W3_r + b3)
        mfma_lds<8, 0, 128><<<gOut, 256, 0, stream>>>(
            S2b, wt3, nullptr, nullptr,
            b3, nullptr, nullptr, nullptr, nullptr,
            U, 94, 0, 0, nullptr, z, D_OUT);
        gather_add_out<<<gblocks, 256, 0, stream>>>(U, row_ptr, ssrc, invd, z);
    } else {
        // SAFE: R5 fp32-LDS pipeline (proven <= 55.2 MB)
        float* aggF = (float*)(ws + 4001152);      // N*256 fp32, ends 55,201,152
        float* U    = aggF;

        const dim3 gHid(D_HID / GBN, (N_NODES + GBM - 1) / GBM);
        const dim3 gOut(1, (N_NODES + GBM - 1) / GBM);

        gather_mean<128><<<gblocks, 256, 0, stream>>>(x, D_IN, row_ptr, ssrc, invd, aggF);
        mfma_gemm<<<gHid, 256, 0, stream>>>(aggF, W1_l, D_IN, x, W1_r, D_IN,
                                            b1, bn1_g, bn1_b, bn1_m, bn1_v,
                                            S1, D_HID, 1, 1);
        gather_mean<256><<<gblocks, 256, 0, stream>>>(S1, D_HID, row_ptr, ssrc, invd, aggF);
        mfma_gemm<<<gHid, 256, 0, stream>>>(aggF, W2_l, D_HID, S1, W2_r, D_HID,
                                            b2, bn2_g, bn2_b, bn2_m, bn2_v,
                                            S2, D_HID, 1, 1);
        mfma_gemm<<<gOut, 256, 0, stream>>>(S2, W3_l, D_HID, nullptr, nullptr, 0,
                                            nullptr, nullptr, nullptr, nullptr, nullptr,
                                            U, D_OUT, 0, 0);
        mfma_gemm<<<gOut, 256, 0, stream>>>(S2, W3_r, D_HID, nullptr, nullptr, 0,
                                            b3, nullptr, nullptr, nullptr, nullptr,
                                            z, D_OUT, 1, 0);
        gather_add_out<<<gblocks, 256, 0, stream>>>(U, row_ptr, ssrc, invd, z);
    }

    log_softmax_kernel<<<gblocks, 256, 0, stream>>>(z, ypred);
}

// Round 7
// 531.610 us; speedup vs baseline: 1.2662x; 1.0236x over previous
//
#include <hip/hip_runtime.h>
#include <cmath>

#define N_NODES 50000
#define N_EDGES 800000
#define D_IN    128
#define D_HID   256
#define D_OUT   47
#define BN_EPS  1e-5f
#define SCAN_NBLK ((N_NODES + 255) / 256)   // 196

typedef __attribute__((ext_vector_type(8))) short bf16x8;
typedef __attribute__((ext_vector_type(4))) float floatx4;
typedef unsigned short u16;
typedef unsigned int u32;

__device__ __forceinline__ short f2bf(float f) {          // legacy (short)
    unsigned u = __float_as_uint(f);
    u += 0x7fff + ((u >> 16) & 1);
    return (short)(u >> 16);
}
__device__ __forceinline__ u16 f2bf_u(float f) {
    unsigned u = __float_as_uint(f);
    u += 0x7fff + ((u >> 16) & 1);
    return (u16)(u >> 16);
}
__device__ __forceinline__ float bf2f(u16 h) {
    return __uint_as_float(((unsigned)h) << 16);
}

// async 16B global->LDS DMA (the op hipcc cannot sink; waited at barrier)
__device__ __forceinline__ void load_lds16(const void* g, void* l) {
    __builtin_amdgcn_global_load_lds(
        (const __attribute__((address_space(1))) u32*)g,
        (__attribute__((address_space(3))) u32*)l,
        16, 0, 0);
}

// ---------------------------------------------------------------------------
// edge_index layout detection (int64 vs int32)
// ---------------------------------------------------------------------------
__global__ void detect_idx_kernel(const int* __restrict__ ei, int* __restrict__ flag) {
    __shared__ int any_nonzero;
    if (threadIdx.x == 0) any_nonzero = 0;
    __syncthreads();
    int v = ei[2 * threadIdx.x + 1];
    if (v != 0) atomicAdd(&any_nonzero, 1);
    __syncthreads();
    if (threadIdx.x == 0) *flag = (any_nonzero == 0) ? 1 : 0;
}

__device__ __forceinline__ int load_edge(const int* __restrict__ ei, int e, int which, int is64) {
    if (is64) return ei[2 * ((long long)which * N_EDGES + e)];
    return ei[(long long)which * N_EDGES + e];
}

// ---------------------------------------------------------------------------
// CSR build
// ---------------------------------------------------------------------------
__global__ void count_deg_kernel(const int* __restrict__ ei, const int* __restrict__ flag,
                                 int* __restrict__ degi) {
    int e = blockIdx.x * blockDim.x + threadIdx.x;
    if (e >= N_EDGES) return;
    int is64 = *flag;
    atomicAdd(&degi[load_edge(ei, e, 1, is64)], 1);
}

__global__ __launch_bounds__(256) void block_sum_kernel(const int* __restrict__ degi,
                                                        int* __restrict__ bsum) {
    const int i = blockIdx.x * 256 + threadIdx.x;
    int v = (i < N_NODES) ? degi[i] : 0;
#pragma unroll
    for (int off = 32; off > 0; off >>= 1) v += __shfl_down(v, off);
    __shared__ int sh[4];
    if ((threadIdx.x & 63) == 0) sh[threadIdx.x >> 6] = v;
    __syncthreads();
    if (threadIdx.x == 0) bsum[blockIdx.x] = sh[0] + sh[1] + sh[2] + sh[3];
}

__global__ __launch_bounds__(256) void scan_bsums_kernel(int* __restrict__ bsum,
                                                         int* __restrict__ row_ptr) {
    const int t = threadIdx.x;
    __shared__ int sh[256];
    int v = (t < SCAN_NBLK) ? bsum[t] : 0;
    sh[t] = v;
    __syncthreads();
#pragma unroll
    for (int off = 1; off < 256; off <<= 1) {
        int u = (t >= off) ? sh[t - off] : 0;
        __syncthreads();
        sh[t] += u;
        __syncthreads();
    }
    if (t < SCAN_NBLK) bsum[t] = sh[t] - v;
    if (t == 255) row_ptr[N_NODES] = sh[255];
}

__global__ __launch_bounds__(256) void fill_rowptr_kernel(const int* __restrict__ degi,
                                                          const int* __restrict__ bsum,
                                                          int* __restrict__ row_ptr,
                                                          int* __restrict__ cursor,
                                                          float* __restrict__ invd) {
    const int t = threadIdx.x;
    const int i = blockIdx.x * 256 + t;
    __shared__ int sh[256];
    int d = (i < N_NODES) ? degi[i] : 0;
    sh[t] = d;
    __syncthreads();
#pragma unroll
    for (int off = 1; off < 256; off <<= 1) {
        int u = (t >= off) ? sh[t - off] : 0;
        __syncthreads();
        sh[t] += u;
        __syncthreads();
    }
    if (i < N_NODES) {
        const int pos = bsum[blockIdx.x] + sh[t] - d;
        row_ptr[i] = pos;
        cursor[i]  = pos;
        invd[i]    = 1.0f / fmaxf((float)d, 1.0f);
    }
}

__global__ void fill_csr_kernel(const int* __restrict__ ei, const int* __restrict__ flag,
                                int* __restrict__ cursor, int* __restrict__ ssrc) {
    int e = blockIdx.x * blockDim.x + threadIdx.x;
    if (e >= N_EDGES) return;
    int is64 = *flag;
    int s = load_edge(ei, e, 0, is64);
    int d = load_edge(ei, e, 1, is64);
    int pos = atomicAdd(&cursor[d], 1);
    ssrc[pos] = s;
}

// ===========================================================================
// FULL (bf16-direct) path kernels
// ===========================================================================

// x (fp32) -> xb (bf16), N*128 elems
__global__ void convert_xb_kernel(const float* __restrict__ x, u16* __restrict__ xb) {
    const int n4 = N_NODES * D_IN / 4;
    int i = blockIdx.x * 256 + threadIdx.x;
    if (i >= n4) return;
    float4 v = ((const float4*)x)[i];
    ushort4 o;
    o.x = f2bf_u(v.x); o.y = f2bf_u(v.y); o.z = f2bf_u(v.z); o.w = f2bf_u(v.w);
    ((ushort4*)xb)[i] = o;
}

// all weights -> bf16, k-blocked layout: WT[kb][col][32] (kb = k/32).
// WT3 = [W3_l | W3_r | 0pad] (128 cols x 256 k)
__global__ void build_wt_kernel(const float* __restrict__ W1l, const float* __restrict__ W1r,
                                const float* __restrict__ W2l, const float* __restrict__ W2r,
                                const float* __restrict__ W3l, const float* __restrict__ W3r,
                                u16* __restrict__ wt1l, u16* __restrict__ wt1r,
                                u16* __restrict__ wt2l, u16* __restrict__ wt2r,
                                u16* __restrict__ wt3) {
    int idx = blockIdx.x * 256 + threadIdx.x;
    if (idx < 65536) {                       // WT1l / WT1r : NC=256, K=128
        int seg = idx >> 15, d = idx & 32767;
        int kb = d >> 13, col = (d >> 5) & 255, kq = d & 31;
        int k = kb * 32 + kq;
        const float* W = seg ? W1r : W1l;
        u16* WT = seg ? wt1r : wt1l;
        WT[d] = f2bf_u(W[k * 256 + col]);
    } else if (idx < 196608) {               // WT2l / WT2r : NC=256, K=256
        int d = idx - 65536;
        int seg = d >> 16; d &= 65535;
        int kb = d >> 13, col = (d >> 5) & 255, kq = d & 31;
        int k = kb * 32 + kq;
        const float* W = seg ? W2r : W2l;
        u16* WT = seg ? wt2r : wt2l;
        WT[d] = f2bf_u(W[k * 256 + col]);
    } else if (idx < 229376) {               // WT3 : NC=128, K=256, zero-padded
        int d = idx - 196608;
        int kb = d >> 12, col = (d >> 5) & 127, kq = d & 31;
        int k = kb * 32 + kq;
        float v = 0.f;
        if (col < 47)      v = W3l[k * 47 + col];
        else if (col < 94) v = W3r[k * 47 + (col - 47)];
        wt3[d] = f2bf_u(v);
    }
}

// CSR gather-mean over bf16 rows: one wave per node.
// 4-way edge unroll: 4 independent row-loads in flight per wave (latency hiding).
template <int CC>
__global__ __launch_bounds__(256) void gather_mean_bf(
    const u16* __restrict__ Xb, const int* __restrict__ rp,
    const int* __restrict__ ssrc, const float* __restrict__ invd,
    u16* __restrict__ agg)
{
    const int w = (blockIdx.x * 256 + threadIdx.x) >> 6;
    const int lane = threadIdx.x & 63;
    if (w >= N_NODES) return;
    const int start = rp[w], end = rp[w + 1];
    const float sc = invd[w];

    if constexpr (CC == 256) {
        const u16* base = Xb + lane * 4;
        float4 a = make_float4(0.f, 0.f, 0.f, 0.f);
        int e = start;
        for (; e + 3 < end; e += 4) {
            const ushort4 v0 = *(const ushort4*)(base + (size_t)ssrc[e] * 256);
            const ushort4 v1 = *(const ushort4*)(base + (size_t)ssrc[e + 1] * 256);
            const ushort4 v2 = *(const ushort4*)(base + (size_t)ssrc[e + 2] * 256);
            const ushort4 v3 = *(const ushort4*)(base + (size_t)ssrc[e + 3] * 256);
            a.x += (bf2f(v0.x) + bf2f(v1.x)) + (bf2f(v2.x) + bf2f(v3.x));
            a.y += (bf2f(v0.y) + bf2f(v1.y)) + (bf2f(v2.y) + bf2f(v3.y));
            a.z += (bf2f(v0.z) + bf2f(v1.z)) + (bf2f(v2.z) + bf2f(v3.z));
            a.w += (bf2f(v0.w) + bf2f(v1.w)) + (bf2f(v2.w) + bf2f(v3.w));
        }
        for (; e < end; ++e) {
            const ushort4 v = *(const ushort4*)(base + (size_t)ssrc[e] * 256);
            a.x += bf2f(v.x); a.y += bf2f(v.y); a.z += bf2f(v.z); a.w += bf2f(v.w);
        }
        ushort4 o;
        o.x = f2bf_u(a.x * sc); o.y = f2bf_u(a.y * sc);
        o.z = f2bf_u(a.z * sc); o.w = f2bf_u(a.w * sc);
        *(ushort4*)(agg + (size_t)w * 256 + lane * 4) = o;
    } else {  // CC == 128
        const u16* base = Xb + lane * 2;
        float2 a = make_float2(0.f, 0.f);
        int e = start;
        for (; e + 3 < end; e += 4) {
            const ushort2 v0 = *(const ushort2*)(base + (size_t)ssrc[e] * 128);
            const ushort2 v1 = *(const ushort2*)(base + (size_t)ssrc[e + 1] * 128);
            const ushort2 v2 = *(const ushort2*)(base + (size_t)ssrc[e + 2] * 128);
            const ushort2 v3 = *(const ushort2*)(base + (size_t)ssrc[e + 3] * 128);
            a.x += (bf2f(v0.x) + bf2f(v1.x)) + (bf2f(v2.x) + bf2f(v3.x));
            a.y += (bf2f(v0.y) + bf2f(v1.y)) + (bf2f(v2.y) + bf2f(v3.y));
        }
        for (; e < end; ++e) {
            const ushort2 v = *(const ushort2*)(base + (size_t)ssrc[e] * 128);
            a.x += bf2f(v.x); a.y += bf2f(v.y);
        }
        ushort2 o;
        o.x = f2bf_u(a.x * sc); o.y = f2bf_u(a.y * sc);
        *(ushort2*)(agg + (size_t)w * 128 + lane * 2) = o;
    }
}

// ---------------------------------------------------------------------------
// LDS-staged bf16 MFMA GEMM, 2-phase double-buffered via global_load_lds (T3).
// Round-7: col-tile 128 -> 64 to double co-residency (the R6 limiter):
//   * Tile 128 rows x 64 cols, 4 waves (wave = 32 rows x 64 cols, 8 MFMA/K-step)
//   * grid (NC/64, 391): L2 = 1564 blocks = 6.1 blocks/CU (was 3.05);
//     LDS 24KB (A 8K + B 4K, x2 dbuf) -> 6 blocks/CU fit. Six independent
//     K-loops per CU interleave their per-K-step vmcnt(0) barrier drains
//     (R6: 21% occupancy, 80% stall -> too few streams to cover the drain).
//   * staging & swizzle unchanged (proven): linear LDS dest, pre-swizzled
//     global source chunk c ^= ((idx>>1)&3), same XOR on ds_read.
// K compile-time: NK0+NK1 k-blocks of 32. A row-major bf16 [N][K].
// WT k-blocked [kb][col][32]. split>0: col<split -> C; split<=col<2s -> C2+bias.
// ---------------------------------------------------------------------------
template <int NK0, int NK1, int NC>
__global__ __launch_bounds__(256, 2) void mfma_lds(
    const u16* __restrict__ A0, const u16* __restrict__ WT0,
    const u16* __restrict__ A1, const u16* __restrict__ WT1,
    const float* __restrict__ bias,
    const float* __restrict__ gamma, const float* __restrict__ beta,
    const float* __restrict__ mean, const float* __restrict__ var,
    float* __restrict__ C, int M, int do_bias, int bn_relu,
    u16* __restrict__ Cb, float* __restrict__ C2, int split)
{
    __shared__ __align__(16) char lds[24576];   // A dbuf @0/8192, B dbuf @16384/20480

    const int t = threadIdx.x;
    const int wv = t >> 6, lane = t & 63;
    const int lr = lane & 15, quad = lane >> 4;
    const int row0 = blockIdx.y * 128;
    const int col0 = blockIdx.x * 64;
    constexpr int NKT = NK0 + NK1;

    // ---- per-thread stage constants
    // A: 2 slots of 16B (8KB tile); B: 1 slot of 16B (4KB tile)
    int sIdxA[2], sCsA[2];
#pragma unroll
    for (int i = 0; i < 2; ++i) {
        int slot = i * 256 + t;            // 0..511
        sIdxA[i] = slot >> 2;              // row 0..127
        int c = slot & 3;
        sCsA[i] = c ^ ((sIdxA[i] >> 1) & 3);
    }
    int srowA[2];
#pragma unroll
    for (int i = 0; i < 2; ++i) {
        int r = row0 + sIdxA[i];
        srowA[i] = (r < N_NODES) ? r : (N_NODES - 1);   // clamp (garbage rows unused)
    }
    const int sIdxB = t >> 2;              // col 0..63
    const int sCsB  = (t & 3) ^ ((sIdxB >> 1) & 3);

    // ---- ds_read byte offsets within a tile (swizzled chunk)
    int offA[2], offB[4];
#pragma unroll
    for (int r = 0; r < 2; ++r) {
        int idx = wv * 32 + r * 16 + lr;
        offA[r] = idx * 64 + ((quad ^ ((idx >> 1) & 3)) * 16);
    }
#pragma unroll
    for (int c = 0; c < 4; ++c) {
        int idx = c * 16 + lr;
        offB[c] = idx * 64 + ((quad ^ ((idx >> 1) & 3)) * 16);
    }

    floatx4 acc[2][4];
#pragma unroll
    for (int r = 0; r < 2; ++r)
#pragma unroll
        for (int c = 0; c < 4; ++c) acc[r][c] = (floatx4){0.f, 0.f, 0.f, 0.f};

    // ---- stage k-step ks into buffer 'cur'
    auto stage = [&](int ks, int cur) {
        const char* Ab; const char* Wb; int kb; size_t Kb;  // Kb = row stride bytes
        if (ks < NK0) { Ab = (const char*)A0; Wb = (const char*)WT0; kb = ks;       Kb = (size_t)NK0 * 64; }
        else          { Ab = (const char*)A1; Wb = (const char*)WT1; kb = ks - NK0; Kb = (size_t)NK1 * 64; }
#pragma unroll
        for (int i = 0; i < 2; ++i) {
            const char* srcA = Ab + (size_t)srowA[i] * Kb + (size_t)kb * 64 + sCsA[i] * 16;
            load_lds16(srcA, lds + cur * 8192 + (i * 256 + t) * 16);
        }
        const char* srcB = Wb + ((size_t)kb * NC + col0 + sIdxB) * 64 + sCsB * 16;
        load_lds16(srcB, lds + 16384 + cur * 4096 + t * 16);
    };

    // ---- compute current buffer: 2 A-frags + 4 B-frags + 8 MFMA
    auto compute = [&](int cur) {
        const char* la = lds + cur * 8192;
        const char* lb = lds + 16384 + cur * 4096;
        bf16x8 a[2], b[4];
#pragma unroll
        for (int r = 0; r < 2; ++r) a[r] = *(const bf16x8*)(la + offA[r]);
#pragma unroll
        for (int c = 0; c < 4; ++c) b[c] = *(const bf16x8*)(lb + offB[c]);
#pragma unroll
        for (int c = 0; c < 4; ++c) {
            acc[0][c] = __builtin_amdgcn_mfma_f32_16x16x32_bf16(a[0], b[c], acc[0][c], 0, 0, 0);
            acc[1][c] = __builtin_amdgcn_mfma_f32_16x16x32_bf16(a[1], b[c], acc[1][c], 0, 0, 0);
        }
    };

    // ---- 2-phase main loop
    stage(0, 0);
    __syncthreads();                 // drain prologue stage
    int cur = 0;
#pragma unroll
    for (int ks = 0; ks < NKT - 1; ++ks) {
        stage(ks + 1, cur ^ 1);      // async loads fly under compute
        compute(cur);
        __syncthreads();             // implicit vmcnt(0)+lgkmcnt(0): next buf ready
        cur ^= 1;
    }
    compute(cur);

    // ---- epilogue (C/D: col=lr, row=quad*4+g) — proven round-0 mapping
#pragma unroll
    for (int r = 0; r < 2; ++r) {
#pragma unroll
        for (int g = 0; g < 4; ++g) {
            const int row = row0 + wv * 32 + r * 16 + quad * 4 + g;
            if (row >= N_NODES) continue;
#pragma unroll
            for (int c = 0; c < 4; ++c) {
                const int col = col0 + c * 16 + lr;
                float v = acc[r][c][g];
                if (split > 0) {
                    if (col < split) {
                        C[(size_t)row * split + col] = v;
                    } else if (col < 2 * split) {
                        C2[(size_t)row * split + (col - split)] = v + bias[col - split];
                    }
                } else {
                    if (col >= M) continue;
                    if (do_bias) v += bias[col];
                    if (bn_relu) {
                        v = (v - mean[col]) * (gamma[col] * rsqrtf(var[col] + BN_EPS)) + beta[col];
                        v = fmaxf(v, 0.0f);
                    }
                    const size_t off = (size_t)row * M + col;
                    C[off] = v;
                    if (Cb) Cb[off] = f2bf_u(v);
                }
            }
        }
    }
}

// ===========================================================================
// SAFE path kernels (R5, proven)
// ===========================================================================
template <int CC>
__global__ __launch_bounds__(256) void gather_mean(
    const float* __restrict__ X, int ldx,
    const int* __restrict__ rp, const int* __restrict__ ssrc,
    const float* __restrict__ invd, float* __restrict__ agg)
{
    const long long gid = (long long)blockIdx.x * blockDim.x + threadIdx.x;
    const int w = (int)(gid >> 6);
    const int lane = threadIdx.x & 63;
    if (w >= N_NODES) return;
    const int start = rp[w], end = rp[w + 1];
    const float sc = invd[w];

    if constexpr (CC == 256) {
        const float* base = X + lane * 4;
        float4 a = make_float4(0.f, 0.f, 0.f, 0.f);
        int e = start;
        for (; e + 1 < end; e += 2) {
            int s0 = ssrc[e], s1 = ssrc[e + 1];
            float4 v0 = *(const float4*)(base + (long long)s0 * ldx);
            float4 v1 = *(const float4*)(base + (long long)s1 * ldx);
            a.x += v0.x + v1.x; a.y += v0.y + v1.y;
            a.z += v0.z + v1.z; a.w += v0.w + v1.w;
        }
        if (e < end) {
            float4 v = *(const float4*)(base + (long long)ssrc[e] * ldx);
            a.x += v.x; a.y += v.y; a.z += v.z; a.w += v.w;
        }
        float4 o = make_float4(a.x * sc, a.y * sc, a.z * sc, a.w * sc);
        *(float4*)(agg + (long long)w * 256 + lane * 4) = o;
    } else {
        const float* base = X + lane * 2;
        float2 a = make_float2(0.f, 0.f);
        int e = start;
        for (; e + 1 < end; e += 2) {
            int s0 = ssrc[e], s1 = ssrc[e + 1];
            float2 v0 = *(const float2*)(base + (long long)s0 * ldx);
            float2 v1 = *(const float2*)(base + (long long)s1 * ldx);
            a.x += v0.x + v1.x; a.y += v0.y + v1.y;
        }
        if (e < end) {
            float2 v = *(const float2*)(base + (long long)ssrc[e] * ldx);
            a.x += v.x; a.y += v.y;
        }
        float2 o = make_float2(a.x * sc, a.y * sc);
        *(float2*)(agg + (long long)w * 128 + lane * 2) = o;
    }
}

#define GBM 128
#define GBN 64
#define GBK 32
#define LDA 40
#define LDB 40

__global__ __launch_bounds__(256) void mfma_gemm(
    const float* __restrict__ A0, const float* __restrict__ B0, int K0,
    const float* __restrict__ A1, const float* __restrict__ B1, int K1,
    const float* __restrict__ bias,
    const float* __restrict__ gamma, const float* __restrict__ beta,
    const float* __restrict__ mean, const float* __restrict__ var,
    float* __restrict__ C, int M, int do_bias, int bn_relu)
{
    __shared__ short As[GBM * LDA];
    __shared__ short Bs[GBN * LDB];

    const int t = threadIdx.x;
    const int wv = t >> 6;
    const int lane = t & 63;
    const int row0 = blockIdx.y * GBM;
    const int col0 = blockIdx.x * GBN;

    const int lr = lane & 15;
    const int lk = (lane >> 4) * 8;

    floatx4 acc[2][4];
#pragma unroll
    for (int r = 0; r < 2; ++r)
#pragma unroll
        for (int c = 0; c < 4; ++c) acc[r][c] = (floatx4){0.f, 0.f, 0.f, 0.f};

    const int arow = t >> 3;
    const int akc  = (t & 7) * 4;
    const int bkr  = t >> 4;
    const int bcc  = (t & 15) * 4;

    for (int pass = 0; pass < 2; ++pass) {
        if (pass == 1 && A1 == nullptr) break;
        const float* __restrict__ A = pass ? A1 : A0;
        const float* __restrict__ B = pass ? B1 : B0;
        const int K = pass ? K1 : K0;

        for (int k0 = 0; k0 < K; k0 += GBK) {
            __syncthreads();
#pragma unroll
            for (int i = 0; i < 4; ++i) {
                const int lrow = arow + i * 32;
                const int grow = row0 + lrow;
                float4 v = make_float4(0.f, 0.f, 0.f, 0.f);
                if (grow < N_NODES)
                    v = *(const float4*)(A + (long long)grow * K + k0 + akc);
                short4 sv;
                sv.x = f2bf(v.x); sv.y = f2bf(v.y);
                sv.z = f2bf(v.z); sv.w = f2bf(v.w);
                *(short4*)(&As[lrow * LDA + akc]) = sv;
            }
#pragma unroll
            for (int i = 0; i < 2; ++i) {
                const int k = bkr + i * 16;
                const int gc = col0 + bcc;
                float4 v;
                if (gc + 3 < M) {
                    v = *(const float4*)(B + (long long)(k0 + k) * M + gc);
                } else {
                    v.x = (gc + 0 < M) ? B[(long long)(k0 + k) * M + gc + 0] : 0.f;
                    v.y = (gc + 1 < M) ? B[(long long)(k0 + k) * M + gc + 1] : 0.f;
                    v.z = (gc + 2 < M) ? B[(long long)(k0 + k) * M + gc + 2] : 0.f;
                    v.w = (gc + 3 < M) ? B[(long long)(k0 + k) * M + gc + 3] : 0.f;
                }
                Bs[(bcc + 0) * LDB + k] = f2bf(v.x);
                Bs[(bcc + 1) * LDB + k] = f2bf(v.y);
                Bs[(bcc + 2) * LDB + k] = f2bf(v.z);
                Bs[(bcc + 3) * LDB + k] = f2bf(v.w);
            }
            __syncthreads();

            bf16x8 af[2], bfr[4];
#pragma unroll
            for (int r = 0; r < 2; ++r)
                af[r] = *(const bf16x8*)(&As[(wv * 32 + r * 16 + lr) * LDA + lk]);
#pragma unroll
            for (int c = 0; c < 4; ++c)
                bfr[c] = *(const bf16x8*)(&Bs[(c * 16 + lr) * LDB + lk]);
#pragma unroll
            for (int r = 0; r < 2; ++r)
#pragma unroll
                for (int c = 0; c < 4; ++c)
                    acc[r][c] = __builtin_amdgcn_mfma_f32_16x16x32_bf16(
                        af[r], bfr[c], acc[r][c], 0, 0, 0);
        }
    }

#pragma unroll
    for (int r = 0; r < 2; ++r) {
#pragma unroll
        for (int g = 0; g < 4; ++g) {
            const int row = row0 + wv * 32 + r * 16 + (lane >> 4) * 4 + g;
            if (row >= N_NODES) continue;
#pragma unroll
            for (int c = 0; c < 4; ++c) {
                const int col = col0 + c * 16 + lr;
                if (col >= M) continue;
                float v = acc[r][c][g];
                if (do_bias) v += bias[col];
                if (bn_relu) {
                    v = (v - mean[col]) * (gamma[col] * rsqrtf(var[col] + BN_EPS)) + beta[col];
                    v = fmaxf(v, 0.0f);
                }
                C[(long long)row * M + col] = v;
            }
        }
    }
}

// ---------------------------------------------------------------------------
// shared epilogue kernels
// ---------------------------------------------------------------------------
// 4-way edge unroll: 4 independent 188B U-row loads in flight per wave
__global__ __launch_bounds__(256) void gather_add_out(
    const float* __restrict__ U, const int* __restrict__ rp,
    const int* __restrict__ ssrc, const float* __restrict__ invd,
    float* __restrict__ z)
{
    const int w = (blockIdx.x * 256 + threadIdx.x) >> 6;
    const int lane = threadIdx.x & 63;
    if (w >= N_NODES) return;
    if (lane >= D_OUT) return;
    const int start = rp[w], end = rp[w + 1];
    const float* Ub = U + lane;
    float a0 = 0.f, a1 = 0.f, a2 = 0.f, a3 = 0.f;
    int e = start;
    for (; e + 3 < end; e += 4) {
        int s0 = ssrc[e], s1 = ssrc[e + 1], s2 = ssrc[e + 2], s3 = ssrc[e + 3];
        a0 += Ub[(long long)s0 * D_OUT];
        a1 += Ub[(long long)s1 * D_OUT];
        a2 += Ub[(long long)s2 * D_OUT];
        a3 += Ub[(long long)s3 * D_OUT];
    }
    for (; e < end; ++e) a0 += Ub[(long long)ssrc[e] * D_OUT];
    z[(long long)w * D_OUT + lane] += ((a0 + a1) + (a2 + a3)) * invd[w];
}

__global__ void log_softmax_kernel(const float* __restrict__ z, float* __restrict__ y) {
    const int gtid = blockIdx.x * blockDim.x + threadIdx.x;
    const int row = gtid >> 6;
    const int lane = threadIdx.x & 63;
    if (row >= N_NODES) return;

    const float* zr = z + (long long)row * D_OUT;
    float v = (lane < D_OUT) ? zr[lane] : -INFINITY;

    float m = v;
#pragma unroll
    for (int off = 32; off > 0; off >>= 1) m = fmaxf(m, __shfl_down(m, off));
    m = __shfl(m, 0);

    float ev = (lane < D_OUT) ? expf(v - m) : 0.0f;
    float s = ev;
#pragma unroll
    for (int off = 32; off > 0; off >>= 1) s += __shfl_down(s, off);
    s = __shfl(s, 0);

    if (lane < D_OUT) y[(long long)row * D_OUT + lane] = v - m - logf(s);
}

// ---------------------------------------------------------------------------
// launch
// ---------------------------------------------------------------------------
extern "C" void kernel_launch(void* const* d_in, const int* in_sizes, int n_in,
                              void* d_out, int out_size, void* d_ws, size_t ws_size,
                              hipStream_t stream) {
    const float* x     = (const float*)d_in[0];
    const int*   ei    = (const int*)d_in[1];
    const float* W1_l  = (const float*)d_in[2];
    const float* b1    = (const float*)d_in[3];
    const float* W1_r  = (const float*)d_in[4];
    const float* bn1_g = (const float*)d_in[5];
    const float* bn1_b = (const float*)d_in[6];
    const float* bn1_m = (const float*)d_in[7];
    const float* bn1_v = (const float*)d_in[8];
    const float* W2_l  = (const float*)d_in[9];
    const float* b2    = (const float*)d_in[10];
    const float* W2_r  = (const float*)d_in[11];
    const float* bn2_g = (const float*)d_in[12];
    const float* bn2_b = (const float*)d_in[13];
    const float* bn2_m = (const float*)d_in[14];
    const float* bn2_v = (const float*)d_in[15];
    const float* W3_l  = (const float*)d_in[16];
    const float* b3    = (const float*)d_in[17];
    const float* W3_r  = (const float*)d_in[18];

    // --- common workspace (CSR) ---
    char* ws = (char*)d_ws;
    int*   degi    = (int*)(ws + 0);
    int*   row_ptr = (int*)(ws + 200064);
    int*   cursor  = (int*)(ws + 400128);
    float* invd    = (float*)(ws + 600192);
    int*   flag    = (int*)(ws + 800256);
    int*   bsum    = (int*)(ws + 800320);
    int*   ssrc    = (int*)(ws + 801152);          // 3.2 MB -> ends 4,001,152

    // d_out layout: z [N*47] | y_pred [N*47] | S1 [N*256] | S2 [N*256]
    float* z     = (float*)d_out;
    float* ypred = z + (long long)N_NODES * D_OUT;
    float* S1    = ypred + (long long)N_NODES * D_OUT;
    float* S2    = S1 + (long long)N_NODES * D_HID;

    // --- CSR build (shared) ---
    detect_idx_kernel<<<1, 256, 0, stream>>>(ei, flag);
    hipMemsetAsync(degi, 0, N_NODES * sizeof(int), stream);
    count_deg_kernel<<<(N_EDGES + 255) / 256, 256, 0, stream>>>(ei, flag, degi);
    block_sum_kernel<<<SCAN_NBLK, 256, 0, stream>>>(degi, bsum);
    scan_bsums_kernel<<<1, 256, 0, stream>>>(bsum, row_ptr);
    fill_rowptr_kernel<<<SCAN_NBLK, 256, 0, stream>>>(degi, bsum, row_ptr, cursor, invd);
    fill_csr_kernel<<<(N_EDGES + 255) / 256, 256, 0, stream>>>(ei, flag, cursor, ssrc);

    const int gblocks = (N_NODES * 64 + 255) / 256;

    // FULL bf16-direct plan needs 94,059,904 B of ws
    if (ws_size >= 94059904ULL) {
        u16*   wt1l = (u16*)(ws + 4001152);
        u16*   wt1r = (u16*)(ws + 4066688);
        u16*   wt2l = (u16*)(ws + 4132224);
        u16*   wt2r = (u16*)(ws + 4263296);
        u16*   wt3  = (u16*)(ws + 4394368);
        u16*   xb   = (u16*)(ws + 4459904);        // N*128 bf16
        u16*   S1b  = (u16*)(ws + 17259904);       // N*256 bf16
        u16*   S2b  = (u16*)(ws + 42859904);       // N*256 bf16
        u16*   agg  = (u16*)(ws + 68459904);       // N*256 bf16 (reused as U fp32)
        float* U    = (float*)agg;

        convert_xb_kernel<<<(N_NODES * D_IN / 4 + 255) / 256, 256, 0, stream>>>(x, xb);
        build_wt_kernel<<<(229376 + 255) / 256, 256, 0, stream>>>(
            W1_l, W1_r, W2_l, W2_r, W3_l, W3_r, wt1l, wt1r, wt2l, wt2r, wt3);

        const dim3 gHid(4, (N_NODES + 127) / 128);   // M=256, 128x64 blocks
        const dim3 gOut(2, (N_NODES + 127) / 128);   // M=94 (padded 128)

        // layer 1 (K=128 x2 passes, NKT=8)
        gather_mean_bf<128><<<gblocks, 256, 0, stream>>>(xb, row_ptr, ssrc, invd, agg);
        mfma_lds<4, 4, 256><<<gHid, 256, 0, stream>>>(
            agg, wt1l, xb, wt1r,
            b1, bn1_g, bn1_b, bn1_m, bn1_v,
            S1, D_HID, 1, 1, S1b, nullptr, 0);
        // layer 2 (K=256 x2 passes, NKT=16)
        gather_mean_bf<256><<<gblocks, 256, 0, stream>>>(S1b, row_ptr, ssrc, invd, agg);
        mfma_lds<8, 8, 256><<<gHid, 256, 0, stream>>>(
            agg, wt2l, S1b, wt2r,
            b2, bn2_g, bn2_b, bn2_m, bn2_v,
            S2, D_HID, 1, 1, S2b, nullptr, 0);
        // layer 3 (fused transform-first: U = S2@W3_l, z = S2@W3_r + b3)
        mfma_lds<8, 0, 128><<<gOut, 256, 0, stream>>>(
            S2b, wt3, nullptr, nullptr,
            b3, nullptr, nullptr, nullptr, nullptr,
            U, 94, 0, 0, nullptr, z, D_OUT);
        gather_add_out<<<gblocks, 256, 0, stream>>>(U, row_ptr, ssrc, invd, z);
    } else {
        // SAFE: R5 fp32-LDS pipeline (proven <= 55.2 MB)
        float* aggF = (float*)(ws + 4001152);      // N*256 fp32, ends 55,201,152
        float* U    = aggF;

        const dim3 gHid(D_HID / GBN, (N_NODES + GBM - 1) / GBM);
        const dim3 gOut(1, (N_NODES + GBM - 1) / GBM);

        gather_mean<128><<<gblocks, 256, 0, stream>>>(x, D_IN, row_ptr, ssrc, invd, aggF);
        mfma_gemm<<<gHid, 256, 0, stream>>>(aggF, W1_l, D_IN, x, W1_r, D_IN,
                                            b1, bn1_g, bn1_b, bn1_m, bn1_v,
                                            S1, D_HID, 1, 1);
        gather_mean<256><<<gblocks, 256, 0, stream>>>(S1, D_HID, row_ptr, ssrc, invd, aggF);
        mfma_gemm<<<gHid, 256, 0, stream>>>(aggF, W2_l, D_HID, S1, W2_r, D_HID,
                                            b2, bn2_g, bn2_b, bn2_m, bn2_v,
                                            S2, D_HID, 1, 1);
        mfma_gemm<<<gOut, 256, 0, stream>>>(S2, W3_l, D_HID, nullptr, nullptr, 0,
                                            nullptr, nullptr, nullptr, nullptr, nullptr,
                                            U, D_OUT, 0, 0);
        mfma_gemm<<<gOut, 256, 0, stream>>>(S2, W3_r, D_HID, nullptr, nullptr, 0,
                                            b3, nullptr, nullptr, nullptr, nullptr,
                                            z, D_OUT, 1, 0);
        gather_add_out<<<gblocks, 256, 0, stream>>>(U, row_ptr, ssrc, invd, z);
    }

    log_softmax_kernel<<<gblocks, 256, 0, stream>>>(z, ypred);
}

// Round 8
// 510.980 us; speedup vs baseline: 1.3173x; 1.0404x over previous
//
#include <hip/hip_runtime.h>
#include <cmath>

#define N_NODES 50000
#define N_EDGES 800000
#define D_IN    128
#define D_HID   256
#define D_OUT   47
#define BN_EPS  1e-5f
#define SCAN_NBLK ((N_NODES + 255) / 256)   // 196

typedef __attribute__((ext_vector_type(8))) short bf16x8;
typedef __attribute__((ext_vector_type(4))) float floatx4;
typedef unsigned short u16;
typedef unsigned int u32;

__device__ __forceinline__ short f2bf(float f) {          // legacy (short)
    unsigned u = __float_as_uint(f);
    u += 0x7fff + ((u >> 16) & 1);
    return (short)(u >> 16);
}
__device__ __forceinline__ u16 f2bf_u(float f) {
    unsigned u = __float_as_uint(f);
    u += 0x7fff + ((u >> 16) & 1);
    return (u16)(u >> 16);
}
__device__ __forceinline__ float bf2f(u16 h) {
    return __uint_as_float(((unsigned)h) << 16);
}

// async 16B global->LDS DMA (the op hipcc cannot sink; tracked by vmcnt)
__device__ __forceinline__ void load_lds16(const void* g, void* l) {
    __builtin_amdgcn_global_load_lds(
        (const __attribute__((address_space(1))) u32*)g,
        (__attribute__((address_space(3))) u32*)l,
        16, 0, 0);
}

// ---------------------------------------------------------------------------
// edge_index layout detection (int64 vs int32)
// ---------------------------------------------------------------------------
__global__ void detect_idx_kernel(const int* __restrict__ ei, int* __restrict__ flag) {
    __shared__ int any_nonzero;
    if (threadIdx.x == 0) any_nonzero = 0;
    __syncthreads();
    int v = ei[2 * threadIdx.x + 1];
    if (v != 0) atomicAdd(&any_nonzero, 1);
    __syncthreads();
    if (threadIdx.x == 0) *flag = (any_nonzero == 0) ? 1 : 0;
}

__device__ __forceinline__ int load_edge(const int* __restrict__ ei, int e, int which, int is64) {
    if (is64) return ei[2 * ((long long)which * N_EDGES + e)];
    return ei[(long long)which * N_EDGES + e];
}

// ---------------------------------------------------------------------------
// CSR build
// ---------------------------------------------------------------------------
__global__ void count_deg_kernel(const int* __restrict__ ei, const int* __restrict__ flag,
                                 int* __restrict__ degi) {
    int e = blockIdx.x * blockDim.x + threadIdx.x;
    if (e >= N_EDGES) return;
    int is64 = *flag;
    atomicAdd(&degi[load_edge(ei, e, 1, is64)], 1);
}

__global__ __launch_bounds__(256) void block_sum_kernel(const int* __restrict__ degi,
                                                        int* __restrict__ bsum) {
    const int i = blockIdx.x * 256 + threadIdx.x;
    int v = (i < N_NODES) ? degi[i] : 0;
#pragma unroll
    for (int off = 32; off > 0; off >>= 1) v += __shfl_down(v, off);
    __shared__ int sh[4];
    if ((threadIdx.x & 63) == 0) sh[threadIdx.x >> 6] = v;
    __syncthreads();
    if (threadIdx.x == 0) bsum[blockIdx.x] = sh[0] + sh[1] + sh[2] + sh[3];
}

__global__ __launch_bounds__(256) void scan_bsums_kernel(int* __restrict__ bsum,
                                                         int* __restrict__ row_ptr) {
    const int t = threadIdx.x;
    __shared__ int sh[256];
    int v = (t < SCAN_NBLK) ? bsum[t] : 0;
    sh[t] = v;
    __syncthreads();
#pragma unroll
    for (int off = 1; off < 256; off <<= 1) {
        int u = (t >= off) ? sh[t - off] : 0;
        __syncthreads();
        sh[t] += u;
        __syncthreads();
    }
    if (t < SCAN_NBLK) bsum[t] = sh[t] - v;
    if (t == 255) row_ptr[N_NODES] = sh[255];
}

__global__ __launch_bounds__(256) void fill_rowptr_kernel(const int* __restrict__ degi,
                                                          const int* __restrict__ bsum,
                                                          int* __restrict__ row_ptr,
                                                          int* __restrict__ cursor,
                                                          float* __restrict__ invd) {
    const int t = threadIdx.x;
    const int i = blockIdx.x * 256 + t;
    __shared__ int sh[256];
    int d = (i < N_NODES) ? degi[i] : 0;
    sh[t] = d;
    __syncthreads();
#pragma unroll
    for (int off = 1; off < 256; off <<= 1) {
        int u = (t >= off) ? sh[t - off] : 0;
        __syncthreads();
        sh[t] += u;
        __syncthreads();
    }
    if (i < N_NODES) {
        const int pos = bsum[blockIdx.x] + sh[t] - d;
        row_ptr[i] = pos;
        cursor[i]  = pos;
        invd[i]    = 1.0f / fmaxf((float)d, 1.0f);
    }
}

__global__ void fill_csr_kernel(const int* __restrict__ ei, const int* __restrict__ flag,
                                int* __restrict__ cursor, int* __restrict__ ssrc) {
    int e = blockIdx.x * blockDim.x + threadIdx.x;
    if (e >= N_EDGES) return;
    int is64 = *flag;
    int s = load_edge(ei, e, 0, is64);
    int d = load_edge(ei, e, 1, is64);
    int pos = atomicAdd(&cursor[d], 1);
    ssrc[pos] = s;
}

// ===========================================================================
// FULL (bf16-direct) path kernels
// ===========================================================================

// x (fp32) -> xb (bf16), N*128 elems
__global__ void convert_xb_kernel(const float* __restrict__ x, u16* __restrict__ xb) {
    const int n4 = N_NODES * D_IN / 4;
    int i = blockIdx.x * 256 + threadIdx.x;
    if (i >= n4) return;
    float4 v = ((const float4*)x)[i];
    ushort4 o;
    o.x = f2bf_u(v.x); o.y = f2bf_u(v.y); o.z = f2bf_u(v.z); o.w = f2bf_u(v.w);
    ((ushort4*)xb)[i] = o;
}

// all weights -> bf16, k-blocked layout: WT[kb][col][32] (kb = k/32).
// WT3 = [W3_l | W3_r | 0pad] (128 cols x 256 k)
__global__ void build_wt_kernel(const float* __restrict__ W1l, const float* __restrict__ W1r,
                                const float* __restrict__ W2l, const float* __restrict__ W2r,
                                const float* __restrict__ W3l, const float* __restrict__ W3r,
                                u16* __restrict__ wt1l, u16* __restrict__ wt1r,
                                u16* __restrict__ wt2l, u16* __restrict__ wt2r,
                                u16* __restrict__ wt3) {
    int idx = blockIdx.x * 256 + threadIdx.x;
    if (idx < 65536) {                       // WT1l / WT1r : NC=256, K=128
        int seg = idx >> 15, d = idx & 32767;
        int kb = d >> 13, col = (d >> 5) & 255, kq = d & 31;
        int k = kb * 32 + kq;
        const float* W = seg ? W1r : W1l;
        u16* WT = seg ? wt1r : wt1l;
        WT[d] = f2bf_u(W[k * 256 + col]);
    } else if (idx < 196608) {               // WT2l / WT2r : NC=256, K=256
        int d = idx - 65536;
        int seg = d >> 16; d &= 65535;
        int kb = d >> 13, col = (d >> 5) & 255, kq = d & 31;
        int k = kb * 32 + kq;
        const float* W = seg ? W2r : W2l;
        u16* WT = seg ? wt2r : wt2l;
        WT[d] = f2bf_u(W[k * 256 + col]);
    } else if (idx < 229376) {               // WT3 : NC=128, K=256, zero-padded
        int d = idx - 196608;
        int kb = d >> 12, col = (d >> 5) & 127, kq = d & 31;
        int k = kb * 32 + kq;
        float v = 0.f;
        if (col < 47)      v = W3l[k * 47 + col];
        else if (col < 94) v = W3r[k * 47 + (col - 47)];
        wt3[d] = f2bf_u(v);
    }
}

// CSR gather-mean over bf16 rows: one wave per node.
// 4-way edge unroll: 4 independent row-loads in flight per wave (latency hiding).
template <int CC>
__global__ __launch_bounds__(256) void gather_mean_bf(
    const u16* __restrict__ Xb, const int* __restrict__ rp,
    const int* __restrict__ ssrc, const float* __restrict__ invd,
    u16* __restrict__ agg)
{
    const int w = (blockIdx.x * 256 + threadIdx.x) >> 6;
    const int lane = threadIdx.x & 63;
    if (w >= N_NODES) return;
    const int start = rp[w], end = rp[w + 1];
    const float sc = invd[w];

    if constexpr (CC == 256) {
        const u16* base = Xb + lane * 4;
        float4 a = make_float4(0.f, 0.f, 0.f, 0.f);
        int e = start;
        for (; e + 3 < end; e += 4) {
            const ushort4 v0 = *(const ushort4*)(base + (size_t)ssrc[e] * 256);
            const ushort4 v1 = *(const ushort4*)(base + (size_t)ssrc[e + 1] * 256);
            const ushort4 v2 = *(const ushort4*)(base + (size_t)ssrc[e + 2] * 256);
            const ushort4 v3 = *(const ushort4*)(base + (size_t)ssrc[e + 3] * 256);
            a.x += (bf2f(v0.x) + bf2f(v1.x)) + (bf2f(v2.x) + bf2f(v3.x));
            a.y += (bf2f(v0.y) + bf2f(v1.y)) + (bf2f(v2.y) + bf2f(v3.y));
            a.z += (bf2f(v0.z) + bf2f(v1.z)) + (bf2f(v2.z) + bf2f(v3.z));
            a.w += (bf2f(v0.w) + bf2f(v1.w)) + (bf2f(v2.w) + bf2f(v3.w));
        }
        for (; e < end; ++e) {
            const ushort4 v = *(const ushort4*)(base + (size_t)ssrc[e] * 256);
            a.x += bf2f(v.x); a.y += bf2f(v.y); a.z += bf2f(v.z); a.w += bf2f(v.w);
        }
        ushort4 o;
        o.x = f2bf_u(a.x * sc); o.y = f2bf_u(a.y * sc);
        o.z = f2bf_u(a.z * sc); o.w = f2bf_u(a.w * sc);
        *(ushort4*)(agg + (size_t)w * 256 + lane * 4) = o;
    } else {  // CC == 128
        const u16* base = Xb + lane * 2;
        float2 a = make_float2(0.f, 0.f);
        int e = start;
        for (; e + 3 < end; e += 4) {
            const ushort2 v0 = *(const ushort2*)(base + (size_t)ssrc[e] * 128);
            const ushort2 v1 = *(const ushort2*)(base + (size_t)ssrc[e + 1] * 128);
            const ushort2 v2 = *(const ushort2*)(base + (size_t)ssrc[e + 2] * 128);
            const ushort2 v3 = *(const ushort2*)(base + (size_t)ssrc[e + 3] * 128);
            a.x += (bf2f(v0.x) + bf2f(v1.x)) + (bf2f(v2.x) + bf2f(v3.x));
            a.y += (bf2f(v0.y) + bf2f(v1.y)) + (bf2f(v2.y) + bf2f(v3.y));
        }
        for (; e < end; ++e) {
            const ushort2 v = *(const ushort2*)(base + (size_t)ssrc[e] * 128);
            a.x += bf2f(v.x); a.y += bf2f(v.y);
        }
        ushort2 o;
        o.x = f2bf_u(a.x * sc); o.y = f2bf_u(a.y * sc);
        *(ushort2*)(agg + (size_t)w * 128 + lane * 2) = o;
    }
}

// ---------------------------------------------------------------------------
// LDS-staged bf16 MFMA GEMM, T3+T4: double-buffered global_load_lds with
// COUNTED vmcnt (never drained to 0 mid-loop) + XCD col-sibling swizzle.
//   * Tile 128 rows x 64 cols, 4 waves, LDS 24KB (6 blocks/CU).
//   * Per-thread loads/stage = exactly 3 (2 A + 1 B) -> vmcnt(3) waits the
//     OLDEST stage while the next stage's 3 loads stay in flight.
//   * Loop: vmcnt(3) ; s_barrier (stage ks landed everywhere) ; compute ;
//     s_barrier (all waves done reading buf) ; stage ks+2 into freed buf.
//   * XCD swizzle: bid -> (xcd=bid&7, cb, yg), yb=yg*8+xcd. The nxb
//     col-siblings of one row-panel share one XCD -> per-XCD A working set
//     49 x 64KB = 3.1MB < 4MB L2: A re-reads become L2 hits (R7: they went
//     to L3 because siblings landed on different XCDs). Bijective w/ guard.
// K compile-time: NK0+NK1 k-blocks of 32. A row-major bf16 [N][K].
// WT k-blocked [kb][col][32]. split>0: col<split -> C; split<=col<2s -> C2+bias.
// ---------------------------------------------------------------------------
template <int NK0, int NK1, int NC>
__global__ __launch_bounds__(256, 2) void mfma_lds(
    const u16* __restrict__ A0, const u16* __restrict__ WT0,
    const u16* __restrict__ A1, const u16* __restrict__ WT1,
    const float* __restrict__ bias,
    const float* __restrict__ gamma, const float* __restrict__ beta,
    const float* __restrict__ mean, const float* __restrict__ var,
    float* __restrict__ C, int M, int do_bias, int bn_relu,
    u16* __restrict__ Cb, float* __restrict__ C2, int split)
{
    __shared__ __align__(16) char lds[24576];   // A dbuf @0/8192, B dbuf @16384/20480

    constexpr int NYB = (N_NODES + 127) / 128;  // 391 row-panels
    constexpr int nxb = NC / 64;                // col-blocks per row-panel

    // ---- XCD col-sibling swizzle (1-D grid, nxb*8*ceil(NYB/8) blocks)
    const int bid  = blockIdx.x;
    const int xcd  = bid & 7;
    const int slot = bid >> 3;
    const int cb   = slot % nxb;
    const int yg   = slot / nxb;
    const int yb   = yg * 8 + xcd;
    if (yb >= NYB) return;                      // pad guard (uniform per block)

    const int t = threadIdx.x;
    const int wv = t >> 6, lane = t & 63;
    const int lr = lane & 15, quad = lane >> 4;
    const int row0 = yb * 128;
    const int col0 = cb * 64;
    constexpr int NKT = NK0 + NK1;

    // ---- per-thread stage constants
    // A: 2 slots of 16B (8KB tile); B: 1 slot of 16B (4KB tile)
    int sIdxA[2], sCsA[2];
#pragma unroll
    for (int i = 0; i < 2; ++i) {
        int slotA = i * 256 + t;           // 0..511
        sIdxA[i] = slotA >> 2;             // row 0..127
        int c = slotA & 3;
        sCsA[i] = c ^ ((sIdxA[i] >> 1) & 3);
    }
    int srowA[2];
#pragma unroll
    for (int i = 0; i < 2; ++i) {
        int r = row0 + sIdxA[i];
        srowA[i] = (r < N_NODES) ? r : (N_NODES - 1);   // clamp (garbage rows unused)
    }
    const int sIdxB = t >> 2;              // col 0..63
    const int sCsB  = (t & 3) ^ ((sIdxB >> 1) & 3);

    // ---- ds_read byte offsets within a tile (swizzled chunk)
    int offA[2], offB[4];
#pragma unroll
    for (int r = 0; r < 2; ++r) {
        int idx = wv * 32 + r * 16 + lr;
        offA[r] = idx * 64 + ((quad ^ ((idx >> 1) & 3)) * 16);
    }
#pragma unroll
    for (int c = 0; c < 4; ++c) {
        int idx = c * 16 + lr;
        offB[c] = idx * 64 + ((quad ^ ((idx >> 1) & 3)) * 16);
    }

    floatx4 acc[2][4];
#pragma unroll
    for (int r = 0; r < 2; ++r)
#pragma unroll
        for (int c = 0; c < 4; ++c) acc[r][c] = (floatx4){0.f, 0.f, 0.f, 0.f};

    // ---- stage k-step ks into buffer 'cur' (3 loads/thread, vmcnt-tracked)
    auto stage = [&](int ks, int cur) {
        const char* Ab; const char* Wb; int kb; size_t Kb;  // Kb = row stride bytes
        if (ks < NK0) { Ab = (const char*)A0; Wb = (const char*)WT0; kb = ks;       Kb = (size_t)NK0 * 64; }
        else          { Ab = (const char*)A1; Wb = (const char*)WT1; kb = ks - NK0; Kb = (size_t)NK1 * 64; }
#pragma unroll
        for (int i = 0; i < 2; ++i) {
            const char* srcA = Ab + (size_t)srowA[i] * Kb + (size_t)kb * 64 + sCsA[i] * 16;
            load_lds16(srcA, lds + cur * 8192 + (i * 256 + t) * 16);
        }
        const char* srcB = Wb + ((size_t)kb * NC + col0 + sIdxB) * 64 + sCsB * 16;
        load_lds16(srcB, lds + 16384 + cur * 4096 + t * 16);
    };

    // ---- compute current buffer: 2 A-frags + 4 B-frags + 8 MFMA
    auto compute = [&](int cur) {
        const char* la = lds + cur * 8192;
        const char* lb = lds + 16384 + cur * 4096;
        bf16x8 a[2], b[4];
#pragma unroll
        for (int r = 0; r < 2; ++r) a[r] = *(const bf16x8*)(la + offA[r]);
#pragma unroll
        for (int c = 0; c < 4; ++c) b[c] = *(const bf16x8*)(lb + offB[c]);
#pragma unroll
        for (int c = 0; c < 4; ++c) {
            acc[0][c] = __builtin_amdgcn_mfma_f32_16x16x32_bf16(a[0], b[c], acc[0][c], 0, 0, 0);
            acc[1][c] = __builtin_amdgcn_mfma_f32_16x16x32_bf16(a[1], b[c], acc[1][c], 0, 0, 0);
        }
    };

    // ---- T4 counted-vmcnt main loop: stages ks and ks+1 in flight; never
    //      drain to 0 until the final stage.
    stage(0, 0);
    if constexpr (NKT > 1) stage(1, 1);
#pragma unroll
    for (int ks = 0; ks < NKT; ++ks) {
        if (ks < NKT - 1) {
            asm volatile("s_waitcnt vmcnt(3)" ::: "memory");   // stage ks landed (3 of ks+1 in flight)
        } else {
            asm volatile("s_waitcnt vmcnt(0)" ::: "memory");   // final stage
        }
        __builtin_amdgcn_s_barrier();        // all waves' stage(ks) visible
        __builtin_amdgcn_sched_barrier(0);   // pin: no hoist of ds_read above barrier
        compute(ks & 1);
        if (ks + 2 < NKT) {
            __builtin_amdgcn_s_barrier();    // all waves done reading buf[ks&1]
            stage(ks + 2, ks & 1);           // refill freed buffer; loads fly on
        }
    }

    // ---- epilogue (C/D: col=lr, row=quad*4+g) — proven round-0 mapping
#pragma unroll
    for (int r = 0; r < 2; ++r) {
#pragma unroll
        for (int g = 0; g < 4; ++g) {
            const int row = row0 + wv * 32 + r * 16 + quad * 4 + g;
            if (row >= N_NODES) continue;
#pragma unroll
            for (int c = 0; c < 4; ++c) {
                const int col = col0 + c * 16 + lr;
                float v = acc[r][c][g];
                if (split > 0) {
                    if (col < split) {
                        C[(size_t)row * split + col] = v;
                    } else if (col < 2 * split) {
                        C2[(size_t)row * split + (col - split)] = v + bias[col - split];
                    }
                } else {
                    if (col >= M) continue;
                    if (do_bias) v += bias[col];
                    if (bn_relu) {
                        v = (v - mean[col]) * (gamma[col] * rsqrtf(var[col] + BN_EPS)) + beta[col];
                        v = fmaxf(v, 0.0f);
                    }
                    const size_t off = (size_t)row * M + col;
                    C[off] = v;
                    if (Cb) Cb[off] = f2bf_u(v);
                }
            }
        }
    }
}

// ===========================================================================
// SAFE path kernels (R5, proven)
// ===========================================================================
template <int CC>
__global__ __launch_bounds__(256) void gather_mean(
    const float* __restrict__ X, int ldx,
    const int* __restrict__ rp, const int* __restrict__ ssrc,
    const float* __restrict__ invd, float* __restrict__ agg)
{
    const long long gid = (long long)blockIdx.x * blockDim.x + threadIdx.x;
    const int w = (int)(gid >> 6);
    const int lane = threadIdx.x & 63;
    if (w >= N_NODES) return;
    const int start = rp[w], end = rp[w + 1];
    const float sc = invd[w];

    if constexpr (CC == 256) {
        const float* base = X + lane * 4;
        float4 a = make_float4(0.f, 0.f, 0.f, 0.f);
        int e = start;
        for (; e + 1 < end; e += 2) {
            int s0 = ssrc[e], s1 = ssrc[e + 1];
            float4 v0 = *(const float4*)(base + (long long)s0 * ldx);
            float4 v1 = *(const float4*)(base + (long long)s1 * ldx);
            a.x += v0.x + v1.x; a.y += v0.y + v1.y;
            a.z += v0.z + v1.z; a.w += v0.w + v1.w;
        }
        if (e < end) {
            float4 v = *(const float4*)(base + (long long)ssrc[e] * ldx);
            a.x += v.x; a.y += v.y; a.z += v.z; a.w += v.w;
        }
        float4 o = make_float4(a.x * sc, a.y * sc, a.z * sc, a.w * sc);
        *(float4*)(agg + (long long)w * 256 + lane * 4) = o;
    } else {
        const float* base = X + lane * 2;
        float2 a = make_float2(0.f, 0.f);
        int e = start;
        for (; e + 1 < end; e += 2) {
            int s0 = ssrc[e], s1 = ssrc[e + 1];
            float2 v0 = *(const float2*)(base + (long long)s0 * ldx);
            float2 v1 = *(const float2*)(base + (long long)s1 * ldx);
            a.x += v0.x + v1.x; a.y += v0.y + v1.y;
        }
        if (e < end) {
            float2 v = *(const float2*)(base + (long long)ssrc[e] * ldx);
            a.x += v.x; a.y += v.y;
        }
        float2 o = make_float2(a.x * sc, a.y * sc);
        *(float2*)(agg + (long long)w * 128 + lane * 2) = o;
    }
}

#define GBM 128
#define GBN 64
#define GBK 32
#define LDA 40
#define LDB 40

__global__ __launch_bounds__(256) void mfma_gemm(
    const float* __restrict__ A0, const float* __restrict__ B0, int K0,
    const float* __restrict__ A1, const float* __restrict__ B1, int K1,
    const float* __restrict__ bias,
    const float* __restrict__ gamma, const float* __restrict__ beta,
    const float* __restrict__ mean, const float* __restrict__ var,
    float* __restrict__ C, int M, int do_bias, int bn_relu)
{
    __shared__ short As[GBM * LDA];
    __shared__ short Bs[GBN * LDB];

    const int t = threadIdx.x;
    const int wv = t >> 6;
    const int lane = t & 63;
    const int row0 = blockIdx.y * GBM;
    const int col0 = blockIdx.x * GBN;

    const int lr = lane & 15;
    const int lk = (lane >> 4) * 8;

    floatx4 acc[2][4];
#pragma unroll
    for (int r = 0; r < 2; ++r)
#pragma unroll
        for (int c = 0; c < 4; ++c) acc[r][c] = (floatx4){0.f, 0.f, 0.f, 0.f};

    const int arow = t >> 3;
    const int akc  = (t & 7) * 4;
    const int bkr  = t >> 4;
    const int bcc  = (t & 15) * 4;

    for (int pass = 0; pass < 2; ++pass) {
        if (pass == 1 && A1 == nullptr) break;
        const float* __restrict__ A = pass ? A1 : A0;
        const float* __restrict__ B = pass ? B1 : B0;
        const int K = pass ? K1 : K0;

        for (int k0 = 0; k0 < K; k0 += GBK) {
            __syncthreads();
#pragma unroll
            for (int i = 0; i < 4; ++i) {
                const int lrow = arow + i * 32;
                const int grow = row0 + lrow;
                float4 v = make_float4(0.f, 0.f, 0.f, 0.f);
                if (grow < N_NODES)
                    v = *(const float4*)(A + (long long)grow * K + k0 + akc);
                short4 sv;
                sv.x = f2bf(v.x); sv.y = f2bf(v.y);
                sv.z = f2bf(v.z); sv.w = f2bf(v.w);
                *(short4*)(&As[lrow * LDA + akc]) = sv;
            }
#pragma unroll
            for (int i = 0; i < 2; ++i) {
                const int k = bkr + i * 16;
                const int gc = col0 + bcc;
                float4 v;
                if (gc + 3 < M) {
                    v = *(const float4*)(B + (long long)(k0 + k) * M + gc);
                } else {
                    v.x = (gc + 0 < M) ? B[(long long)(k0 + k) * M + gc + 0] : 0.f;
                    v.y = (gc + 1 < M) ? B[(long long)(k0 + k) * M + gc + 1] : 0.f;
                    v.z = (gc + 2 < M) ? B[(long long)(k0 + k) * M + gc + 2] : 0.f;
                    v.w = (gc + 3 < M) ? B[(long long)(k0 + k) * M + gc + 3] : 0.f;
                }
                Bs[(bcc + 0) * LDB + k] = f2bf(v.x);
                Bs[(bcc + 1) * LDB + k] = f2bf(v.y);
                Bs[(bcc + 2) * LDB + k] = f2bf(v.z);
                Bs[(bcc + 3) * LDB + k] = f2bf(v.w);
            }
            __syncthreads();

            bf16x8 af[2], bfr[4];
#pragma unroll
            for (int r = 0; r < 2; ++r)
                af[r] = *(const bf16x8*)(&As[(wv * 32 + r * 16 + lr) * LDA + lk]);
#pragma unroll
            for (int c = 0; c < 4; ++c)
                bfr[c] = *(const bf16x8*)(&Bs[(c * 16 + lr) * LDB + lk]);
#pragma unroll
            for (int r = 0; r < 2; ++r)
#pragma unroll
                for (int c = 0; c < 4; ++c)
                    acc[r][c] = __builtin_amdgcn_mfma_f32_16x16x32_bf16(
                        af[r], bfr[c], acc[r][c], 0, 0, 0);
        }
    }

#pragma unroll
    for (int r = 0; r < 2; ++r) {
#pragma unroll
        for (int g = 0; g < 4; ++g) {
            const int row = row0 + wv * 32 + r * 16 + (lane >> 4) * 4 + g;
            if (row >= N_NODES) continue;
#pragma unroll
            for (int c = 0; c < 4; ++c) {
                const int col = col0 + c * 16 + lr;
                if (col >= M) continue;
                float v = acc[r][c][g];
                if (do_bias) v += bias[col];
                if (bn_relu) {
                    v = (v - mean[col]) * (gamma[col] * rsqrtf(var[col] + BN_EPS)) + beta[col];
                    v = fmaxf(v, 0.0f);
                }
                C[(long long)row * M + col] = v;
            }
        }
    }
}

// ---------------------------------------------------------------------------
// shared epilogue kernels
// ---------------------------------------------------------------------------
// 4-way edge unroll: 4 independent 188B U-row loads in flight per wave
__global__ __launch_bounds__(256) void gather_add_out(
    const float* __restrict__ U, const int* __restrict__ rp,
    const int* __restrict__ ssrc, const float* __restrict__ invd,
    float* __restrict__ z)
{
    const int w = (blockIdx.x * 256 + threadIdx.x) >> 6;
    const int lane = threadIdx.x & 63;
    if (w >= N_NODES) return;
    if (lane >= D_OUT) return;
    const int start = rp[w], end = rp[w + 1];
    const float* Ub = U + lane;
    float a0 = 0.f, a1 = 0.f, a2 = 0.f, a3 = 0.f;
    int e = start;
    for (; e + 3 < end; e += 4) {
        int s0 = ssrc[e], s1 = ssrc[e + 1], s2 = ssrc[e + 2], s3 = ssrc[e + 3];
        a0 += Ub[(long long)s0 * D_OUT];
        a1 += Ub[(long long)s1 * D_OUT];
        a2 += Ub[(long long)s2 * D_OUT];
        a3 += Ub[(long long)s3 * D_OUT];
    }
    for (; e < end; ++e) a0 += Ub[(long long)ssrc[e] * D_OUT];
    z[(long long)w * D_OUT + lane] += ((a0 + a1) + (a2 + a3)) * invd[w];
}

__global__ void log_softmax_kernel(const float* __restrict__ z, float* __restrict__ y) {
    const int gtid = blockIdx.x * blockDim.x + threadIdx.x;
    const int row = gtid >> 6;
    const int lane = threadIdx.x & 63;
    if (row >= N_NODES) return;

    const float* zr = z + (long long)row * D_OUT;
    float v = (lane < D_OUT) ? zr[lane] : -INFINITY;

    float m = v;
#pragma unroll
    for (int off = 32; off > 0; off >>= 1) m = fmaxf(m, __shfl_down(m, off));
    m = __shfl(m, 0);

    float ev = (lane < D_OUT) ? expf(v - m) : 0.0f;
    float s = ev;
#pragma unroll
    for (int off = 32; off > 0; off >>= 1) s += __shfl_down(s, off);
    s = __shfl(s, 0);

    if (lane < D_OUT) y[(long long)row * D_OUT + lane] = v - m - logf(s);
}

// ---------------------------------------------------------------------------
// launch
// ---------------------------------------------------------------------------
extern "C" void kernel_launch(void* const* d_in, const int* in_sizes, int n_in,
                              void* d_out, int out_size, void* d_ws, size_t ws_size,
                              hipStream_t stream) {
    const float* x     = (const float*)d_in[0];
    const int*   ei    = (const int*)d_in[1];
    const float* W1_l  = (const float*)d_in[2];
    const float* b1    = (const float*)d_in[3];
    const float* W1_r  = (const float*)d_in[4];
    const float* bn1_g = (const float*)d_in[5];
    const float* bn1_b = (const float*)d_in[6];
    const float* bn1_m = (const float*)d_in[7];
    const float* bn1_v = (const float*)d_in[8];
    const float* W2_l  = (const float*)d_in[9];
    const float* b2    = (const float*)d_in[10];
    const float* W2_r  = (const float*)d_in[11];
    const float* bn2_g = (const float*)d_in[12];
    const float* bn2_b = (const float*)d_in[13];
    const float* bn2_m = (const float*)d_in[14];
    const float* bn2_v = (const float*)d_in[15];
    const float* W3_l  = (const float*)d_in[16];
    const float* b3    = (const float*)d_in[17];
    const float* W3_r  = (const float*)d_in[18];

    // --- common workspace (CSR) ---
    char* ws = (char*)d_ws;
    int*   degi    = (int*)(ws + 0);
    int*   row_ptr = (int*)(ws + 200064);
    int*   cursor  = (int*)(ws + 400128);
    float* invd    = (float*)(ws + 600192);
    int*   flag    = (int*)(ws + 800256);
    int*   bsum    = (int*)(ws + 800320);
    int*   ssrc    = (int*)(ws + 801152);          // 3.2 MB -> ends 4,001,152

    // d_out layout: z [N*47] | y_pred [N*47] | S1 [N*256] | S2 [N*256]
    float* z     = (float*)d_out;
    float* ypred = z + (long long)N_NODES * D_OUT;
    float* S1    = ypred + (long long)N_NODES * D_OUT;
    float* S2    = S1 + (long long)N_NODES * D_HID;

    // --- CSR build (shared) ---
    detect_idx_kernel<<<1, 256, 0, stream>>>(ei, flag);
    hipMemsetAsync(degi, 0, N_NODES * sizeof(int), stream);
    count_deg_kernel<<<(N_EDGES + 255) / 256, 256, 0, stream>>>(ei, flag, degi);
    block_sum_kernel<<<SCAN_NBLK, 256, 0, stream>>>(degi, bsum);
    scan_bsums_kernel<<<1, 256, 0, stream>>>(bsum, row_ptr);
    fill_rowptr_kernel<<<SCAN_NBLK, 256, 0, stream>>>(degi, bsum, row_ptr, cursor, invd);
    fill_csr_kernel<<<(N_EDGES + 255) / 256, 256, 0, stream>>>(ei, flag, cursor, ssrc);

    const int gblocks = (N_NODES * 64 + 255) / 256;

    // FULL bf16-direct plan needs 94,059,904 B of ws
    if (ws_size >= 94059904ULL) {
        u16*   wt1l = (u16*)(ws + 4001152);
        u16*   wt1r = (u16*)(ws + 4066688);
        u16*   wt2l = (u16*)(ws + 4132224);
        u16*   wt2r = (u16*)(ws + 4263296);
        u16*   wt3  = (u16*)(ws + 4394368);
        u16*   xb   = (u16*)(ws + 4459904);        // N*128 bf16
        u16*   S1b  = (u16*)(ws + 17259904);       // N*256 bf16
        u16*   S2b  = (u16*)(ws + 42859904);       // N*256 bf16
        u16*   agg  = (u16*)(ws + 68459904);       // N*256 bf16 (reused as U fp32)
        float* U    = (float*)agg;

        convert_xb_kernel<<<(N_NODES * D_IN / 4 + 255) / 256, 256, 0, stream>>>(x, xb);
        build_wt_kernel<<<(229376 + 255) / 256, 256, 0, stream>>>(
            W1_l, W1_r, W2_l, W2_r, W3_l, W3_r, wt1l, wt1r, wt2l, wt2r, wt3);

        // 1-D swizzled grids: nxb * 8 * ceil(391/8) blocks
        const int nHid = 4 * 8 * 49;   // NC=256 -> 1568 (4 early-return)
        const int nOut = 2 * 8 * 49;   // NC=128 -> 784  (2 early-return)

        // layer 1 (K=128 x2 passes, NKT=8)
        gather_mean_bf<128><<<gblocks, 256, 0, stream>>>(xb, row_ptr, ssrc, invd, agg);
        mfma_lds<4, 4, 256><<<nHid, 256, 0, stream>>>(
            agg, wt1l, xb, wt1r,
            b1, bn1_g, bn1_b, bn1_m, bn1_v,
            S1, D_HID, 1, 1, S1b, nullptr, 0);
        // layer 2 (K=256 x2 passes, NKT=16)
        gather_mean_bf<256><<<gblocks, 256, 0, stream>>>(S1b, row_ptr, ssrc, invd, agg);
        mfma_lds<8, 8, 256><<<nHid, 256, 0, stream>>>(
            agg, wt2l, S1b, wt2r,
            b2, bn2_g, bn2_b, bn2_m, bn2_v,
            S2, D_HID, 1, 1, S2b, nullptr, 0);
        // layer 3 (fused transform-first: U = S2@W3_l, z = S2@W3_r + b3)
        mfma_lds<8, 0, 128><<<nOut, 256, 0, stream>>>(
            S2b, wt3, nullptr, nullptr,
            b3, nullptr, nullptr, nullptr, nullptr,
            U, 94, 0, 0, nullptr, z, D_OUT);
        gather_add_out<<<gblocks, 256, 0, stream>>>(U, row_ptr, ssrc, invd, z);
    } else {
        // SAFE: R5 fp32-LDS pipeline (proven <= 55.2 MB)
        float* aggF = (float*)(ws + 4001152);      // N*256 fp32, ends 55,201,152
        float* U    = aggF;

        const dim3 gHid(D_HID / GBN, (N_NODES + GBM - 1) / GBM);
        const dim3 gOut(1, (N_NODES + GBM - 1) / GBM);

        gather_mean<128><<<gblocks, 256, 0, stream>>>(x, D_IN, row_ptr, ssrc, invd, aggF);
        mfma_gemm<<<gHid, 256, 0, stream>>>(aggF, W1_l, D_IN, x, W1_r, D_IN,
                                            b1, bn1_g, bn1_b, bn1_m, bn1_v,
                                            S1, D_HID, 1, 1);
        gather_mean<256><<<gblocks, 256, 0, stream>>>(S1, D_HID, row_ptr, ssrc, invd, aggF);
        mfma_gemm<<<gHid, 256, 0, stream>>>(aggF, W2_l, D_HID, S1, W2_r, D_HID,
                                            b2, bn2_g, bn2_b, bn2_m, bn2_v,
                                            S2, D_HID, 1, 1);
        mfma_gemm<<<gOut, 256, 0, stream>>>(S2, W3_l, D_HID, nullptr, nullptr, 0,
                                            nullptr, nullptr, nullptr, nullptr, nullptr,
                                            U, D_OUT, 0, 0);
        mfma_gemm<<<gOut, 256, 0, stream>>>(S2, W3_r, D_HID, nullptr, nullptr, 0,
                                            b3, nullptr, nullptr, nullptr, nullptr,
                                            z, D_OUT, 1, 0);
        gather_add_out<<<gblocks, 256, 0, stream>>>(U, row_ptr, ssrc, invd, z);
    }

    log_softmax_kernel<<<gblocks, 256, 0, stream>>>(z, ypred);
}

// Round 10
// 498.724 us; speedup vs baseline: 1.3497x; 1.0246x over previous
//
#include <hip/hip_runtime.h>
#include <cmath>

#define N_NODES 50000
#define N_EDGES 800000
#define D_IN    128
#define D_HID   256
#define D_OUT   47
#define BN_EPS  1e-5f
#define SCAN_NBLK ((N_NODES + 255) / 256)   // 196

typedef __attribute__((ext_vector_type(8))) short bf16x8;
typedef __attribute__((ext_vector_type(4))) float floatx4;
typedef unsigned short u16;
typedef unsigned int u32;

__device__ __forceinline__ short f2bf(float f) {          // legacy (short)
    unsigned u = __float_as_uint(f);
    u += 0x7fff + ((u >> 16) & 1);
    return (short)(u >> 16);
}
__device__ __forceinline__ u16 f2bf_u(float f) {
    unsigned u = __float_as_uint(f);
    u += 0x7fff + ((u >> 16) & 1);
    return (u16)(u >> 16);
}
__device__ __forceinline__ float bf2f(u16 h) {
    return __uint_as_float(((unsigned)h) << 16);
}

// async 16B global->LDS DMA (the op hipcc cannot sink; tracked by vmcnt)
__device__ __forceinline__ void load_lds16(const void* g, void* l) {
    __builtin_amdgcn_global_load_lds(
        (const __attribute__((address_space(1))) u32*)g,
        (__attribute__((address_space(3))) u32*)l,
        16, 0, 0);
}

// ---------------------------------------------------------------------------
// edge_index layout detection (int64 vs int32)
// ---------------------------------------------------------------------------
__global__ void detect_idx_kernel(const int* __restrict__ ei, int* __restrict__ flag) {
    __shared__ int any_nonzero;
    if (threadIdx.x == 0) any_nonzero = 0;
    __syncthreads();
    int v = ei[2 * threadIdx.x + 1];
    if (v != 0) atomicAdd(&any_nonzero, 1);
    __syncthreads();
    if (threadIdx.x == 0) *flag = (any_nonzero == 0) ? 1 : 0;
}

__device__ __forceinline__ int load_edge(const int* __restrict__ ei, int e, int which, int is64) {
    if (is64) return ei[2 * ((long long)which * N_EDGES + e)];
    return ei[(long long)which * N_EDGES + e];
}

// ---------------------------------------------------------------------------
// CSR build
// ---------------------------------------------------------------------------
__global__ void count_deg_kernel(const int* __restrict__ ei, const int* __restrict__ flag,
                                 int* __restrict__ degi) {
    int e = blockIdx.x * blockDim.x + threadIdx.x;
    if (e >= N_EDGES) return;
    int is64 = *flag;
    atomicAdd(&degi[load_edge(ei, e, 1, is64)], 1);
}

__global__ __launch_bounds__(256) void block_sum_kernel(const int* __restrict__ degi,
                                                        int* __restrict__ bsum) {
    const int i = blockIdx.x * 256 + threadIdx.x;
    int v = (i < N_NODES) ? degi[i] : 0;
#pragma unroll
    for (int off = 32; off > 0; off >>= 1) v += __shfl_down(v, off);
    __shared__ int sh[4];
    if ((threadIdx.x & 63) == 0) sh[threadIdx.x >> 6] = v;
    __syncthreads();
    if (threadIdx.x == 0) bsum[blockIdx.x] = sh[0] + sh[1] + sh[2] + sh[3];
}

__global__ __launch_bounds__(256) void scan_bsums_kernel(int* __restrict__ bsum,
                                                         int* __restrict__ row_ptr) {
    const int t = threadIdx.x;
    __shared__ int sh[256];
    int v = (t < SCAN_NBLK) ? bsum[t] : 0;
    sh[t] = v;
    __syncthreads();
#pragma unroll
    for (int off = 1; off < 256; off <<= 1) {
        int u = (t >= off) ? sh[t - off] : 0;
        __syncthreads();
        sh[t] += u;
        __syncthreads();
    }
    if (t < SCAN_NBLK) bsum[t] = sh[t] - v;
    if (t == 255) row_ptr[N_NODES] = sh[255];
}

__global__ __launch_bounds__(256) void fill_rowptr_kernel(const int* __restrict__ degi,
                                                          const int* __restrict__ bsum,
                                                          int* __restrict__ row_ptr,
                                                          int* __restrict__ cursor,
                                                          float* __restrict__ invd) {
    const int t = threadIdx.x;
    const int i = blockIdx.x * 256 + t;
    __shared__ int sh[256];
    int d = (i < N_NODES) ? degi[i] : 0;
    sh[t] = d;
    __syncthreads();
#pragma unroll
    for (int off = 1; off < 256; off <<= 1) {
        int u = (t >= off) ? sh[t - off] : 0;
        __syncthreads();
        sh[t] += u;
        __syncthreads();
    }
    if (i < N_NODES) {
        const int pos = bsum[blockIdx.x] + sh[t] - d;
        row_ptr[i] = pos;
        cursor[i]  = pos;
        invd[i]    = 1.0f / fmaxf((float)d, 1.0f);
    }
}

__global__ void fill_csr_kernel(const int* __restrict__ ei, const int* __restrict__ flag,
                                int* __restrict__ cursor, int* __restrict__ ssrc) {
    int e = blockIdx.x * blockDim.x + threadIdx.x;
    if (e >= N_EDGES) return;
    int is64 = *flag;
    int s = load_edge(ei, e, 0, is64);
    int d = load_edge(ei, e, 1, is64);
    int pos = atomicAdd(&cursor[d], 1);
    ssrc[pos] = s;
}

// ===========================================================================
// FULL (bf16-direct) path kernels
// ===========================================================================

// x (fp32) -> xb (bf16), N*128 elems
__global__ void convert_xb_kernel(const float* __restrict__ x, u16* __restrict__ xb) {
    const int n4 = N_NODES * D_IN / 4;
    int i = blockIdx.x * 256 + threadIdx.x;
    if (i >= n4) return;
    float4 v = ((const float4*)x)[i];
    ushort4 o;
    o.x = f2bf_u(v.x); o.y = f2bf_u(v.y); o.z = f2bf_u(v.z); o.w = f2bf_u(v.w);
    ((ushort4*)xb)[i] = o;
}

// all weights -> bf16, k-blocked layout: WT[kb][col][32] (kb = k/32).
// WT3 = [W3_l | W3_r | 0pad] (128 cols x 256 k)
__global__ void build_wt_kernel(const float* __restrict__ W1l, const float* __restrict__ W1r,
                                const float* __restrict__ W2l, const float* __restrict__ W2r,
                                const float* __restrict__ W3l, const float* __restrict__ W3r,
                                u16* __restrict__ wt1l, u16* __restrict__ wt1r,
                                u16* __restrict__ wt2l, u16* __restrict__ wt2r,
                                u16* __restrict__ wt3) {
    int idx = blockIdx.x * 256 + threadIdx.x;
    if (idx < 65536) {                       // WT1l / WT1r : NC=256, K=128
        int seg = idx >> 15, d = idx & 32767;
        int kb = d >> 13, col = (d >> 5) & 255, kq = d & 31;
        int k = kb * 32 + kq;
        const float* W = seg ? W1r : W1l;
        u16* WT = seg ? wt1r : wt1l;
        WT[d] = f2bf_u(W[k * 256 + col]);
    } else if (idx < 196608) {               // WT2l / WT2r : NC=256, K=256
        int d = idx - 65536;
        int seg = d >> 16; d &= 65535;
        int kb = d >> 13, col = (d >> 5) & 255, kq = d & 31;
        int k = kb * 32 + kq;
        const float* W = seg ? W2r : W2l;
        u16* WT = seg ? wt2r : wt2l;
        WT[d] = f2bf_u(W[k * 256 + col]);
    } else if (idx < 229376) {               // WT3 : NC=128, K=256, zero-padded
        int d = idx - 196608;
        int kb = d >> 12, col = (d >> 5) & 127, kq = d & 31;
        int k = kb * 32 + kq;
        float v = 0.f;
        if (col < 47)      v = W3l[k * 47 + col];
        else if (col < 94) v = W3r[k * 47 + (col - 47)];
        wt3[d] = f2bf_u(v);
    }
}

// CSR gather-mean over bf16 rows: one wave per node.
// 8-way edge unroll: 8 independent row-loads in flight per wave (R8: 4-way
// left ~2x MLP on the table; this kernel family is latency-bound, not BW).
template <int CC>
__global__ __launch_bounds__(256) void gather_mean_bf(
    const u16* __restrict__ Xb, const int* __restrict__ rp,
    const int* __restrict__ ssrc, const float* __restrict__ invd,
    u16* __restrict__ agg)
{
    const int w = (blockIdx.x * 256 + threadIdx.x) >> 6;
    const int lane = threadIdx.x & 63;
    if (w >= N_NODES) return;
    const int start = rp[w], end = rp[w + 1];
    const float sc = invd[w];

    if constexpr (CC == 256) {
        const u16* base = Xb + lane * 4;
        float4 a = make_float4(0.f, 0.f, 0.f, 0.f);
        float4 b = make_float4(0.f, 0.f, 0.f, 0.f);
        int e = start;
        for (; e + 7 < end; e += 8) {
            const ushort4 v0 = *(const ushort4*)(base + (size_t)ssrc[e] * 256);
            const ushort4 v1 = *(const ushort4*)(base + (size_t)ssrc[e + 1] * 256);
            const ushort4 v2 = *(const ushort4*)(base + (size_t)ssrc[e + 2] * 256);
            const ushort4 v3 = *(const ushort4*)(base + (size_t)ssrc[e + 3] * 256);
            const ushort4 v4 = *(const ushort4*)(base + (size_t)ssrc[e + 4] * 256);
            const ushort4 v5 = *(const ushort4*)(base + (size_t)ssrc[e + 5] * 256);
            const ushort4 v6 = *(const ushort4*)(base + (size_t)ssrc[e + 6] * 256);
            const ushort4 v7 = *(const ushort4*)(base + (size_t)ssrc[e + 7] * 256);
            a.x += (bf2f(v0.x) + bf2f(v1.x)) + (bf2f(v2.x) + bf2f(v3.x));
            a.y += (bf2f(v0.y) + bf2f(v1.y)) + (bf2f(v2.y) + bf2f(v3.y));
            a.z += (bf2f(v0.z) + bf2f(v1.z)) + (bf2f(v2.z) + bf2f(v3.z));
            a.w += (bf2f(v0.w) + bf2f(v1.w)) + (bf2f(v2.w) + bf2f(v3.w));
            b.x += (bf2f(v4.x) + bf2f(v5.x)) + (bf2f(v6.x) + bf2f(v7.x));
            b.y += (bf2f(v4.y) + bf2f(v5.y)) + (bf2f(v6.y) + bf2f(v7.y));
            b.z += (bf2f(v4.z) + bf2f(v5.z)) + (bf2f(v6.z) + bf2f(v7.z));
            b.w += (bf2f(v4.w) + bf2f(v5.w)) + (bf2f(v6.w) + bf2f(v7.w));
        }
        for (; e < end; ++e) {
            const ushort4 v = *(const ushort4*)(base + (size_t)ssrc[e] * 256);
            a.x += bf2f(v.x); a.y += bf2f(v.y); a.z += bf2f(v.z); a.w += bf2f(v.w);
        }
        ushort4 o;
        o.x = f2bf_u((a.x + b.x) * sc); o.y = f2bf_u((a.y + b.y) * sc);
        o.z = f2bf_u((a.z + b.z) * sc); o.w = f2bf_u((a.w + b.w) * sc);
        *(ushort4*)(agg + (size_t)w * 256 + lane * 4) = o;
    } else {  // CC == 128
        const u16* base = Xb + lane * 2;
        float2 a = make_float2(0.f, 0.f);
        float2 b = make_float2(0.f, 0.f);
        int e = start;
        for (; e + 7 < end; e += 8) {
            const ushort2 v0 = *(const ushort2*)(base + (size_t)ssrc[e] * 128);
            const ushort2 v1 = *(const ushort2*)(base + (size_t)ssrc[e + 1] * 128);
            const ushort2 v2 = *(const ushort2*)(base + (size_t)ssrc[e + 2] * 128);
            const ushort2 v3 = *(const ushort2*)(base + (size_t)ssrc[e + 3] * 128);
            const ushort2 v4 = *(const ushort2*)(base + (size_t)ssrc[e + 4] * 128);
            const ushort2 v5 = *(const ushort2*)(base + (size_t)ssrc[e + 5] * 128);
            const ushort2 v6 = *(const ushort2*)(base + (size_t)ssrc[e + 6] * 128);
            const ushort2 v7 = *(const ushort2*)(base + (size_t)ssrc[e + 7] * 128);
            a.x += (bf2f(v0.x) + bf2f(v1.x)) + (bf2f(v2.x) + bf2f(v3.x));
            a.y += (bf2f(v0.y) + bf2f(v1.y)) + (bf2f(v2.y) + bf2f(v3.y));
            b.x += (bf2f(v4.x) + bf2f(v5.x)) + (bf2f(v6.x) + bf2f(v7.x));
            b.y += (bf2f(v4.y) + bf2f(v5.y)) + (bf2f(v6.y) + bf2f(v7.y));
        }
        for (; e < end; ++e) {
            const ushort2 v = *(const ushort2*)(base + (size_t)ssrc[e] * 128);
            a.x += bf2f(v.x); a.y += bf2f(v.y);
        }
        ushort2 o;
        o.x = f2bf_u((a.x + b.x) * sc); o.y = f2bf_u((a.y + b.y) * sc);
        *(ushort2*)(agg + (size_t)w * 128 + lane * 2) = o;
    }
}

// ---------------------------------------------------------------------------
// LDS-staged bf16 MFMA GEMM, T3+T4 (proven R8): counted vmcnt + XCD swizzle.
// ---------------------------------------------------------------------------
template <int NK0, int NK1, int NC>
__global__ __launch_bounds__(256, 2) void mfma_lds(
    const u16* __restrict__ A0, const u16* __restrict__ WT0,
    const u16* __restrict__ A1, const u16* __restrict__ WT1,
    const float* __restrict__ bias,
    const float* __restrict__ gamma, const float* __restrict__ beta,
    const float* __restrict__ mean, const float* __restrict__ var,
    float* __restrict__ C, int M, int do_bias, int bn_relu,
    u16* __restrict__ Cb, float* __restrict__ C2, int split)
{
    __shared__ __align__(16) char lds[24576];   // A dbuf @0/8192, B dbuf @16384/20480

    constexpr int NYB = (N_NODES + 127) / 128;  // 391 row-panels
    constexpr int nxb = NC / 64;                // col-blocks per row-panel

    // ---- XCD col-sibling swizzle (1-D grid, nxb*8*ceil(NYB/8) blocks)
    const int bid  = blockIdx.x;
    const int xcd  = bid & 7;
    const int slot = bid >> 3;
    const int cb   = slot % nxb;
    const int yg   = slot / nxb;
    const int yb   = yg * 8 + xcd;
    if (yb >= NYB) return;                      // pad guard (uniform per block)

    const int t = threadIdx.x;
    const int wv = t >> 6, lane = t & 63;
    const int lr = lane & 15, quad = lane >> 4;
    const int row0 = yb * 128;
    const int col0 = cb * 64;
    constexpr int NKT = NK0 + NK1;

    // ---- per-thread stage constants
    // A: 2 slots of 16B (8KB tile); B: 1 slot of 16B (4KB tile)
    int sIdxA[2], sCsA[2];
#pragma unroll
    for (int i = 0; i < 2; ++i) {
        int slotA = i * 256 + t;           // 0..511
        sIdxA[i] = slotA >> 2;             // row 0..127
        int c = slotA & 3;
        sCsA[i] = c ^ ((sIdxA[i] >> 1) & 3);
    }
    int srowA[2];
#pragma unroll
    for (int i = 0; i < 2; ++i) {
        int r = row0 + sIdxA[i];
        srowA[i] = (r < N_NODES) ? r : (N_NODES - 1);   // clamp (garbage rows unused)
    }
    const int sIdxB = t >> 2;              // col 0..63
    const int sCsB  = (t & 3) ^ ((sIdxB >> 1) & 3);

    // ---- ds_read byte offsets within a tile (swizzled chunk)
    int offA[2], offB[4];
#pragma unroll
    for (int r = 0; r < 2; ++r) {
        int idx = wv * 32 + r * 16 + lr;
        offA[r] = idx * 64 + ((quad ^ ((idx >> 1) & 3)) * 16);
    }
#pragma unroll
    for (int c = 0; c < 4; ++c) {
        int idx = c * 16 + lr;
        offB[c] = idx * 64 + ((quad ^ ((idx >> 1) & 3)) * 16);
    }

    floatx4 acc[2][4];
#pragma unroll
    for (int r = 0; r < 2; ++r)
#pragma unroll
        for (int c = 0; c < 4; ++c) acc[r][c] = (floatx4){0.f, 0.f, 0.f, 0.f};

    // ---- stage k-step ks into buffer 'cur' (3 loads/thread, vmcnt-tracked)
    auto stage = [&](int ks, int cur) {
        const char* Ab; const char* Wb; int kb; size_t Kb;  // Kb = row stride bytes
        if (ks < NK0) { Ab = (const char*)A0; Wb = (const char*)WT0; kb = ks;       Kb = (size_t)NK0 * 64; }
        else          { Ab = (const char*)A1; Wb = (const char*)WT1; kb = ks - NK0; Kb = (size_t)NK1 * 64; }
#pragma unroll
        for (int i = 0; i < 2; ++i) {
            const char* srcA = Ab + (size_t)srowA[i] * Kb + (size_t)kb * 64 + sCsA[i] * 16;
            load_lds16(srcA, lds + cur * 8192 + (i * 256 + t) * 16);
        }
        const char* srcB = Wb + ((size_t)kb * NC + col0 + sIdxB) * 64 + sCsB * 16;
        load_lds16(srcB, lds + 16384 + cur * 4096 + t * 16);
    };

    // ---- compute current buffer: 2 A-frags + 4 B-frags + 8 MFMA
    auto compute = [&](int cur) {
        const char* la = lds + cur * 8192;
        const char* lb = lds + 16384 + cur * 4096;
        bf16x8 a[2], b[4];
#pragma unroll
        for (int r = 0; r < 2; ++r) a[r] = *(const bf16x8*)(la + offA[r]);
#pragma unroll
        for (int c = 0; c < 4; ++c) b[c] = *(const bf16x8*)(lb + offB[c]);
#pragma unroll
        for (int c = 0; c < 4; ++c) {
            acc[0][c] = __builtin_amdgcn_mfma_f32_16x16x32_bf16(a[0], b[c], acc[0][c], 0, 0, 0);
            acc[1][c] = __builtin_amdgcn_mfma_f32_16x16x32_bf16(a[1], b[c], acc[1][c], 0, 0, 0);
        }
    };

    // ---- T4 counted-vmcnt main loop: stages ks and ks+1 in flight; never
    //      drain to 0 until the final stage.
    stage(0, 0);
    if constexpr (NKT > 1) stage(1, 1);
#pragma unroll
    for (int ks = 0; ks < NKT; ++ks) {
        if (ks < NKT - 1) {
            asm volatile("s_waitcnt vmcnt(3)" ::: "memory");   // stage ks landed (3 of ks+1 in flight)
        } else {
            asm volatile("s_waitcnt vmcnt(0)" ::: "memory");   // final stage
        }
        __builtin_amdgcn_s_barrier();        // all waves' stage(ks) visible
        __builtin_amdgcn_sched_barrier(0);   // pin: no hoist of ds_read above barrier
        compute(ks & 1);
        if (ks + 2 < NKT) {
            __builtin_amdgcn_s_barrier();    // all waves done reading buf[ks&1]
            stage(ks + 2, ks & 1);           // refill freed buffer; loads fly on
        }
    }

    // ---- epilogue (C/D: col=lr, row=quad*4+g) — proven round-0 mapping
#pragma unroll
    for (int r = 0; r < 2; ++r) {
#pragma unroll
        for (int g = 0; g < 4; ++g) {
            const int row = row0 + wv * 32 + r * 16 + quad * 4 + g;
            if (row >= N_NODES) continue;
#pragma unroll
            for (int c = 0; c < 4; ++c) {
                const int col = col0 + c * 16 + lr;
                float v = acc[r][c][g];
                if (split > 0) {
                    if (col < split) {
                        C[(size_t)row * split + col] = v;
                    } else if (col < 2 * split) {
                        C2[(size_t)row * split + (col - split)] = v + bias[col - split];
                    }
                } else {
                    if (col >= M) continue;
                    if (do_bias) v += bias[col];
                    if (bn_relu) {
                        v = (v - mean[col]) * (gamma[col] * rsqrtf(var[col] + BN_EPS)) + beta[col];
                        v = fmaxf(v, 0.0f);
                    }
                    const size_t off = (size_t)row * M + col;
                    C[off] = v;
                    if (Cb) Cb[off] = f2bf_u(v);
                }
            }
        }
    }
}

// ===========================================================================
// SAFE path kernels (R5, proven)
// ===========================================================================
template <int CC>
__global__ __launch_bounds__(256) void gather_mean(
    const float* __restrict__ X, int ldx,
    const int* __restrict__ rp, const int* __restrict__ ssrc,
    const float* __restrict__ invd, float* __restrict__ agg)
{
    const long long gid = (long long)blockIdx.x * blockDim.x + threadIdx.x;
    const int w = (int)(gid >> 6);
    const int lane = threadIdx.x & 63;
    if (w >= N_NODES) return;
    const int start = rp[w], end = rp[w + 1];
    const float sc = invd[w];

    if constexpr (CC == 256) {
        const float* base = X + lane * 4;
        float4 a = make_float4(0.f, 0.f, 0.f, 0.f);
        int e = start;
        for (; e + 1 < end; e += 2) {
            int s0 = ssrc[e], s1 = ssrc[e + 1];
            float4 v0 = *(const float4*)(base + (long long)s0 * ldx);
            float4 v1 = *(const float4*)(base + (long long)s1 * ldx);
            a.x += v0.x + v1.x; a.y += v0.y + v1.y;
            a.z += v0.z + v1.z; a.w += v0.w + v1.w;
        }
        if (e < end) {
            float4 v = *(const float4*)(base + (long long)ssrc[e] * ldx);
            a.x += v.x; a.y += v.y; a.z += v.z; a.w += v.w;
        }
        float4 o = make_float4(a.x * sc, a.y * sc, a.z * sc, a.w * sc);
        *(float4*)(agg + (long long)w * 256 + lane * 4) = o;
    } else {
        const float* base = X + lane * 2;
        float2 a = make_float2(0.f, 0.f);
        int e = start;
        for (; e + 1 < end; e += 2) {
            int s0 = ssrc[e], s1 = ssrc[e + 1];
            float2 v0 = *(const float2*)(base + (long long)s0 * ldx);
            float2 v1 = *(const float2*)(base + (long long)s1 * ldx);
            a.x += v0.x + v1.x; a.y += v0.y + v1.y;
        }
        if (e < end) {
            float2 v = *(const float2*)(base + (long long)ssrc[e] * ldx);
            a.x += v.x; a.y += v.y;
        }
        float2 o = make_float2(a.x * sc, a.y * sc);
        *(float2*)(agg + (long long)w * 128 + lane * 2) = o;
    }
}

#define GBM 128
#define GBN 64
#define GBK 32
#define LDA 40
#define LDB 40

__global__ __launch_bounds__(256) void mfma_gemm(
    const float* __restrict__ A0, const float* __restrict__ B0, int K0,
    const float* __restrict__ A1, const float* __restrict__ B1, int K1,
    const float* __restrict__ bias,
    const float* __restrict__ gamma, const float* __restrict__ beta,
    const float* __restrict__ mean, const float* __restrict__ var,
    float* __restrict__ C, int M, int do_bias, int bn_relu)
{
    __shared__ short As[GBM * LDA];
    __shared__ short Bs[GBN * LDB];

    const int t = threadIdx.x;
    const int wv = t >> 6;
    const int lane = t & 63;
    const int row0 = blockIdx.y * GBM;
    const int col0 = blockIdx.x * GBN;

    const int lr = lane & 15;
    const int lk = (lane >> 4) * 8;

    floatx4 acc[2][4];
#pragma unroll
    for (int r = 0; r < 2; ++r)
#pragma unroll
        for (int c = 0; c < 4; ++c) acc[r][c] = (floatx4){0.f, 0.f, 0.f, 0.f};

    const int arow = t >> 3;
    const int akc  = (t & 7) * 4;
    const int bkr  = t >> 4;
    const int bcc  = (t & 15) * 4;

    for (int pass = 0; pass < 2; ++pass) {
        if (pass == 1 && A1 == nullptr) break;
        const float* __restrict__ A = pass ? A1 : A0;
        const float* __restrict__ B = pass ? B1 : B0;
        const int K = pass ? K1 : K0;

        for (int k0 = 0; k0 < K; k0 += GBK) {
            __syncthreads();
#pragma unroll
            for (int i = 0; i < 4; ++i) {
                const int lrow = arow + i * 32;
                const int grow = row0 + lrow;
                float4 v = make_float4(0.f, 0.f, 0.f, 0.f);
                if (grow < N_NODES)
                    v = *(const float4*)(A + (long long)grow * K + k0 + akc);
                short4 sv;
                sv.x = f2bf(v.x); sv.y = f2bf(v.y);
                sv.z = f2bf(v.z); sv.w = f2bf(v.w);
                *(short4*)(&As[lrow * LDA + akc]) = sv;
            }
#pragma unroll
            for (int i = 0; i < 2; ++i) {
                const int k = bkr + i * 16;
                const int gc = col0 + bcc;
                float4 v;
                if (gc + 3 < M) {
                    v = *(const float4*)(B + (long long)(k0 + k) * M + gc);
                } else {
                    v.x = (gc + 0 < M) ? B[(long long)(k0 + k) * M + gc + 0] : 0.f;
                    v.y = (gc + 1 < M) ? B[(long long)(k0 + k) * M + gc + 1] : 0.f;
                    v.z = (gc + 2 < M) ? B[(long long)(k0 + k) * M + gc + 2] : 0.f;
                    v.w = (gc + 3 < M) ? B[(long long)(k0 + k) * M + gc + 3] : 0.f;
                }
                Bs[(bcc + 0) * LDB + k] = f2bf(v.x);
                Bs[(bcc + 1) * LDB + k] = f2bf(v.y);
                Bs[(bcc + 2) * LDB + k] = f2bf(v.z);
                Bs[(bcc + 3) * LDB + k] = f2bf(v.w);
            }
            __syncthreads();

            bf16x8 af[2], bfr[4];
#pragma unroll
            for (int r = 0; r < 2; ++r)
                af[r] = *(const bf16x8*)(&As[(wv * 32 + r * 16 + lr) * LDA + lk]);
#pragma unroll
            for (int c = 0; c < 4; ++c)
                bfr[c] = *(const bf16x8*)(&Bs[(c * 16 + lr) * LDB + lk]);
#pragma unroll
            for (int r = 0; r < 2; ++r)
#pragma unroll
                for (int c = 0; c < 4; ++c)
                    acc[r][c] = __builtin_amdgcn_mfma_f32_16x16x32_bf16(
                        af[r], bfr[c], acc[r][c], 0, 0, 0);
        }
    }

#pragma unroll
    for (int r = 0; r < 2; ++r) {
#pragma unroll
        for (int g = 0; g < 4; ++g) {
            const int row = row0 + wv * 32 + r * 16 + (lane >> 4) * 4 + g;
            if (row >= N_NODES) continue;
#pragma unroll
            for (int c = 0; c < 4; ++c) {
                const int col = col0 + c * 16 + lr;
                if (col >= M) continue;
                float v = acc[r][c][g];
                if (do_bias) v += bias[col];
                if (bn_relu) {
                    v = (v - mean[col]) * (gamma[col] * rsqrtf(var[col] + BN_EPS)) + beta[col];
                    v = fmaxf(v, 0.0f);
                }
                C[(long long)row * M + col] = v;
            }
        }
    }
}

// ---------------------------------------------------------------------------
// fused epilogue: gather-add U into z, then log_softmax on the completed
// row IN-WAVE (each wave holds all 47 cols of its node). Eliminates the
// separate log_softmax kernel + z round-trip (18.8 MB).
// 8-way edge unroll (R6 proved 4-way fixed the MLP ceiling; 8 doubles it).
// ---------------------------------------------------------------------------
__global__ __launch_bounds__(256) void gather_add_softmax(
    const float* __restrict__ U, const int* __restrict__ rp,
    const int* __restrict__ ssrc, const float* __restrict__ invd,
    float* __restrict__ z, float* __restrict__ y)
{
    const int w = (blockIdx.x * 256 + threadIdx.x) >> 6;
    const int lane = threadIdx.x & 63;
    if (w >= N_NODES) return;
    const bool act = lane < D_OUT;
    const int start = rp[w], end = rp[w + 1];
    const float* Ub = U + lane;

    float a0 = 0.f, a1 = 0.f, a2 = 0.f, a3 = 0.f;
    float a4 = 0.f, a5 = 0.f, a6 = 0.f, a7 = 0.f;
    if (act) {
        int e = start;
        for (; e + 7 < end; e += 8) {
            a0 += Ub[(long long)ssrc[e]     * D_OUT];
            a1 += Ub[(long long)ssrc[e + 1] * D_OUT];
            a2 += Ub[(long long)ssrc[e + 2] * D_OUT];
            a3 += Ub[(long long)ssrc[e + 3] * D_OUT];
            a4 += Ub[(long long)ssrc[e + 4] * D_OUT];
            a5 += Ub[(long long)ssrc[e + 5] * D_OUT];
            a6 += Ub[(long long)ssrc[e + 6] * D_OUT];
            a7 += Ub[(long long)ssrc[e + 7] * D_OUT];
        }
        for (; e < end; ++e) a0 += Ub[(long long)ssrc[e] * D_OUT];
    }
    // all 64 lanes converge here for the wave reductions
    float zv = 0.f;
    if (act) {
        zv = z[(long long)w * D_OUT + lane]
           + (((a0 + a1) + (a2 + a3)) + ((a4 + a5) + (a6 + a7))) * invd[w];
        z[(long long)w * D_OUT + lane] = zv;
    }

    float v = act ? zv : -INFINITY;
    float m = v;
#pragma unroll
    for (int off = 32; off > 0; off >>= 1) m = fmaxf(m, __shfl_down(m, off));
    m = __shfl(m, 0);

    float ev = act ? expf(v - m) : 0.0f;
    float s = ev;
#pragma unroll
    for (int off = 32; off > 0; off >>= 1) s += __shfl_down(s, off);
    s = __shfl(s, 0);

    if (act) y[(long long)w * D_OUT + lane] = v - m - logf(s);
}

// ---------------------------------------------------------------------------
// launch
// ---------------------------------------------------------------------------
extern "C" void kernel_launch(void* const* d_in, const int* in_sizes, int n_in,
                              void* d_out, int out_size, void* d_ws, size_t ws_size,
                              hipStream_t stream) {
    const float* x     = (const float*)d_in[0];
    const int*   ei    = (const int*)d_in[1];
    const float* W1_l  = (const float*)d_in[2];
    const float* b1    = (const float*)d_in[3];
    const float* W1_r  = (const float*)d_in[4];
    const float* bn1_g = (const float*)d_in[5];
    const float* bn1_b = (const float*)d_in[6];
    const float* bn1_m = (const float*)d_in[7];
    const float* bn1_v = (const float*)d_in[8];
    const float* W2_l  = (const float*)d_in[9];
    const float* b2    = (const float*)d_in[10];
    const float* W2_r  = (const float*)d_in[11];
    const float* bn2_g = (const float*)d_in[12];
    const float* bn2_b = (const float*)d_in[13];
    const float* bn2_m = (const float*)d_in[14];
    const float* bn2_v = (const float*)d_in[15];
    const float* W3_l  = (const float*)d_in[16];
    const float* b3    = (const float*)d_in[17];
    const float* W3_r  = (const float*)d_in[18];

    // --- common workspace (CSR) ---
    char* ws = (char*)d_ws;
    int*   degi    = (int*)(ws + 0);
    int*   row_ptr = (int*)(ws + 200064);
    int*   cursor  = (int*)(ws + 400128);
    float* invd    = (float*)(ws + 600192);
    int*   flag    = (int*)(ws + 800256);
    int*   bsum    = (int*)(ws + 800320);
    int*   ssrc    = (int*)(ws + 801152);          // 3.2 MB -> ends 4,001,152

    // d_out layout: z [N*47] | y_pred [N*47] | S1 [N*256] | S2 [N*256]
    float* z     = (float*)d_out;
    float* ypred = z + (long long)N_NODES * D_OUT;
    float* S1    = ypred + (long long)N_NODES * D_OUT;
    float* S2    = S1 + (long long)N_NODES * D_HID;

    // --- CSR build (shared) ---
    detect_idx_kernel<<<1, 256, 0, stream>>>(ei, flag);
    hipMemsetAsync(degi, 0, N_NODES * sizeof(int), stream);
    count_deg_kernel<<<(N_EDGES + 255) / 256, 256, 0, stream>>>(ei, flag, degi);
    block_sum_kernel<<<SCAN_NBLK, 256, 0, stream>>>(degi, bsum);
    scan_bsums_kernel<<<1, 256, 0, stream>>>(bsum, row_ptr);
    fill_rowptr_kernel<<<SCAN_NBLK, 256, 0, stream>>>(degi, bsum, row_ptr, cursor, invd);
    fill_csr_kernel<<<(N_EDGES + 255) / 256, 256, 0, stream>>>(ei, flag, cursor, ssrc);

    const int gblocks = (N_NODES * 64 + 255) / 256;

    // FULL bf16-direct plan needs 94,059,904 B of ws
    if (ws_size >= 94059904ULL) {
        u16*   wt1l = (u16*)(ws + 4001152);
        u16*   wt1r = (u16*)(ws + 4066688);
        u16*   wt2l = (u16*)(ws + 4132224);
        u16*   wt2r = (u16*)(ws + 4263296);
        u16*   wt3  = (u16*)(ws + 4394368);
        u16*   xb   = (u16*)(ws + 4459904);        // N*128 bf16
        u16*   S1b  = (u16*)(ws + 17259904);       // N*256 bf16
        u16*   S2b  = (u16*)(ws + 42859904);       // N*256 bf16
        u16*   agg  = (u16*)(ws + 68459904);       // N*256 bf16 (reused as U fp32)
        float* U    = (float*)agg;

        convert_xb_kernel<<<(N_NODES * D_IN / 4 + 255) / 256, 256, 0, stream>>>(x, xb);
        build_wt_kernel<<<(229376 + 255) / 256, 256, 0, stream>>>(
            W1_l, W1_r, W2_l, W2_r, W3_l, W3_r, wt1l, wt1r, wt2l, wt2r, wt3);

        // 1-D swizzled grids: nxb * 8 * ceil(391/8) blocks
        const int nHid = 4 * 8 * 49;   // NC=256 -> 1568 (4 early-return)
        const int nOut = 2 * 8 * 49;   // NC=128 -> 784  (2 early-return)

        // layer 1 (K=128 x2 passes, NKT=8)
        gather_mean_bf<128><<<gblocks, 256, 0, stream>>>(xb, row_ptr, ssrc, invd, agg);
        mfma_lds<4, 4, 256><<<nHid, 256, 0, stream>>>(
            agg, wt1l, xb, wt1r,
            b1, bn1_g, bn1_b, bn1_m, bn1_v,
            S1, D_HID, 1, 1, S1b, nullptr, 0);
        // layer 2 (K=256 x2 passes, NKT=16)
        gather_mean_bf<256><<<gblocks, 256, 0, stream>>>(S1b, row_ptr, ssrc, invd, agg);
        mfma_lds<8, 8, 256><<<nHid, 256, 0, stream>>>(
            agg, wt2l, S1b, wt2r,
            b2, bn2_g, bn2_b, bn2_m, bn2_v,
            S2, D_HID, 1, 1, S2b, nullptr, 0);
        // layer 3 (fused transform-first: U = S2@W3_l, z = S2@W3_r + b3)
        mfma_lds<8, 0, 128><<<nOut, 256, 0, stream>>>(
            S2b, wt3, nullptr, nullptr,
            b3, nullptr, nullptr, nullptr, nullptr,
            U, 94, 0, 0, nullptr, z, D_OUT);
        gather_add_softmax<<<gblocks, 256, 0, stream>>>(U, row_ptr, ssrc, invd, z, ypred);
    } else {
        // SAFE: R5 fp32-LDS pipeline (proven <= 55.2 MB)
        float* aggF = (float*)(ws + 4001152);      // N*256 fp32, ends 55,201,152
        float* U    = aggF;

        const dim3 gHid(D_HID / GBN, (N_NODES + GBM - 1) / GBM);
        const dim3 gOut(1, (N_NODES + GBM - 1) / GBM);

        gather_mean<128><<<gblocks, 256, 0, stream>>>(x, D_IN, row_ptr, ssrc, invd, aggF);
        mfma_gemm<<<gHid, 256, 0, stream>>>(aggF, W1_l, D_IN, x, W1_r, D_IN,
                                            b1, bn1_g, bn1_b, bn1_m, bn1_v,
                                            S1, D_HID, 1, 1);
        gather_mean<256><<<gblocks, 256, 0, stream>>>(S1, D_HID, row_ptr, ssrc, invd, aggF);
        mfma_gemm<<<gHid, 256, 0, stream>>>(aggF, W2_l, D_HID, S1, W2_r, D_HID,
                                            b2, bn2_g, bn2_b, bn2_m, bn2_v,
                                            S2, D_HID, 1, 1);
        mfma_gemm<<<gOut, 256, 0, stream>>>(S2, W3_l, D_HID, nullptr, nullptr, 0,
                                            nullptr, nullptr, nullptr, nullptr, nullptr,
                                            U, D_OUT, 0, 0);
        mfma_gemm<<<gOut, 256, 0, stream>>>(S2, W3_r, D_HID, nullptr, nullptr, 0,
                                            b3, nullptr, nullptr, nullptr, nullptr,
                                            z, D_OUT, 1, 0);
        gather_add_softmax<<<gblocks, 256, 0, stream>>>(U, row_ptr, ssrc, invd, z, ypred);
    }
}